// Round 1
// baseline (1422.893 us; speedup 1.0000x reference)
//
#include <hip/hip_runtime.h>
#include <math.h>

#define NEG_SLOPE 0.2f

// ---------------- CSR build ----------------

__global__ void deg_kernel(const int* __restrict__ dst, int* __restrict__ deg, int E) {
    int i = blockIdx.x * 256 + threadIdx.x;
    if (i < E) atomicAdd(&deg[dst[i]], 1);
}

__global__ void scan_kernel(const int* __restrict__ deg, int* __restrict__ offs,
                            int* __restrict__ curs, int n) {
    __shared__ int tmp[256];
    __shared__ int carrysh;
    int t = threadIdx.x;
    if (t == 0) { carrysh = 0; offs[0] = 0; }
    __syncthreads();
    const int PER = 16;
    for (int base = 0; base < n; base += 256 * PER) {
        int loc[PER]; int s = 0;
        int b0 = base + t * PER;
#pragma unroll
        for (int k = 0; k < PER; k++) {
            int idx = b0 + k;
            int v = (idx < n) ? deg[idx] : 0;
            loc[k] = v; s += v;
        }
        tmp[t] = s; __syncthreads();
        for (int off = 1; off < 256; off <<= 1) {
            int x = (t >= off) ? tmp[t - off] : 0;
            __syncthreads();
            tmp[t] += x;
            __syncthreads();
        }
        int carry = carrysh;
        int pre = carry + tmp[t] - s;   // exclusive prefix of this thread's segment
#pragma unroll
        for (int k = 0; k < PER; k++) {
            int idx = b0 + k;
            if (idx < n) {
                curs[idx] = pre;
                offs[idx + 1] = pre + loc[k];
                pre += loc[k];
            }
        }
        __syncthreads();
        if (t == 255) carrysh = carry + tmp[255];
        __syncthreads();
    }
}

__global__ void fill_kernel(const int* __restrict__ src, const int* __restrict__ dst,
                            int* __restrict__ curs, int* __restrict__ csrc, int E) {
    int i = blockIdx.x * 256 + threadIdx.x;
    if (i < E) {
        int d = dst[i];
        int p = atomicAdd(&curs[d], 1);
        csrc[p] = src[i];
    }
}

// ---------------- fp32 GEMM: Y[M,Nout] = X[M,K] @ W[K,Nout] ----------------
// K multiple of 16, Nout multiple of 64.

__global__ __launch_bounds__(256) void gemm_kernel(const float* __restrict__ X,
                                                   const float* __restrict__ W,
                                                   float* __restrict__ Y,
                                                   int M, int K, int Nout) {
    __shared__ float As[16][68];   // transposed A tile, padded
    __shared__ float Bs[16][64];
    int tid = threadIdx.x;
    int bm = blockIdx.x * 64;
    int bn = blockIdx.y * 64;
    int tx = tid & 15, ty = tid >> 4;
    float acc[4][4] = {};
    int lr = tid >> 2;            // A-load row within tile
    int lk = (tid & 3) * 4;       // A-load k offset
    int wr = tid >> 4;            // B-load k row
    int wc = (tid & 15) * 4;      // B-load col
    for (int k0 = 0; k0 < K; k0 += 16) {
        float4 av = make_float4(0.f, 0.f, 0.f, 0.f);
        int row = bm + lr;
        if (row < M) av = *(const float4*)(X + (size_t)row * K + k0 + lk);
        As[lk + 0][lr] = av.x; As[lk + 1][lr] = av.y;
        As[lk + 2][lr] = av.z; As[lk + 3][lr] = av.w;
        *(float4*)&Bs[wr][wc] = *(const float4*)(W + (size_t)(k0 + wr) * Nout + bn + wc);
        __syncthreads();
#pragma unroll
        for (int kk = 0; kk < 16; kk++) {
            float4 a4 = *(const float4*)&As[kk][ty * 4];
            float4 b4 = *(const float4*)&Bs[kk][tx * 4];
            float a[4] = {a4.x, a4.y, a4.z, a4.w};
            float b[4] = {b4.x, b4.y, b4.z, b4.w};
#pragma unroll
            for (int i = 0; i < 4; i++)
#pragma unroll
                for (int j = 0; j < 4; j++) acc[i][j] += a[i] * b[j];
        }
        __syncthreads();
    }
#pragma unroll
    for (int i = 0; i < 4; i++) {
        int row = bm + ty * 4 + i;
        if (row < M) {
            float4 v = make_float4(acc[i][0], acc[i][1], acc[i][2], acc[i][3]);
            *(float4*)(Y + (size_t)row * Nout + bn + tx * 4) = v;
        }
    }
}

// ---------------- attention scores a_s[n,h], a_d[n,h] ----------------

__global__ void scores_kernel(const float* __restrict__ h, const float* __restrict__ att_s,
                              const float* __restrict__ att_d,
                              float* __restrict__ a_s, float* __restrict__ a_d,
                              int N, int H, int C) {
    int id = blockIdx.x * 256 + threadIdx.x;
    if (id >= N * H) return;
    int n = id / H, hh = id % H;
    const float* hp = h + (size_t)n * H * C + hh * C;
    float ss = 0.f, sd = 0.f;
    for (int c = 0; c < C; c++) {
        float v = hp[c];
        ss += v * att_s[hh * C + c];
        sd += v * att_d[hh * C + c];
    }
    a_s[id] = ss; a_d[id] = sd;
}

// ---------------- per-node GAT aggregation (wave per node) ----------------
// out[n, :] = sum_e softmax-weighted h[src_e, :] + bias ; self-loop included.

template <int H, int C, int CPL>
__global__ __launch_bounds__(256) void agg_kernel(const float* __restrict__ h,
                                                  const float* __restrict__ a_s,
                                                  const float* __restrict__ a_d,
                                                  const int* __restrict__ offs,
                                                  const int* __restrict__ csrc,
                                                  const float* __restrict__ bias,
                                                  float* __restrict__ out, int N) {
    const int HC = H * C;
    int lane = threadIdx.x & 63;
    int wid = threadIdx.x >> 6;
    int node = blockIdx.x * 4 + wid;
    if (node >= N) return;
    int off = offs[node];
    int deg = offs[node + 1] - off;
    int mych = lane * CPL;
    int myhead = mych / C;

    float adl[H];
#pragma unroll
    for (int hh = 0; hh < H; hh++) adl[hh] = a_d[node * H + hh];

    // pass 1: segment max per head (self-loop as init)
    float mx[H];
#pragma unroll
    for (int hh = 0; hh < H; hh++) {
        float sc = a_s[node * H + hh] + adl[hh];
        mx[hh] = sc > 0.f ? sc : NEG_SLOPE * sc;
    }
    for (int i = lane; i < deg; i += 64) {
        int s = csrc[off + i];
#pragma unroll
        for (int hh = 0; hh < H; hh++) {
            float sc = a_s[s * H + hh] + adl[hh];
            sc = sc > 0.f ? sc : NEG_SLOPE * sc;
            mx[hh] = fmaxf(mx[hh], sc);
        }
    }
#pragma unroll
    for (int hh = 0; hh < H; hh++) {
#pragma unroll
        for (int d = 32; d >= 1; d >>= 1)
            mx[hh] = fmaxf(mx[hh], __shfl_xor(mx[hh], d, 64));
    }

    float m_me = mx[myhead];
    float ad_me = adl[myhead];
    float den = 1e-16f;
    float acc[CPL];
#pragma unroll
    for (int k = 0; k < CPL; k++) acc[k] = 0.f;

    // self loop
    {
        float sc = a_s[node * H + myhead] + ad_me;
        sc = sc > 0.f ? sc : NEG_SLOPE * sc;
        float w = __expf(sc - m_me);
        den += w;
        const float* hp = h + (size_t)node * HC + mych;
        if (CPL == 4) {
            float4 v = *(const float4*)hp;
            acc[0] += w * v.x; acc[1] += w * v.y; acc[2] += w * v.z; acc[3] += w * v.w;
        } else if (CPL == 2) {
            float2 v = *(const float2*)hp;
            acc[0] += w * v.x; acc[1] += w * v.y;
        } else {
            acc[0] += w * hp[0];
        }
    }
    // incoming edges (serial over edges, wave-wide over channels)
    for (int e = 0; e < deg; e++) {
        int s = csrc[off + e];
        float sc = a_s[s * H + myhead] + ad_me;
        sc = sc > 0.f ? sc : NEG_SLOPE * sc;
        float w = __expf(sc - m_me);
        den += w;
        const float* hp = h + (size_t)s * HC + mych;
        if (CPL == 4) {
            float4 v = *(const float4*)hp;
            acc[0] += w * v.x; acc[1] += w * v.y; acc[2] += w * v.z; acc[3] += w * v.w;
        } else if (CPL == 2) {
            float2 v = *(const float2*)hp;
            acc[0] += w * v.x; acc[1] += w * v.y;
        } else {
            acc[0] += w * hp[0];
        }
    }
    float inv = 1.0f / den;
#pragma unroll
    for (int k = 0; k < CPL; k++)
        out[(size_t)node * HC + mych + k] = acc[k] * inv + bias[mych + k];
}

// ---------------- batch norm ----------------

__global__ void bnstats_kernel(const float* __restrict__ buf, float* __restrict__ sums,
                               int N, int Cc) {
    int t = threadIdx.x;
    int c = t % Cc;
    int rpb = 256 / Cc;
    int row = blockIdx.x * rpb + t / Cc;
    int stride = gridDim.x * rpb;
    float s = 0.f, s2 = 0.f;
    for (int n = row; n < N; n += stride) {
        float v = buf[(size_t)n * Cc + c];
        s += v; s2 += v * v;
    }
    atomicAdd(&sums[c], s);
    atomicAdd(&sums[Cc + c], s2);
}

__global__ void bnfinal_kernel(const float* __restrict__ sums, const float* __restrict__ g,
                               const float* __restrict__ bt, float* __restrict__ ss,
                               float invN, int Cc) {
    int c = threadIdx.x;
    if (c < Cc) {
        float mu = sums[c] * invN;
        float var = sums[Cc + c] * invN - mu * mu;
        float sc = g[c] * rsqrtf(var + 1e-5f);
        ss[c] = sc;
        ss[Cc + c] = bt[c] - mu * sc;
    }
}

__global__ void bnapply_kernel(float* __restrict__ buf, const float* __restrict__ ss,
                               int total, int cmask, int Cc) {
    int i = blockIdx.x * 256 + threadIdx.x;
    if (i >= total) return;
    int c = i & cmask;
    float v = buf[i] * ss[c] + ss[Cc + c];
    buf[i] = v > 0.f ? v : (__expf(v) - 1.0f);   // ELU
}

// ---------------- global mean pool ----------------

__global__ void pool_kernel(const float* __restrict__ h, const int* __restrict__ batch,
                            float* __restrict__ pooled, float* __restrict__ cnt, int N) {
    int i = blockIdx.x * 256 + threadIdx.x;
    if (i >= N * 64) return;
    int n = i >> 6, c = i & 63;
    int g = batch[n];
    atomicAdd(&pooled[g * 64 + c], h[i]);
    if (c == 0) atomicAdd(&cnt[g], 1.0f);
}

// ---------------- MLP head (single block) ----------------

__global__ __launch_bounds__(256) void mlp_kernel(const float* __restrict__ pooled,
                                                  const float* __restrict__ cnt,
                                                  const float* __restrict__ fw1, const float* __restrict__ fb1,
                                                  const float* __restrict__ fw2, const float* __restrict__ fb2,
                                                  const float* __restrict__ fw3, const float* __restrict__ fb3,
                                                  float* __restrict__ out) {
    __shared__ float pm[64 * 64];
    __shared__ float z1[64 * 128];
    __shared__ float z2[64 * 32];
    int t = threadIdx.x;
    for (int i = t; i < 64 * 64; i += 256) {
        int r = i >> 6;
        pm[i] = pooled[i] / fmaxf(cnt[r], 1.0f);
    }
    __syncthreads();
    for (int i = t; i < 64 * 128; i += 256) {
        int r = i >> 7, j = i & 127;
        float s = fb1[j];
        for (int k = 0; k < 64; k++) s += pm[r * 64 + k] * fw1[k * 128 + j];
        z1[i] = s > 0.f ? s : NEG_SLOPE * s;
    }
    __syncthreads();
    for (int i = t; i < 64 * 32; i += 256) {
        int r = i >> 5, j = i & 31;
        float s = fb2[j];
        for (int k = 0; k < 128; k++) s += z1[r * 128 + k] * fw2[k * 32 + j];
        z2[i] = s > 0.f ? s : NEG_SLOPE * s;
    }
    __syncthreads();
    for (int i = t; i < 64 * 2; i += 256) {
        int r = i >> 1, j = i & 1;
        float s = fb3[j];
        for (int k = 0; k < 32; k++) s += z2[r * 32 + k] * fw3[k * 2 + j];
        out[i] = s;
    }
}

// ---------------- launch ----------------

extern "C" void kernel_launch(void* const* d_in, const int* in_sizes, int n_in,
                              void* d_out, int out_size, void* d_ws, size_t ws_size,
                              hipStream_t stream) {
    const float* x   = (const float*)d_in[0];
    const int*   ei  = (const int*)d_in[1];
    const int*   batch = (const int*)d_in[2];
    const float* W1  = (const float*)d_in[3];
    const float* as1 = (const float*)d_in[4];
    const float* ad1 = (const float*)d_in[5];
    const float* b1  = (const float*)d_in[6];
    const float* W2  = (const float*)d_in[7];
    const float* as2 = (const float*)d_in[8];
    const float* ad2 = (const float*)d_in[9];
    const float* b2  = (const float*)d_in[10];
    const float* W3  = (const float*)d_in[11];
    const float* as3 = (const float*)d_in[12];
    const float* ad3 = (const float*)d_in[13];
    const float* b3  = (const float*)d_in[14];
    const float* g1  = (const float*)d_in[15];
    const float* bt1 = (const float*)d_in[16];
    const float* g2  = (const float*)d_in[17];
    const float* bt2 = (const float*)d_in[18];
    const float* g3  = (const float*)d_in[19];
    const float* bt3 = (const float*)d_in[20];
    const float* fw1 = (const float*)d_in[21];
    const float* fb1 = (const float*)d_in[22];
    const float* fw2 = (const float*)d_in[23];
    const float* fb2 = (const float*)d_in[24];
    const float* fw3 = (const float*)d_in[25];
    const float* fb3 = (const float*)d_in[26];

    const int N = in_sizes[0] / 128;
    const int E = in_sizes[1] / 2;
    const int* srcv = ei;
    const int* dstv = ei + E;

    // workspace layout
    float* fws   = (float*)d_ws;
    float* hA    = fws;                            // N*256
    float* hB    = hA + (size_t)N * 256;           // N*256
    float* a_s   = hB + (size_t)N * 256;           // N*4
    float* a_d   = a_s + (size_t)N * 4;            // N*4
    float* bnsum = a_d + (size_t)N * 4;            // 512
    float* bnss  = bnsum + 512;                    // 512
    float* pooled= bnss + 512;                     // 4096
    float* cnt   = pooled + 4096;                  // 64
    int*   deg   = (int*)(cnt + 64);               // N
    int*   offs  = deg + N;                        // N+1
    int*   curs  = offs + N + 1;                   // N
    int*   csrc  = curs + N;                       // E

    // --- build CSR by dst (reused across all 3 layers) ---
    hipMemsetAsync(deg, 0, (size_t)N * 4, stream);
    deg_kernel<<<(E + 255) / 256, 256, 0, stream>>>(dstv, deg, E);
    scan_kernel<<<1, 256, 0, stream>>>(deg, offs, curs, N);
    fill_kernel<<<(E + 255) / 256, 256, 0, stream>>>(srcv, dstv, curs, csrc, E);

    dim3 blk(256);

    // --- layer 1: 128 -> 4x64 ---
    {
        dim3 grid((N + 63) / 64, 256 / 64);
        gemm_kernel<<<grid, blk, 0, stream>>>(x, W1, hA, N, 128, 256);
        scores_kernel<<<(N * 4 + 255) / 256, blk, 0, stream>>>(hA, as1, ad1, a_s, a_d, N, 4, 64);
        agg_kernel<4, 64, 4><<<(N + 3) / 4, blk, 0, stream>>>(hA, a_s, a_d, offs, csrc, b1, hB, N);
        hipMemsetAsync(bnsum, 0, 2 * 256 * 4, stream);
        bnstats_kernel<<<256, blk, 0, stream>>>(hB, bnsum, N, 256);
        bnfinal_kernel<<<1, blk, 0, stream>>>(bnsum, g1, bt1, bnss, 1.0f / N, 256);
        bnapply_kernel<<<((size_t)N * 256 + 255) / 256, blk, 0, stream>>>(hB, bnss, N * 256, 255, 256);
    }
    // --- layer 2: 256 -> 4x32 ---
    {
        dim3 grid((N + 63) / 64, 128 / 64);
        gemm_kernel<<<grid, blk, 0, stream>>>(hB, W2, hA, N, 256, 128);
        scores_kernel<<<(N * 4 + 255) / 256, blk, 0, stream>>>(hA, as2, ad2, a_s, a_d, N, 4, 32);
        agg_kernel<4, 32, 2><<<(N + 3) / 4, blk, 0, stream>>>(hA, a_s, a_d, offs, csrc, b2, hB, N);
        hipMemsetAsync(bnsum, 0, 2 * 128 * 4, stream);
        bnstats_kernel<<<256, blk, 0, stream>>>(hB, bnsum, N, 128);
        bnfinal_kernel<<<1, blk, 0, stream>>>(bnsum, g2, bt2, bnss, 1.0f / N, 128);
        bnapply_kernel<<<((size_t)N * 128 + 255) / 256, blk, 0, stream>>>(hB, bnss, N * 128, 127, 128);
    }
    // --- layer 3: 128 -> 1x64 (mean over 1 head = identity) ---
    {
        dim3 grid((N + 63) / 64, 64 / 64);
        gemm_kernel<<<grid, blk, 0, stream>>>(hB, W3, hA, N, 128, 64);
        scores_kernel<<<(N + 255) / 256, blk, 0, stream>>>(hA, as3, ad3, a_s, a_d, N, 1, 64);
        agg_kernel<1, 64, 1><<<(N + 3) / 4, blk, 0, stream>>>(hA, a_s, a_d, offs, csrc, b3, hB, N);
        hipMemsetAsync(bnsum, 0, 2 * 64 * 4, stream);
        bnstats_kernel<<<256, blk, 0, stream>>>(hB, bnsum, N, 64);
        bnfinal_kernel<<<1, blk, 0, stream>>>(bnsum, g3, bt3, bnss, 1.0f / N, 64);
        bnapply_kernel<<<((size_t)N * 64 + 255) / 256, blk, 0, stream>>>(hB, bnss, N * 64, 63, 64);
    }

    // --- global mean pool + MLP head ---
    hipMemsetAsync(pooled, 0, (4096 + 64) * 4, stream);
    pool_kernel<<<((size_t)N * 64 + 255) / 256, blk, 0, stream>>>(hB, batch, pooled, cnt, N);
    mlp_kernel<<<1, blk, 0, stream>>>(pooled, cnt, fw1, fb1, fw2, fb2, fw3, fb3, (float*)d_out);
}

// Round 2
// 1078.518 us; speedup vs baseline: 1.3193x; 1.3193x over previous
//
#include <hip/hip_runtime.h>
#include <math.h>

#define NEG_SLOPE 0.2f

// ---------------- CSR build ----------------

__global__ void deg_kernel(const int* __restrict__ dst, int* __restrict__ deg, int E) {
    int i = blockIdx.x * 256 + threadIdx.x;
    if (i < E) atomicAdd(&deg[dst[i]], 1);
}

__global__ void scan_kernel(const int* __restrict__ deg, int* __restrict__ offs,
                            int* __restrict__ curs, int n) {
    __shared__ int tmp[256];
    __shared__ int carrysh;
    int t = threadIdx.x;
    if (t == 0) { carrysh = 0; offs[0] = 0; }
    __syncthreads();
    const int PER = 16;
    for (int base = 0; base < n; base += 256 * PER) {
        int loc[PER]; int s = 0;
        int b0 = base + t * PER;
#pragma unroll
        for (int k = 0; k < PER; k++) {
            int idx = b0 + k;
            int v = (idx < n) ? deg[idx] : 0;
            loc[k] = v; s += v;
        }
        tmp[t] = s; __syncthreads();
        for (int off = 1; off < 256; off <<= 1) {
            int x = (t >= off) ? tmp[t - off] : 0;
            __syncthreads();
            tmp[t] += x;
            __syncthreads();
        }
        int carry = carrysh;
        int pre = carry + tmp[t] - s;   // exclusive prefix of this thread's segment
#pragma unroll
        for (int k = 0; k < PER; k++) {
            int idx = b0 + k;
            if (idx < n) {
                curs[idx] = pre;
                offs[idx + 1] = pre + loc[k];
                pre += loc[k];
            }
        }
        __syncthreads();
        if (t == 255) carrysh = carry + tmp[255];
        __syncthreads();
    }
}

__global__ void fill_kernel(const int* __restrict__ src, const int* __restrict__ dst,
                            int* __restrict__ curs, int* __restrict__ csrc, int E) {
    int i = blockIdx.x * 256 + threadIdx.x;
    if (i < E) {
        int d = dst[i];
        int p = atomicAdd(&curs[d], 1);
        csrc[p] = src[i];
    }
}

// ---------------- fp32 GEMM: Y[M,Nout] = X[M,K] @ W[K,Nout] ----------------
// K multiple of 16, Nout multiple of 64.

__global__ __launch_bounds__(256) void gemm_kernel(const float* __restrict__ X,
                                                   const float* __restrict__ W,
                                                   float* __restrict__ Y,
                                                   int M, int K, int Nout) {
    __shared__ float As[16][68];   // transposed A tile, padded
    __shared__ float Bs[16][64];
    int tid = threadIdx.x;
    int bm = blockIdx.x * 64;
    int bn = blockIdx.y * 64;
    int tx = tid & 15, ty = tid >> 4;
    float acc[4][4] = {};
    int lr = tid >> 2;            // A-load row within tile
    int lk = (tid & 3) * 4;       // A-load k offset
    int wr = tid >> 4;            // B-load k row
    int wc = (tid & 15) * 4;      // B-load col
    for (int k0 = 0; k0 < K; k0 += 16) {
        float4 av = make_float4(0.f, 0.f, 0.f, 0.f);
        int row = bm + lr;
        if (row < M) av = *(const float4*)(X + (size_t)row * K + k0 + lk);
        As[lk + 0][lr] = av.x; As[lk + 1][lr] = av.y;
        As[lk + 2][lr] = av.z; As[lk + 3][lr] = av.w;
        *(float4*)&Bs[wr][wc] = *(const float4*)(W + (size_t)(k0 + wr) * Nout + bn + wc);
        __syncthreads();
#pragma unroll
        for (int kk = 0; kk < 16; kk++) {
            float4 a4 = *(const float4*)&As[kk][ty * 4];
            float4 b4 = *(const float4*)&Bs[kk][tx * 4];
            float a[4] = {a4.x, a4.y, a4.z, a4.w};
            float b[4] = {b4.x, b4.y, b4.z, b4.w};
#pragma unroll
            for (int i = 0; i < 4; i++)
#pragma unroll
                for (int j = 0; j < 4; j++) acc[i][j] += a[i] * b[j];
        }
        __syncthreads();
    }
#pragma unroll
    for (int i = 0; i < 4; i++) {
        int row = bm + ty * 4 + i;
        if (row < M) {
            float4 v = make_float4(acc[i][0], acc[i][1], acc[i][2], acc[i][3]);
            *(float4*)(Y + (size_t)row * Nout + bn + tx * 4) = v;
        }
    }
}

// ---------------- attention scores a_s[n,h], a_d[n,h] ----------------

__global__ void scores_kernel(const float* __restrict__ h, const float* __restrict__ att_s,
                              const float* __restrict__ att_d,
                              float* __restrict__ a_s, float* __restrict__ a_d,
                              int N, int H, int C) {
    int id = blockIdx.x * 256 + threadIdx.x;
    if (id >= N * H) return;
    int n = id / H, hh = id % H;
    const float* hp = h + (size_t)n * H * C + hh * C;
    float ss = 0.f, sd = 0.f;
    for (int c = 0; c < C; c++) {
        float v = hp[c];
        ss += v * att_s[hh * C + c];
        sd += v * att_d[hh * C + c];
    }
    a_s[id] = ss; a_d[id] = sd;
}

// ---------------- per-node GAT aggregation (wave per node) ----------------
// out[n, :] = sum_e softmax-weighted h[src_e, :] + bias ; self-loop included.

template <int H, int C, int CPL>
__global__ __launch_bounds__(256) void agg_kernel(const float* __restrict__ h,
                                                  const float* __restrict__ a_s,
                                                  const float* __restrict__ a_d,
                                                  const int* __restrict__ offs,
                                                  const int* __restrict__ csrc,
                                                  const float* __restrict__ bias,
                                                  float* __restrict__ out, int N) {
    const int HC = H * C;
    int lane = threadIdx.x & 63;
    int wid = threadIdx.x >> 6;
    int node = blockIdx.x * 4 + wid;
    if (node >= N) return;
    int off = offs[node];
    int deg = offs[node + 1] - off;
    int mych = lane * CPL;
    int myhead = mych / C;

    float adl[H];
#pragma unroll
    for (int hh = 0; hh < H; hh++) adl[hh] = a_d[node * H + hh];

    // pass 1: segment max per head (self-loop as init)
    float mx[H];
#pragma unroll
    for (int hh = 0; hh < H; hh++) {
        float sc = a_s[node * H + hh] + adl[hh];
        mx[hh] = sc > 0.f ? sc : NEG_SLOPE * sc;
    }
    for (int i = lane; i < deg; i += 64) {
        int s = csrc[off + i];
#pragma unroll
        for (int hh = 0; hh < H; hh++) {
            float sc = a_s[s * H + hh] + adl[hh];
            sc = sc > 0.f ? sc : NEG_SLOPE * sc;
            mx[hh] = fmaxf(mx[hh], sc);
        }
    }
#pragma unroll
    for (int hh = 0; hh < H; hh++) {
#pragma unroll
        for (int d = 32; d >= 1; d >>= 1)
            mx[hh] = fmaxf(mx[hh], __shfl_xor(mx[hh], d, 64));
    }

    float m_me = mx[myhead];
    float ad_me = adl[myhead];
    float den = 1e-16f;
    float acc[CPL];
#pragma unroll
    for (int k = 0; k < CPL; k++) acc[k] = 0.f;

    // self loop
    {
        float sc = a_s[node * H + myhead] + ad_me;
        sc = sc > 0.f ? sc : NEG_SLOPE * sc;
        float w = __expf(sc - m_me);
        den += w;
        const float* hp = h + (size_t)node * HC + mych;
        if (CPL == 4) {
            float4 v = *(const float4*)hp;
            acc[0] += w * v.x; acc[1] += w * v.y; acc[2] += w * v.z; acc[3] += w * v.w;
        } else if (CPL == 2) {
            float2 v = *(const float2*)hp;
            acc[0] += w * v.x; acc[1] += w * v.y;
        } else {
            acc[0] += w * hp[0];
        }
    }
    // incoming edges (serial over edges, wave-wide over channels)
    for (int e = 0; e < deg; e++) {
        int s = csrc[off + e];
        float sc = a_s[s * H + myhead] + ad_me;
        sc = sc > 0.f ? sc : NEG_SLOPE * sc;
        float w = __expf(sc - m_me);
        den += w;
        const float* hp = h + (size_t)s * HC + mych;
        if (CPL == 4) {
            float4 v = *(const float4*)hp;
            acc[0] += w * v.x; acc[1] += w * v.y; acc[2] += w * v.z; acc[3] += w * v.w;
        } else if (CPL == 2) {
            float2 v = *(const float2*)hp;
            acc[0] += w * v.x; acc[1] += w * v.y;
        } else {
            acc[0] += w * hp[0];
        }
    }
    float inv = 1.0f / den;
#pragma unroll
    for (int k = 0; k < CPL; k++)
        out[(size_t)node * HC + mych + k] = acc[k] * inv + bias[mych + k];
}

// ---------------- batch norm ----------------

__global__ void bnstats_kernel(const float* __restrict__ buf, float* __restrict__ sums,
                               int N, int Cc) {
    int t = threadIdx.x;
    int c = t % Cc;
    int rpb = 256 / Cc;
    int row = blockIdx.x * rpb + t / Cc;
    int stride = gridDim.x * rpb;
    float s = 0.f, s2 = 0.f;
    for (int n = row; n < N; n += stride) {
        float v = buf[(size_t)n * Cc + c];
        s += v; s2 += v * v;
    }
    atomicAdd(&sums[c], s);
    atomicAdd(&sums[Cc + c], s2);
}

__global__ void bnfinal_kernel(const float* __restrict__ sums, const float* __restrict__ g,
                               const float* __restrict__ bt, float* __restrict__ ss,
                               float invN, int Cc) {
    int c = threadIdx.x;
    if (c < Cc) {
        float mu = sums[c] * invN;
        float var = sums[Cc + c] * invN - mu * mu;
        float sc = g[c] * rsqrtf(var + 1e-5f);
        ss[c] = sc;
        ss[Cc + c] = bt[c] - mu * sc;
    }
}

__global__ void bnapply_kernel(float* __restrict__ buf, const float* __restrict__ ss,
                               int total, int cmask, int Cc) {
    int i = blockIdx.x * 256 + threadIdx.x;
    if (i >= total) return;
    int c = i & cmask;
    float v = buf[i] * ss[c] + ss[Cc + c];
    buf[i] = v > 0.f ? v : (__expf(v) - 1.0f);   // ELU
}

// ---------------- global mean pool: one block per graph (batch is sorted) ----

__global__ __launch_bounds__(256) void pool_kernel(const float* __restrict__ h,
                                                   const int* __restrict__ batch,
                                                   float* __restrict__ pooled, int N) {
    int g = blockIdx.x;
    int t = threadIdx.x;
    // lower_bound(g), lower_bound(g+1) in sorted batch[]
    int lo = 0, hi = N;
    while (lo < hi) { int mid = (lo + hi) >> 1; if (batch[mid] < g) lo = mid + 1; else hi = mid; }
    int s = lo;
    hi = N;
    while (lo < hi) { int mid = (lo + hi) >> 1; if (batch[mid] < g + 1) lo = mid + 1; else hi = mid; }
    int e = lo;

    int c = t & 63, rr = t >> 6;          // 4 rows in parallel, 64 channels
    float acc = 0.f;
    for (int n = s + rr; n < e; n += 4)
        acc += h[(size_t)n * 64 + c];
    __shared__ float red[256];
    red[t] = acc;
    __syncthreads();
    if (t < 128) red[t] += red[t + 128];
    __syncthreads();
    if (t < 64) {
        float v = red[t] + red[t + 64];
        float cntf = (float)(e - s);
        pooled[g * 64 + t] = v / fmaxf(cntf, 1.0f);   // already averaged
    }
}

// ---------------- MLP head (single block) ----------------

__global__ __launch_bounds__(256) void mlp_kernel(const float* __restrict__ pooled,
                                                  const float* __restrict__ fw1, const float* __restrict__ fb1,
                                                  const float* __restrict__ fw2, const float* __restrict__ fb2,
                                                  const float* __restrict__ fw3, const float* __restrict__ fb3,
                                                  float* __restrict__ out) {
    __shared__ float pm[64 * 64];
    __shared__ float z1[64 * 128];
    __shared__ float z2[64 * 32];
    int t = threadIdx.x;
    for (int i = t; i < 64 * 64; i += 256) pm[i] = pooled[i];
    __syncthreads();
    for (int i = t; i < 64 * 128; i += 256) {
        int r = i >> 7, j = i & 127;
        float s = fb1[j];
        for (int k = 0; k < 64; k++) s += pm[r * 64 + k] * fw1[k * 128 + j];
        z1[i] = s > 0.f ? s : NEG_SLOPE * s;
    }
    __syncthreads();
    for (int i = t; i < 64 * 32; i += 256) {
        int r = i >> 5, j = i & 31;
        float s = fb2[j];
        for (int k = 0; k < 128; k++) s += z1[r * 128 + k] * fw2[k * 32 + j];
        z2[i] = s > 0.f ? s : NEG_SLOPE * s;
    }
    __syncthreads();
    for (int i = t; i < 64 * 2; i += 256) {
        int r = i >> 1, j = i & 1;
        float s = fb3[j];
        for (int k = 0; k < 32; k++) s += z2[r * 32 + k] * fw3[k * 2 + j];
        out[i] = s;
    }
}

// ---------------- launch ----------------

extern "C" void kernel_launch(void* const* d_in, const int* in_sizes, int n_in,
                              void* d_out, int out_size, void* d_ws, size_t ws_size,
                              hipStream_t stream) {
    const float* x   = (const float*)d_in[0];
    const int*   ei  = (const int*)d_in[1];
    const int*   batch = (const int*)d_in[2];
    const float* W1  = (const float*)d_in[3];
    const float* as1 = (const float*)d_in[4];
    const float* ad1 = (const float*)d_in[5];
    const float* b1  = (const float*)d_in[6];
    const float* W2  = (const float*)d_in[7];
    const float* as2 = (const float*)d_in[8];
    const float* ad2 = (const float*)d_in[9];
    const float* b2  = (const float*)d_in[10];
    const float* W3  = (const float*)d_in[11];
    const float* as3 = (const float*)d_in[12];
    const float* ad3 = (const float*)d_in[13];
    const float* b3  = (const float*)d_in[14];
    const float* g1  = (const float*)d_in[15];
    const float* bt1 = (const float*)d_in[16];
    const float* g2  = (const float*)d_in[17];
    const float* bt2 = (const float*)d_in[18];
    const float* g3  = (const float*)d_in[19];
    const float* bt3 = (const float*)d_in[20];
    const float* fw1 = (const float*)d_in[21];
    const float* fb1 = (const float*)d_in[22];
    const float* fw2 = (const float*)d_in[23];
    const float* fb2 = (const float*)d_in[24];
    const float* fw3 = (const float*)d_in[25];
    const float* fb3 = (const float*)d_in[26];

    const int N = in_sizes[0] / 128;
    const int E = in_sizes[1] / 2;
    const int* srcv = ei;
    const int* dstv = ei + E;

    // workspace layout
    float* fws   = (float*)d_ws;
    float* hA    = fws;                            // N*256
    float* hB    = hA + (size_t)N * 256;           // N*256
    float* a_s   = hB + (size_t)N * 256;           // N*4
    float* a_d   = a_s + (size_t)N * 4;            // N*4
    float* bnsum = a_d + (size_t)N * 4;            // 512
    float* bnss  = bnsum + 512;                    // 512
    float* pooled= bnss + 512;                     // 4096
    float* cnt   = pooled + 4096;                  // 64 (unused now)
    int*   deg   = (int*)(cnt + 64);               // N
    int*   offs  = deg + N;                        // N+1
    int*   curs  = offs + N + 1;                   // N
    int*   csrc  = curs + N;                       // E

    // --- build CSR by dst (reused across all 3 layers) ---
    hipMemsetAsync(deg, 0, (size_t)N * 4, stream);
    deg_kernel<<<(E + 255) / 256, 256, 0, stream>>>(dstv, deg, E);
    scan_kernel<<<1, 256, 0, stream>>>(deg, offs, curs, N);
    fill_kernel<<<(E + 255) / 256, 256, 0, stream>>>(srcv, dstv, curs, csrc, E);

    dim3 blk(256);

    // --- layer 1: 128 -> 4x64 ---
    {
        dim3 grid((N + 63) / 64, 256 / 64);
        gemm_kernel<<<grid, blk, 0, stream>>>(x, W1, hA, N, 128, 256);
        scores_kernel<<<(N * 4 + 255) / 256, blk, 0, stream>>>(hA, as1, ad1, a_s, a_d, N, 4, 64);
        agg_kernel<4, 64, 4><<<(N + 3) / 4, blk, 0, stream>>>(hA, a_s, a_d, offs, csrc, b1, hB, N);
        hipMemsetAsync(bnsum, 0, 2 * 256 * 4, stream);
        bnstats_kernel<<<256, blk, 0, stream>>>(hB, bnsum, N, 256);
        bnfinal_kernel<<<1, blk, 0, stream>>>(bnsum, g1, bt1, bnss, 1.0f / N, 256);
        bnapply_kernel<<<((size_t)N * 256 + 255) / 256, blk, 0, stream>>>(hB, bnss, N * 256, 255, 256);
    }
    // --- layer 2: 256 -> 4x32 ---
    {
        dim3 grid((N + 63) / 64, 128 / 64);
        gemm_kernel<<<grid, blk, 0, stream>>>(hB, W2, hA, N, 256, 128);
        scores_kernel<<<(N * 4 + 255) / 256, blk, 0, stream>>>(hA, as2, ad2, a_s, a_d, N, 4, 32);
        agg_kernel<4, 32, 2><<<(N + 3) / 4, blk, 0, stream>>>(hA, a_s, a_d, offs, csrc, b2, hB, N);
        hipMemsetAsync(bnsum, 0, 2 * 128 * 4, stream);
        bnstats_kernel<<<256, blk, 0, stream>>>(hB, bnsum, N, 128);
        bnfinal_kernel<<<1, blk, 0, stream>>>(bnsum, g2, bt2, bnss, 1.0f / N, 128);
        bnapply_kernel<<<((size_t)N * 128 + 255) / 256, blk, 0, stream>>>(hB, bnss, N * 128, 127, 128);
    }
    // --- layer 3: 128 -> 1x64 (mean over 1 head = identity) ---
    {
        dim3 grid((N + 63) / 64, 64 / 64);
        gemm_kernel<<<grid, blk, 0, stream>>>(hB, W3, hA, N, 128, 64);
        scores_kernel<<<(N + 255) / 256, blk, 0, stream>>>(hA, as3, ad3, a_s, a_d, N, 1, 64);
        agg_kernel<1, 64, 1><<<(N + 3) / 4, blk, 0, stream>>>(hA, a_s, a_d, offs, csrc, b3, hB, N);
        hipMemsetAsync(bnsum, 0, 2 * 64 * 4, stream);
        bnstats_kernel<<<256, blk, 0, stream>>>(hB, bnsum, N, 64);
        bnfinal_kernel<<<1, blk, 0, stream>>>(bnsum, g3, bt3, bnss, 1.0f / N, 64);
        bnapply_kernel<<<((size_t)N * 64 + 255) / 256, blk, 0, stream>>>(hB, bnss, N * 64, 63, 64);
    }

    // --- global mean pool (no atomics; batch sorted) + MLP head ---
    pool_kernel<<<64, blk, 0, stream>>>(hB, batch, pooled, N);
    mlp_kernel<<<1, blk, 0, stream>>>(pooled, fw1, fb1, fw2, fb2, fw3, fb3, (float*)d_out);
}

// Round 3
// 921.979 us; speedup vs baseline: 1.5433x; 1.1698x over previous
//
#include <hip/hip_runtime.h>
#include <math.h>

#define NEG_SLOPE 0.2f

// ---------------- CSR build ----------------

__global__ void deg_kernel(const int* __restrict__ dst, int* __restrict__ deg, int E) {
    int i = blockIdx.x * 256 + threadIdx.x;
    if (i < E) atomicAdd(&deg[dst[i]], 1);
}

__global__ void scan_kernel(const int* __restrict__ deg, int* __restrict__ offs,
                            int* __restrict__ curs, int n) {
    __shared__ int tmp[256];
    __shared__ int carrysh;
    int t = threadIdx.x;
    if (t == 0) { carrysh = 0; offs[0] = 0; }
    __syncthreads();
    const int PER = 16;
    for (int base = 0; base < n; base += 256 * PER) {
        int loc[PER]; int s = 0;
        int b0 = base + t * PER;
#pragma unroll
        for (int k = 0; k < PER; k++) {
            int idx = b0 + k;
            int v = (idx < n) ? deg[idx] : 0;
            loc[k] = v; s += v;
        }
        tmp[t] = s; __syncthreads();
        for (int off = 1; off < 256; off <<= 1) {
            int x = (t >= off) ? tmp[t - off] : 0;
            __syncthreads();
            tmp[t] += x;
            __syncthreads();
        }
        int carry = carrysh;
        int pre = carry + tmp[t] - s;   // exclusive prefix of this thread's segment
#pragma unroll
        for (int k = 0; k < PER; k++) {
            int idx = b0 + k;
            if (idx < n) {
                curs[idx] = pre;
                offs[idx + 1] = pre + loc[k];
                pre += loc[k];
            }
        }
        __syncthreads();
        if (t == 255) carrysh = carry + tmp[255];
        __syncthreads();
    }
}

__global__ void fill_kernel(const int* __restrict__ src, const int* __restrict__ dst,
                            int* __restrict__ curs, int* __restrict__ csrc, int E) {
    int i = blockIdx.x * 256 + threadIdx.x;
    if (i < E) {
        int d = dst[i];
        int p = atomicAdd(&curs[d], 1);
        csrc[p] = src[i];
    }
}

// ---------------- fp32 GEMM: Y[M,Nout] = X[M,K] @ W[K,Nout] ----------------
// 128x64 tile, 8x4 acc per thread. K multiple of 16, Nout multiple of 64.

__global__ __launch_bounds__(256) void gemm_kernel(const float* __restrict__ X,
                                                   const float* __restrict__ W,
                                                   float* __restrict__ Y,
                                                   int M, int K, int Nout) {
    __shared__ float As[16][132];   // [k][m], 132*4=528B rows keep float4 alignment
    __shared__ float Bs[16][64];
    int tid = threadIdx.x;
    int bm = blockIdx.x * 128;
    int bn = blockIdx.y * 64;
    int tx = tid & 15, ty = tid >> 4;
    float acc[8][4] = {};
    int ar0 = tid >> 2;            // A rows ar0, ar0+64
    int ak  = (tid & 3) * 4;       // A k offset
    int wr  = tid >> 4;            // B k row
    int wc  = (tid & 15) * 4;      // B col
    for (int k0 = 0; k0 < K; k0 += 16) {
        float4 a0 = make_float4(0.f, 0.f, 0.f, 0.f);
        float4 a1 = make_float4(0.f, 0.f, 0.f, 0.f);
        int r0 = bm + ar0, r1 = r0 + 64;
        if (r0 < M) a0 = *(const float4*)(X + (size_t)r0 * K + k0 + ak);
        if (r1 < M) a1 = *(const float4*)(X + (size_t)r1 * K + k0 + ak);
        As[ak + 0][ar0] = a0.x; As[ak + 1][ar0] = a0.y;
        As[ak + 2][ar0] = a0.z; As[ak + 3][ar0] = a0.w;
        As[ak + 0][ar0 + 64] = a1.x; As[ak + 1][ar0 + 64] = a1.y;
        As[ak + 2][ar0 + 64] = a1.z; As[ak + 3][ar0 + 64] = a1.w;
        *(float4*)&Bs[wr][wc] = *(const float4*)(W + (size_t)(k0 + wr) * Nout + bn + wc);
        __syncthreads();
#pragma unroll
        for (int kk = 0; kk < 16; kk++) {
            float4 al = *(const float4*)&As[kk][ty * 8];
            float4 ah = *(const float4*)&As[kk][ty * 8 + 4];
            float4 b4 = *(const float4*)&Bs[kk][tx * 4];
            float a[8] = {al.x, al.y, al.z, al.w, ah.x, ah.y, ah.z, ah.w};
            float b[4] = {b4.x, b4.y, b4.z, b4.w};
#pragma unroll
            for (int i = 0; i < 8; i++)
#pragma unroll
                for (int j = 0; j < 4; j++) acc[i][j] += a[i] * b[j];
        }
        __syncthreads();
    }
#pragma unroll
    for (int i = 0; i < 8; i++) {
        int row = bm + ty * 8 + i;
        if (row < M) {
            float4 v = make_float4(acc[i][0], acc[i][1], acc[i][2], acc[i][3]);
            *(float4*)(Y + (size_t)row * Nout + bn + tx * 4) = v;
        }
    }
}

// ---------------- attention scores a_s[n,h], a_d[n,h] ----------------

__global__ void scores_kernel(const float* __restrict__ h, const float* __restrict__ att_s,
                              const float* __restrict__ att_d,
                              float* __restrict__ a_s, float* __restrict__ a_d,
                              int N, int H, int C) {
    int id = blockIdx.x * 256 + threadIdx.x;
    if (id >= N * H) return;
    int n = id / H, hh = id % H;
    const float* hp = h + (size_t)n * H * C + hh * C;
    float ss = 0.f, sd = 0.f;
    for (int c = 0; c < C; c += 4) {
        float4 v = *(const float4*)(hp + c);
        float4 s4 = *(const float4*)(att_s + hh * C + c);
        float4 d4 = *(const float4*)(att_d + hh * C + c);
        ss += v.x * s4.x + v.y * s4.y + v.z * s4.z + v.w * s4.w;
        sd += v.x * d4.x + v.y * d4.y + v.z * d4.z + v.w * d4.w;
    }
    a_s[id] = ss; a_d[id] = sd;
}

// ---------------- per-node GAT aggregation (wave per node) ----------------
// Single pass: softmax without max-subtraction (scores are O(10); exp safe in
// fp32; alpha mathematically identical). Phase A: edge-parallel score+exp,
// staged to LDS. Phase B: unrolled channel-parallel weighted gather.

template <int H, int C, int CPL>
__global__ __launch_bounds__(256) void agg_kernel(const float* __restrict__ h,
                                                  const float* __restrict__ a_s,
                                                  const float* __restrict__ a_d,
                                                  const int* __restrict__ offs,
                                                  const int* __restrict__ csrc,
                                                  const float* __restrict__ bias,
                                                  float* __restrict__ out, int N) {
    const int HC = H * C;
    __shared__ float wbuf[4][64 * H];
    __shared__ int   sbuf[4][64];
    int lane = threadIdx.x & 63;
    int wid  = threadIdx.x >> 6;
    int node = blockIdx.x * 4 + wid;
    if (node >= N) return;
    int off = offs[node];
    int deg = offs[node + 1] - off;
    int mych = lane * CPL;
    const int myhead = (CPL * 63) / C == 0 ? 0 : mych / C;   // compile-time simplifiable
    int mh = mych / C;

    float adl[H];
#pragma unroll
    for (int hh = 0; hh < H; hh++) adl[hh] = a_d[node * H + hh];

    // self loop contribution
    float acc[CPL];
    float sc_self = a_s[node * H + mh] + adl[mh];
    sc_self = sc_self > 0.f ? sc_self : NEG_SLOPE * sc_self;
    float w_self = __expf(sc_self);
    {
        const float* hp = h + (size_t)node * HC + mych;
        if (CPL == 4) {
            float4 v = *(const float4*)hp;
            acc[0] = w_self * v.x; acc[1] = w_self * v.y;
            acc[2] = w_self * v.z; acc[3] = w_self * v.w;
        } else if (CPL == 2) {
            float2 v = *(const float2*)hp;
            acc[0] = w_self * v.x; acc[1] = w_self * v.y;
        } else {
            acc[0] = w_self * hp[0];
        }
    }

    float denp[H];
#pragma unroll
    for (int hh = 0; hh < H; hh++) denp[hh] = 0.f;

    for (int base = 0; base < deg; base += 64) {
        int i = base + lane;
        if (i < deg) {
            int s = csrc[off + i];
            sbuf[wid][lane] = s;
            float asv[H];
            if (H == 4) {
                float4 t4 = *(const float4*)(a_s + (size_t)s * 4);
                asv[0] = t4.x; asv[1] = t4.y; asv[2] = t4.z; asv[3] = t4.w;
            } else {
                asv[0] = a_s[s];
            }
#pragma unroll
            for (int hh = 0; hh < H; hh++) {
                float sc = asv[hh] + adl[hh];
                sc = sc > 0.f ? sc : NEG_SLOPE * sc;
                float w = __expf(sc);
                wbuf[wid][lane * H + hh] = w;
                denp[hh] += w;
            }
        }
        asm volatile("s_waitcnt lgkmcnt(0)" ::: "memory");  // wave-local LDS visibility
        int cl = deg - base; if (cl > 64) cl = 64;
#pragma unroll 4
        for (int e = 0; e < cl; e++) {
            int s = sbuf[wid][e];
            float w = wbuf[wid][e * H + mh];
            const float* hp = h + (size_t)s * HC + mych;
            if (CPL == 4) {
                float4 v = *(const float4*)hp;
                acc[0] += w * v.x; acc[1] += w * v.y;
                acc[2] += w * v.z; acc[3] += w * v.w;
            } else if (CPL == 2) {
                float2 v = *(const float2*)hp;
                acc[0] += w * v.x; acc[1] += w * v.y;
            } else {
                acc[0] += w * hp[0];
            }
        }
    }
    // reduce den partials across the wave (each lane gets full per-head sums)
#pragma unroll
    for (int hh = 0; hh < H; hh++) {
#pragma unroll
        for (int d = 32; d >= 1; d >>= 1)
            denp[hh] += __shfl_xor(denp[hh], d, 64);
    }
    float inv = 1.0f / (denp[mh] + w_self + 1e-16f);
#pragma unroll
    for (int k = 0; k < CPL; k++)
        out[(size_t)node * HC + mych + k] = acc[k] * inv + bias[mych + k];
    (void)myhead;
}

// ---------------- batch norm ----------------

__global__ void bnstats_kernel(const float* __restrict__ buf, float* __restrict__ sums,
                               int N, int Cc) {
    int t = threadIdx.x;
    int c = t % Cc;
    int rpb = 256 / Cc;
    int row = blockIdx.x * rpb + t / Cc;
    int stride = gridDim.x * rpb;
    float s = 0.f, s2 = 0.f;
    for (int n = row; n < N; n += stride) {
        float v = buf[(size_t)n * Cc + c];
        s += v; s2 += v * v;
    }
    atomicAdd(&sums[c], s);
    atomicAdd(&sums[Cc + c], s2);
}

__global__ void bnfinal_kernel(const float* __restrict__ sums, const float* __restrict__ g,
                               const float* __restrict__ bt, float* __restrict__ ss,
                               float invN, int Cc) {
    int c = threadIdx.x;
    if (c < Cc) {
        float mu = sums[c] * invN;
        float var = sums[Cc + c] * invN - mu * mu;
        float sc = g[c] * rsqrtf(var + 1e-5f);
        ss[c] = sc;
        ss[Cc + c] = bt[c] - mu * sc;
    }
}

__global__ void bnapply_kernel(float* __restrict__ buf, const float* __restrict__ ss,
                               int total, int cmask, int Cc) {
    int i = blockIdx.x * 256 + threadIdx.x;
    if (i >= total) return;
    int c = i & cmask;
    float v = buf[i] * ss[c] + ss[Cc + c];
    buf[i] = v > 0.f ? v : (__expf(v) - 1.0f);   // ELU
}

// ---------------- global mean pool: one block per graph (batch is sorted) ----

__global__ __launch_bounds__(256) void pool_kernel(const float* __restrict__ h,
                                                   const int* __restrict__ batch,
                                                   float* __restrict__ pooled, int N) {
    int g = blockIdx.x;
    int t = threadIdx.x;
    int lo = 0, hi = N;
    while (lo < hi) { int mid = (lo + hi) >> 1; if (batch[mid] < g) lo = mid + 1; else hi = mid; }
    int s = lo;
    hi = N;
    while (lo < hi) { int mid = (lo + hi) >> 1; if (batch[mid] < g + 1) lo = mid + 1; else hi = mid; }
    int e = lo;

    int c = t & 63, rr = t >> 6;
    float acc = 0.f;
    for (int n = s + rr; n < e; n += 4)
        acc += h[(size_t)n * 64 + c];
    __shared__ float red[256];
    red[t] = acc;
    __syncthreads();
    if (t < 128) red[t] += red[t + 128];
    __syncthreads();
    if (t < 64) {
        float v = red[t] + red[t + 64];
        float cntf = (float)(e - s);
        pooled[g * 64 + t] = v / fmaxf(cntf, 1.0f);
    }
}

// ---------------- MLP head (single block) ----------------

__global__ __launch_bounds__(256) void mlp_kernel(const float* __restrict__ pooled,
                                                  const float* __restrict__ fw1, const float* __restrict__ fb1,
                                                  const float* __restrict__ fw2, const float* __restrict__ fb2,
                                                  const float* __restrict__ fw3, const float* __restrict__ fb3,
                                                  float* __restrict__ out) {
    __shared__ float pm[64 * 64];
    __shared__ float z1[64 * 128];
    __shared__ float z2[64 * 32];
    int t = threadIdx.x;
    for (int i = t; i < 64 * 64; i += 256) pm[i] = pooled[i];
    __syncthreads();
    for (int i = t; i < 64 * 128; i += 256) {
        int r = i >> 7, j = i & 127;
        float s = fb1[j];
        for (int k = 0; k < 64; k++) s += pm[r * 64 + k] * fw1[k * 128 + j];
        z1[i] = s > 0.f ? s : NEG_SLOPE * s;
    }
    __syncthreads();
    for (int i = t; i < 64 * 32; i += 256) {
        int r = i >> 5, j = i & 31;
        float s = fb2[j];
        for (int k = 0; k < 128; k++) s += z1[r * 128 + k] * fw2[k * 32 + j];
        z2[i] = s > 0.f ? s : NEG_SLOPE * s;
    }
    __syncthreads();
    for (int i = t; i < 64 * 2; i += 256) {
        int r = i >> 1, j = i & 1;
        float s = fb3[j];
        for (int k = 0; k < 32; k++) s += z2[r * 32 + k] * fw3[k * 2 + j];
        out[i] = s;
    }
}

// ---------------- launch ----------------

extern "C" void kernel_launch(void* const* d_in, const int* in_sizes, int n_in,
                              void* d_out, int out_size, void* d_ws, size_t ws_size,
                              hipStream_t stream) {
    const float* x   = (const float*)d_in[0];
    const int*   ei  = (const int*)d_in[1];
    const int*   batch = (const int*)d_in[2];
    const float* W1  = (const float*)d_in[3];
    const float* as1 = (const float*)d_in[4];
    const float* ad1 = (const float*)d_in[5];
    const float* b1  = (const float*)d_in[6];
    const float* W2  = (const float*)d_in[7];
    const float* as2 = (const float*)d_in[8];
    const float* ad2 = (const float*)d_in[9];
    const float* b2  = (const float*)d_in[10];
    const float* W3  = (const float*)d_in[11];
    const float* as3 = (const float*)d_in[12];
    const float* ad3 = (const float*)d_in[13];
    const float* b3  = (const float*)d_in[14];
    const float* g1  = (const float*)d_in[15];
    const float* bt1 = (const float*)d_in[16];
    const float* g2  = (const float*)d_in[17];
    const float* bt2 = (const float*)d_in[18];
    const float* g3  = (const float*)d_in[19];
    const float* bt3 = (const float*)d_in[20];
    const float* fw1 = (const float*)d_in[21];
    const float* fb1 = (const float*)d_in[22];
    const float* fw2 = (const float*)d_in[23];
    const float* fb2 = (const float*)d_in[24];
    const float* fw3 = (const float*)d_in[25];
    const float* fb3 = (const float*)d_in[26];

    const int N = in_sizes[0] / 128;
    const int E = in_sizes[1] / 2;
    const int* srcv = ei;
    const int* dstv = ei + E;

    // workspace layout
    float* fws   = (float*)d_ws;
    float* hA    = fws;                            // N*256
    float* hB    = hA + (size_t)N * 256;           // N*256
    float* a_s   = hB + (size_t)N * 256;           // N*4
    float* a_d   = a_s + (size_t)N * 4;            // N*4
    float* bnsum = a_d + (size_t)N * 4;            // 512
    float* bnss  = bnsum + 512;                    // 512
    float* pooled= bnss + 512;                     // 4096
    float* cnt   = pooled + 4096;                  // 64 (unused)
    int*   deg   = (int*)(cnt + 64);               // N
    int*   offs  = deg + N;                        // N+1
    int*   curs  = offs + N + 1;                   // N
    int*   csrc  = curs + N;                       // E

    // --- build CSR by dst (reused across all 3 layers) ---
    hipMemsetAsync(deg, 0, (size_t)N * 4, stream);
    deg_kernel<<<(E + 255) / 256, 256, 0, stream>>>(dstv, deg, E);
    scan_kernel<<<1, 256, 0, stream>>>(deg, offs, curs, N);
    fill_kernel<<<(E + 255) / 256, 256, 0, stream>>>(srcv, dstv, curs, csrc, E);

    dim3 blk(256);

    // --- layer 1: 128 -> 4x64 ---
    {
        dim3 grid((N + 127) / 128, 256 / 64);
        gemm_kernel<<<grid, blk, 0, stream>>>(x, W1, hA, N, 128, 256);
        scores_kernel<<<(N * 4 + 255) / 256, blk, 0, stream>>>(hA, as1, ad1, a_s, a_d, N, 4, 64);
        agg_kernel<4, 64, 4><<<(N + 3) / 4, blk, 0, stream>>>(hA, a_s, a_d, offs, csrc, b1, hB, N);
        hipMemsetAsync(bnsum, 0, 2 * 256 * 4, stream);
        bnstats_kernel<<<256, blk, 0, stream>>>(hB, bnsum, N, 256);
        bnfinal_kernel<<<1, blk, 0, stream>>>(bnsum, g1, bt1, bnss, 1.0f / N, 256);
        bnapply_kernel<<<((size_t)N * 256 + 255) / 256, blk, 0, stream>>>(hB, bnss, N * 256, 255, 256);
    }
    // --- layer 2: 256 -> 4x32 ---
    {
        dim3 grid((N + 127) / 128, 128 / 64);
        gemm_kernel<<<grid, blk, 0, stream>>>(hB, W2, hA, N, 256, 128);
        scores_kernel<<<(N * 4 + 255) / 256, blk, 0, stream>>>(hA, as2, ad2, a_s, a_d, N, 4, 32);
        agg_kernel<4, 32, 2><<<(N + 3) / 4, blk, 0, stream>>>(hA, a_s, a_d, offs, csrc, b2, hB, N);
        hipMemsetAsync(bnsum, 0, 2 * 128 * 4, stream);
        bnstats_kernel<<<256, blk, 0, stream>>>(hB, bnsum, N, 128);
        bnfinal_kernel<<<1, blk, 0, stream>>>(bnsum, g2, bt2, bnss, 1.0f / N, 128);
        bnapply_kernel<<<((size_t)N * 128 + 255) / 256, blk, 0, stream>>>(hB, bnss, N * 128, 127, 128);
    }
    // --- layer 3: 128 -> 1x64 (mean over 1 head = identity) ---
    {
        dim3 grid((N + 127) / 128, 64 / 64);
        gemm_kernel<<<grid, blk, 0, stream>>>(hB, W3, hA, N, 128, 64);
        scores_kernel<<<(N + 255) / 256, blk, 0, stream>>>(hA, as3, ad3, a_s, a_d, N, 1, 64);
        agg_kernel<1, 64, 1><<<(N + 3) / 4, blk, 0, stream>>>(hA, a_s, a_d, offs, csrc, b3, hB, N);
        hipMemsetAsync(bnsum, 0, 2 * 64 * 4, stream);
        bnstats_kernel<<<256, blk, 0, stream>>>(hB, bnsum, N, 64);
        bnfinal_kernel<<<1, blk, 0, stream>>>(bnsum, g3, bt3, bnss, 1.0f / N, 64);
        bnapply_kernel<<<((size_t)N * 64 + 255) / 256, blk, 0, stream>>>(hB, bnss, N * 64, 63, 64);
    }

    // --- global mean pool (no atomics; batch sorted) + MLP head ---
    pool_kernel<<<64, blk, 0, stream>>>(hB, batch, pooled, N);
    mlp_kernel<<<1, blk, 0, stream>>>(pooled, fw1, fb1, fw2, fb2, fw3, fb3, (float*)d_out);
}

// Round 4
// 877.879 us; speedup vs baseline: 1.6208x; 1.0502x over previous
//
#include <hip/hip_runtime.h>
#include <hip/hip_fp16.h>
#include <math.h>

#define NEG_SLOPE 0.2f

// ---------------- CSR build ----------------

__global__ void deg_kernel(const int* __restrict__ dst, int* __restrict__ deg, int E) {
    int i = blockIdx.x * 256 + threadIdx.x;
    if (i < E) atomicAdd(&deg[dst[i]], 1);
}

__global__ void scan_kernel(const int* __restrict__ deg, int* __restrict__ offs,
                            int* __restrict__ curs, int n) {
    __shared__ int tmp[256];
    __shared__ int carrysh;
    int t = threadIdx.x;
    if (t == 0) { carrysh = 0; offs[0] = 0; }
    __syncthreads();
    const int PER = 16;
    for (int base = 0; base < n; base += 256 * PER) {
        int loc[PER]; int s = 0;
        int b0 = base + t * PER;
#pragma unroll
        for (int k = 0; k < PER; k++) {
            int idx = b0 + k;
            int v = (idx < n) ? deg[idx] : 0;
            loc[k] = v; s += v;
        }
        tmp[t] = s; __syncthreads();
        for (int off = 1; off < 256; off <<= 1) {
            int x = (t >= off) ? tmp[t - off] : 0;
            __syncthreads();
            tmp[t] += x;
            __syncthreads();
        }
        int carry = carrysh;
        int pre = carry + tmp[t] - s;
#pragma unroll
        for (int k = 0; k < PER; k++) {
            int idx = b0 + k;
            if (idx < n) {
                curs[idx] = pre;
                offs[idx + 1] = pre + loc[k];
                pre += loc[k];
            }
        }
        __syncthreads();
        if (t == 255) carrysh = carry + tmp[255];
        __syncthreads();
    }
}

__global__ void fill_kernel(const int* __restrict__ src, const int* __restrict__ dst,
                            int* __restrict__ curs, int* __restrict__ csrc, int E) {
    int i = blockIdx.x * 256 + threadIdx.x;
    if (i < E) {
        int d = dst[i];
        int p = atomicAdd(&curs[d], 1);
        csrc[p] = src[i];
    }
}

// ---------------- fp32 GEMM, fp16 output: Yh[M,Nout] = half(X[M,K] @ W[K,Nout]) --
// 128x64 tile, 8x4 acc per thread. K multiple of 16, Nout multiple of 64.

__global__ __launch_bounds__(256) void gemm_kernel(const float* __restrict__ X,
                                                   const float* __restrict__ W,
                                                   __half* __restrict__ Yh,
                                                   int M, int K, int Nout) {
    __shared__ float As[16][132];
    __shared__ float Bs[16][64];
    int tid = threadIdx.x;
    int bm = blockIdx.x * 128;
    int bn = blockIdx.y * 64;
    int tx = tid & 15, ty = tid >> 4;
    float acc[8][4] = {};
    int ar0 = tid >> 2;
    int ak  = (tid & 3) * 4;
    int wr  = tid >> 4;
    int wc  = (tid & 15) * 4;
    for (int k0 = 0; k0 < K; k0 += 16) {
        float4 a0 = make_float4(0.f, 0.f, 0.f, 0.f);
        float4 a1 = make_float4(0.f, 0.f, 0.f, 0.f);
        int r0 = bm + ar0, r1 = r0 + 64;
        if (r0 < M) a0 = *(const float4*)(X + (size_t)r0 * K + k0 + ak);
        if (r1 < M) a1 = *(const float4*)(X + (size_t)r1 * K + k0 + ak);
        As[ak + 0][ar0] = a0.x; As[ak + 1][ar0] = a0.y;
        As[ak + 2][ar0] = a0.z; As[ak + 3][ar0] = a0.w;
        As[ak + 0][ar0 + 64] = a1.x; As[ak + 1][ar0 + 64] = a1.y;
        As[ak + 2][ar0 + 64] = a1.z; As[ak + 3][ar0 + 64] = a1.w;
        *(float4*)&Bs[wr][wc] = *(const float4*)(W + (size_t)(k0 + wr) * Nout + bn + wc);
        __syncthreads();
#pragma unroll
        for (int kk = 0; kk < 16; kk++) {
            float4 al = *(const float4*)&As[kk][ty * 8];
            float4 ah = *(const float4*)&As[kk][ty * 8 + 4];
            float4 b4 = *(const float4*)&Bs[kk][tx * 4];
            float a[8] = {al.x, al.y, al.z, al.w, ah.x, ah.y, ah.z, ah.w};
            float b[4] = {b4.x, b4.y, b4.z, b4.w};
#pragma unroll
            for (int i = 0; i < 8; i++)
#pragma unroll
                for (int j = 0; j < 4; j++) acc[i][j] += a[i] * b[j];
        }
        __syncthreads();
    }
#pragma unroll
    for (int i = 0; i < 8; i++) {
        int row = bm + ty * 8 + i;
        if (row < M) {
            __half2 pk[2];
            pk[0] = __floats2half2_rn(acc[i][0], acc[i][1]);
            pk[1] = __floats2half2_rn(acc[i][2], acc[i][3]);
            *(uint2*)(Yh + (size_t)row * Nout + bn + tx * 4) = *(uint2*)pk;
        }
    }
}

// ---------------- attention scores a_s[n,h], a_d[n,h] (fp16 h) ----------------

__global__ void scores_kernel(const __half* __restrict__ h, const float* __restrict__ att_s,
                              const float* __restrict__ att_d,
                              float* __restrict__ a_s, float* __restrict__ a_d,
                              int N, int H, int C) {
    int id = blockIdx.x * 256 + threadIdx.x;
    if (id >= N * H) return;
    int n = id / H, hh = id % H;
    const __half* hp = h + (size_t)n * H * C + hh * C;
    float ss = 0.f, sd = 0.f;
    for (int c = 0; c < C; c += 2) {
        float2 v = __half22float2(*(const __half2*)(hp + c));
        float2 s2 = *(const float2*)(att_s + hh * C + c);
        float2 d2 = *(const float2*)(att_d + hh * C + c);
        ss += v.x * s2.x + v.y * s2.y;
        sd += v.x * d2.x + v.y * d2.y;
    }
    a_s[id] = ss; a_d[id] = sd;
}

// ---------------- per-node GAT aggregation (wave per node, fp16 gather) -------
// Single pass, no max-subtraction (scores O(10), exp safe in fp32).
// Phase A: edge-parallel score+exp staged to LDS. Phase B: weighted fp16 gather.

template <int H, int C, int CPL>
__global__ __launch_bounds__(256) void agg_kernel(const __half* __restrict__ h,
                                                  const float* __restrict__ a_s,
                                                  const float* __restrict__ a_d,
                                                  const int* __restrict__ offs,
                                                  const int* __restrict__ csrc,
                                                  const float* __restrict__ bias,
                                                  float* __restrict__ out, int N) {
    const int HC = H * C;
    __shared__ float wbuf[4][64 * H];
    __shared__ int   sbuf[4][64];
    int lane = threadIdx.x & 63;
    int wid  = threadIdx.x >> 6;
    int node = blockIdx.x * 4 + wid;
    if (node >= N) return;
    int off = offs[node];
    int deg = offs[node + 1] - off;
    int mych = lane * CPL;
    int mh = mych / C;

    float adl[H];
#pragma unroll
    for (int hh = 0; hh < H; hh++) adl[hh] = a_d[node * H + hh];

    // self loop contribution
    float acc[CPL];
    float sc_self = a_s[node * H + mh] + adl[mh];
    sc_self = sc_self > 0.f ? sc_self : NEG_SLOPE * sc_self;
    float w_self = __expf(sc_self);
    {
        const __half* hp = h + (size_t)node * HC + mych;
        if (CPL == 4) {
            uint2 raw = *(const uint2*)hp;
            float2 f0 = __half22float2(*(__half2*)&raw.x);
            float2 f1 = __half22float2(*(__half2*)&raw.y);
            acc[0] = w_self * f0.x; acc[1] = w_self * f0.y;
            acc[2] = w_self * f1.x; acc[3] = w_self * f1.y;
        } else if (CPL == 2) {
            float2 f = __half22float2(*(const __half2*)hp);
            acc[0] = w_self * f.x; acc[1] = w_self * f.y;
        } else {
            acc[0] = w_self * __half2float(hp[0]);
        }
    }

    float denp[H];
#pragma unroll
    for (int hh = 0; hh < H; hh++) denp[hh] = 0.f;

    for (int base = 0; base < deg; base += 64) {
        int i = base + lane;
        if (i < deg) {
            int s = csrc[off + i];
            sbuf[wid][lane] = s;
            float asv[H];
            if (H == 4) {
                float4 t4 = *(const float4*)(a_s + (size_t)s * 4);
                asv[0] = t4.x; asv[1] = t4.y; asv[2] = t4.z; asv[3] = t4.w;
            } else {
                asv[0] = a_s[s];
            }
#pragma unroll
            for (int hh = 0; hh < H; hh++) {
                float sc = asv[hh] + adl[hh];
                sc = sc > 0.f ? sc : NEG_SLOPE * sc;
                float w = __expf(sc);
                wbuf[wid][lane * H + hh] = w;
                denp[hh] += w;
            }
        }
        asm volatile("s_waitcnt lgkmcnt(0)" ::: "memory");  // wave-local LDS visibility
        int cl = deg - base; if (cl > 64) cl = 64;
#pragma unroll 4
        for (int e = 0; e < cl; e++) {
            int s = sbuf[wid][e];
            float w = wbuf[wid][e * H + mh];
            const __half* hp = h + (size_t)s * HC + mych;
            if (CPL == 4) {
                uint2 raw = *(const uint2*)hp;
                float2 f0 = __half22float2(*(__half2*)&raw.x);
                float2 f1 = __half22float2(*(__half2*)&raw.y);
                acc[0] += w * f0.x; acc[1] += w * f0.y;
                acc[2] += w * f1.x; acc[3] += w * f1.y;
            } else if (CPL == 2) {
                float2 f = __half22float2(*(const __half2*)hp);
                acc[0] += w * f.x; acc[1] += w * f.y;
            } else {
                acc[0] += w * __half2float(hp[0]);
            }
        }
    }
#pragma unroll
    for (int hh = 0; hh < H; hh++) {
#pragma unroll
        for (int d = 32; d >= 1; d >>= 1)
            denp[hh] += __shfl_xor(denp[hh], d, 64);
    }
    float inv = 1.0f / (denp[mh] + w_self + 1e-16f);
#pragma unroll
    for (int k = 0; k < CPL; k++)
        out[(size_t)node * HC + mych + k] = acc[k] * inv + bias[mych + k];
}

// ---------------- batch norm ----------------

__global__ void bnstats_kernel(const float* __restrict__ buf, float* __restrict__ sums,
                               int N, int Cc) {
    int t = threadIdx.x;
    int c = t % Cc;
    int rpb = 256 / Cc;
    int row = blockIdx.x * rpb + t / Cc;
    int stride = gridDim.x * rpb;
    float s = 0.f, s2 = 0.f;
    for (int n = row; n < N; n += stride) {
        float v = buf[(size_t)n * Cc + c];
        s += v; s2 += v * v;
    }
    atomicAdd(&sums[c], s);
    atomicAdd(&sums[Cc + c], s2);
}

__global__ void bnfinal_kernel(const float* __restrict__ sums, const float* __restrict__ g,
                               const float* __restrict__ bt, float* __restrict__ ss,
                               float invN, int Cc) {
    int c = threadIdx.x;
    if (c < Cc) {
        float mu = sums[c] * invN;
        float var = sums[Cc + c] * invN - mu * mu;
        float sc = g[c] * rsqrtf(var + 1e-5f);
        ss[c] = sc;
        ss[Cc + c] = bt[c] - mu * sc;
    }
}

__global__ void bnapply_kernel(float* __restrict__ buf, const float* __restrict__ ss,
                               int total, int cmask, int Cc) {
    int i = blockIdx.x * 256 + threadIdx.x;
    if (i >= total) return;
    int c = i & cmask;
    float v = buf[i] * ss[c] + ss[Cc + c];
    buf[i] = v > 0.f ? v : (__expf(v) - 1.0f);   // ELU
}

// ---------------- global mean pool: one block per graph (batch is sorted) ----

__global__ __launch_bounds__(256) void pool_kernel(const float* __restrict__ h,
                                                   const int* __restrict__ batch,
                                                   float* __restrict__ pooled, int N) {
    int g = blockIdx.x;
    int t = threadIdx.x;
    int lo = 0, hi = N;
    while (lo < hi) { int mid = (lo + hi) >> 1; if (batch[mid] < g) lo = mid + 1; else hi = mid; }
    int s = lo;
    hi = N;
    while (lo < hi) { int mid = (lo + hi) >> 1; if (batch[mid] < g + 1) lo = mid + 1; else hi = mid; }
    int e = lo;

    int c = t & 63, rr = t >> 6;
    float acc = 0.f;
    for (int n = s + rr; n < e; n += 4)
        acc += h[(size_t)n * 64 + c];
    __shared__ float red[256];
    red[t] = acc;
    __syncthreads();
    if (t < 128) red[t] += red[t + 128];
    __syncthreads();
    if (t < 64) {
        float v = red[t] + red[t + 64];
        float cntf = (float)(e - s);
        pooled[g * 64 + t] = v / fmaxf(cntf, 1.0f);
    }
}

// ---------------- MLP head (single block) ----------------

__global__ __launch_bounds__(256) void mlp_kernel(const float* __restrict__ pooled,
                                                  const float* __restrict__ fw1, const float* __restrict__ fb1,
                                                  const float* __restrict__ fw2, const float* __restrict__ fb2,
                                                  const float* __restrict__ fw3, const float* __restrict__ fb3,
                                                  float* __restrict__ out) {
    __shared__ float pm[64 * 64];
    __shared__ float z1[64 * 128];
    __shared__ float z2[64 * 32];
    int t = threadIdx.x;
    for (int i = t; i < 64 * 64; i += 256) pm[i] = pooled[i];
    __syncthreads();
    for (int i = t; i < 64 * 128; i += 256) {
        int r = i >> 7, j = i & 127;
        float s = fb1[j];
        for (int k = 0; k < 64; k++) s += pm[r * 64 + k] * fw1[k * 128 + j];
        z1[i] = s > 0.f ? s : NEG_SLOPE * s;
    }
    __syncthreads();
    for (int i = t; i < 64 * 32; i += 256) {
        int r = i >> 5, j = i & 31;
        float s = fb2[j];
        for (int k = 0; k < 128; k++) s += z1[r * 128 + k] * fw2[k * 32 + j];
        z2[i] = s > 0.f ? s : NEG_SLOPE * s;
    }
    __syncthreads();
    for (int i = t; i < 64 * 2; i += 256) {
        int r = i >> 1, j = i & 1;
        float s = fb3[j];
        for (int k = 0; k < 32; k++) s += z2[r * 32 + k] * fw3[k * 2 + j];
        out[i] = s;
    }
}

// ---------------- launch ----------------

extern "C" void kernel_launch(void* const* d_in, const int* in_sizes, int n_in,
                              void* d_out, int out_size, void* d_ws, size_t ws_size,
                              hipStream_t stream) {
    const float* x   = (const float*)d_in[0];
    const int*   ei  = (const int*)d_in[1];
    const int*   batch = (const int*)d_in[2];
    const float* W1  = (const float*)d_in[3];
    const float* as1 = (const float*)d_in[4];
    const float* ad1 = (const float*)d_in[5];
    const float* b1  = (const float*)d_in[6];
    const float* W2  = (const float*)d_in[7];
    const float* as2 = (const float*)d_in[8];
    const float* ad2 = (const float*)d_in[9];
    const float* b2  = (const float*)d_in[10];
    const float* W3  = (const float*)d_in[11];
    const float* as3 = (const float*)d_in[12];
    const float* ad3 = (const float*)d_in[13];
    const float* b3  = (const float*)d_in[14];
    const float* g1  = (const float*)d_in[15];
    const float* bt1 = (const float*)d_in[16];
    const float* g2  = (const float*)d_in[17];
    const float* bt2 = (const float*)d_in[18];
    const float* g3  = (const float*)d_in[19];
    const float* bt3 = (const float*)d_in[20];
    const float* fw1 = (const float*)d_in[21];
    const float* fb1 = (const float*)d_in[22];
    const float* fw2 = (const float*)d_in[23];
    const float* fb2 = (const float*)d_in[24];
    const float* fw3 = (const float*)d_in[25];
    const float* fb3 = (const float*)d_in[26];

    const int N = in_sizes[0] / 128;
    const int E = in_sizes[1] / 2;
    const int* srcv = ei;
    const int* dstv = ei + E;

    // workspace layout (hA region reused as fp16 h buffer; half the floats used)
    float* fws   = (float*)d_ws;
    float* hA    = fws;                            // N*256 floats (holds N*256 halves)
    float* hB    = hA + (size_t)N * 256;           // N*256
    float* a_s   = hB + (size_t)N * 256;           // N*4
    float* a_d   = a_s + (size_t)N * 4;            // N*4
    float* bnsum = a_d + (size_t)N * 4;            // 512
    float* bnss  = bnsum + 512;                    // 512
    float* pooled= bnss + 512;                     // 4096
    float* cnt   = pooled + 4096;                  // 64 (unused)
    int*   deg   = (int*)(cnt + 64);               // N
    int*   offs  = deg + N;                        // N+1
    int*   curs  = offs + N + 1;                   // N
    int*   csrc  = curs + N;                       // E
    __half* hH   = (__half*)hA;                    // N*256 halves

    // --- build CSR by dst (reused across all 3 layers) ---
    hipMemsetAsync(deg, 0, (size_t)N * 4, stream);
    deg_kernel<<<(E + 255) / 256, 256, 0, stream>>>(dstv, deg, E);
    scan_kernel<<<1, 256, 0, stream>>>(deg, offs, curs, N);
    fill_kernel<<<(E + 255) / 256, 256, 0, stream>>>(srcv, dstv, curs, csrc, E);

    dim3 blk(256);

    // --- layer 1: 128 -> 4x64 ---
    {
        dim3 grid((N + 127) / 128, 256 / 64);
        gemm_kernel<<<grid, blk, 0, stream>>>(x, W1, hH, N, 128, 256);
        scores_kernel<<<(N * 4 + 255) / 256, blk, 0, stream>>>(hH, as1, ad1, a_s, a_d, N, 4, 64);
        agg_kernel<4, 64, 4><<<(N + 3) / 4, blk, 0, stream>>>(hH, a_s, a_d, offs, csrc, b1, hB, N);
        hipMemsetAsync(bnsum, 0, 2 * 256 * 4, stream);
        bnstats_kernel<<<256, blk, 0, stream>>>(hB, bnsum, N, 256);
        bnfinal_kernel<<<1, blk, 0, stream>>>(bnsum, g1, bt1, bnss, 1.0f / N, 256);
        bnapply_kernel<<<((size_t)N * 256 + 255) / 256, blk, 0, stream>>>(hB, bnss, N * 256, 255, 256);
    }
    // --- layer 2: 256 -> 4x32 ---
    {
        dim3 grid((N + 127) / 128, 128 / 64);
        gemm_kernel<<<grid, blk, 0, stream>>>(hB, W2, hH, N, 256, 128);
        scores_kernel<<<(N * 4 + 255) / 256, blk, 0, stream>>>(hH, as2, ad2, a_s, a_d, N, 4, 32);
        agg_kernel<4, 32, 2><<<(N + 3) / 4, blk, 0, stream>>>(hH, a_s, a_d, offs, csrc, b2, hB, N);
        hipMemsetAsync(bnsum, 0, 2 * 128 * 4, stream);
        bnstats_kernel<<<256, blk, 0, stream>>>(hB, bnsum, N, 128);
        bnfinal_kernel<<<1, blk, 0, stream>>>(bnsum, g2, bt2, bnss, 1.0f / N, 128);
        bnapply_kernel<<<((size_t)N * 128 + 255) / 256, blk, 0, stream>>>(hB, bnss, N * 128, 127, 128);
    }
    // --- layer 3: 128 -> 1x64 (mean over 1 head = identity) ---
    {
        dim3 grid((N + 127) / 128, 64 / 64);
        gemm_kernel<<<grid, blk, 0, stream>>>(hB, W3, hH, N, 128, 64);
        scores_kernel<<<(N + 255) / 256, blk, 0, stream>>>(hH, as3, ad3, a_s, a_d, N, 1, 64);
        agg_kernel<1, 64, 1><<<(N + 3) / 4, blk, 0, stream>>>(hH, a_s, a_d, offs, csrc, b3, hB, N);
        hipMemsetAsync(bnsum, 0, 2 * 64 * 4, stream);
        bnstats_kernel<<<256, blk, 0, stream>>>(hB, bnsum, N, 64);
        bnfinal_kernel<<<1, blk, 0, stream>>>(bnsum, g3, bt3, bnss, 1.0f / N, 64);
        bnapply_kernel<<<((size_t)N * 64 + 255) / 256, blk, 0, stream>>>(hB, bnss, N * 64, 63, 64);
    }

    // --- global mean pool (no atomics; batch sorted) + MLP head ---
    pool_kernel<<<64, blk, 0, stream>>>(hB, batch, pooled, N);
    mlp_kernel<<<1, blk, 0, stream>>>(pooled, fw1, fb1, fw2, fb2, fw3, fb3, (float*)d_out);
}

// Round 5
// 810.250 us; speedup vs baseline: 1.7561x; 1.0835x over previous
//
#include <hip/hip_runtime.h>
#include <hip/hip_fp16.h>
#include <math.h>

#define NEG_SLOPE 0.2f
#define SCAN_CHUNK 1024   // 256 threads x 4 elems

// ---------------- CSR build ----------------

__global__ void deg_kernel(const int* __restrict__ dst, int* __restrict__ deg, int E) {
    int i = blockIdx.x * 256 + threadIdx.x;
    if (i < E) atomicAdd(&deg[dst[i]], 1);
}

// phase 1: per-block chunk sums
__global__ __launch_bounds__(256) void scan_part1(const int* __restrict__ deg,
                                                  int* __restrict__ bsums, int n) {
    __shared__ int red[256];
    int t = threadIdx.x;
    int b0 = blockIdx.x * SCAN_CHUNK + t * 4;
    int s = 0;
#pragma unroll
    for (int k = 0; k < 4; k++) {
        int idx = b0 + k;
        if (idx < n) s += deg[idx];
    }
    red[t] = s;
    __syncthreads();
    for (int off = 128; off >= 1; off >>= 1) {
        if (t < off) red[t] += red[t + off];
        __syncthreads();
    }
    if (t == 0) bsums[blockIdx.x] = red[0];
}

// phase 2: single small block inclusive-scans the block sums (nb is tiny)
__global__ __launch_bounds__(256) void scan_part2(int* __restrict__ bsums, int nb) {
    __shared__ int tmp[256];
    __shared__ int carrysh;
    int t = threadIdx.x;
    if (t == 0) carrysh = 0;
    __syncthreads();
    for (int base = 0; base < nb; base += 256) {
        int idx = base + t;
        int v = (idx < nb) ? bsums[idx] : 0;
        tmp[t] = v;
        __syncthreads();
        for (int off = 1; off < 256; off <<= 1) {
            int x = (t >= off) ? tmp[t - off] : 0;
            __syncthreads();
            tmp[t] += x;
            __syncthreads();
        }
        int carry = carrysh;
        if (idx < nb) bsums[idx] = tmp[t] + carry;
        __syncthreads();
        if (t == 255) carrysh = carry + tmp[255];
        __syncthreads();
    }
}

// phase 3: local exclusive scan + carry, write offs/curs
__global__ __launch_bounds__(256) void scan_part3(const int* __restrict__ deg,
                                                  const int* __restrict__ bsums,
                                                  int* __restrict__ offs,
                                                  int* __restrict__ curs, int n) {
    __shared__ int tmp[256];
    int t = threadIdx.x;
    int b = blockIdx.x;
    int b0 = b * SCAN_CHUNK + t * 4;
    int loc[4]; int s = 0;
#pragma unroll
    for (int k = 0; k < 4; k++) {
        int idx = b0 + k;
        int v = (idx < n) ? deg[idx] : 0;
        loc[k] = v; s += v;
    }
    tmp[t] = s;
    __syncthreads();
    for (int off = 1; off < 256; off <<= 1) {
        int x = (t >= off) ? tmp[t - off] : 0;
        __syncthreads();
        tmp[t] += x;
        __syncthreads();
    }
    int carry = (b == 0) ? 0 : bsums[b - 1];
    int pre = carry + tmp[t] - s;
#pragma unroll
    for (int k = 0; k < 4; k++) {
        int idx = b0 + k;
        if (idx < n) {
            curs[idx] = pre;
            offs[idx + 1] = pre + loc[k];
            pre += loc[k];
        }
    }
    if (b == 0 && t == 0) offs[0] = 0;
}

__global__ void fill_kernel(const int* __restrict__ src, const int* __restrict__ dst,
                            int* __restrict__ curs, int* __restrict__ csrc, int E) {
    int i = blockIdx.x * 256 + threadIdx.x;
    if (i < E) {
        int d = dst[i];
        int p = atomicAdd(&curs[d], 1);
        csrc[p] = src[i];
    }
}

// ---------------- fp32 GEMM, fp16 output: Yh[M,Nout] = half(X[M,K] @ W[K,Nout]) --
// 128x64 tile, 8x4 acc per thread. K multiple of 16, Nout multiple of 64.

__global__ __launch_bounds__(256) void gemm_kernel(const float* __restrict__ X,
                                                   const float* __restrict__ W,
                                                   __half* __restrict__ Yh,
                                                   int M, int K, int Nout) {
    __shared__ float As[16][132];
    __shared__ float Bs[16][64];
    int tid = threadIdx.x;
    int bm = blockIdx.x * 128;
    int bn = blockIdx.y * 64;
    int tx = tid & 15, ty = tid >> 4;
    float acc[8][4] = {};
    int ar0 = tid >> 2;
    int ak  = (tid & 3) * 4;
    int wr  = tid >> 4;
    int wc  = (tid & 15) * 4;
    for (int k0 = 0; k0 < K; k0 += 16) {
        float4 a0 = make_float4(0.f, 0.f, 0.f, 0.f);
        float4 a1 = make_float4(0.f, 0.f, 0.f, 0.f);
        int r0 = bm + ar0, r1 = r0 + 64;
        if (r0 < M) a0 = *(const float4*)(X + (size_t)r0 * K + k0 + ak);
        if (r1 < M) a1 = *(const float4*)(X + (size_t)r1 * K + k0 + ak);
        As[ak + 0][ar0] = a0.x; As[ak + 1][ar0] = a0.y;
        As[ak + 2][ar0] = a0.z; As[ak + 3][ar0] = a0.w;
        As[ak + 0][ar0 + 64] = a1.x; As[ak + 1][ar0 + 64] = a1.y;
        As[ak + 2][ar0 + 64] = a1.z; As[ak + 3][ar0 + 64] = a1.w;
        *(float4*)&Bs[wr][wc] = *(const float4*)(W + (size_t)(k0 + wr) * Nout + bn + wc);
        __syncthreads();
#pragma unroll
        for (int kk = 0; kk < 16; kk++) {
            float4 al = *(const float4*)&As[kk][ty * 8];
            float4 ah = *(const float4*)&As[kk][ty * 8 + 4];
            float4 b4 = *(const float4*)&Bs[kk][tx * 4];
            float a[8] = {al.x, al.y, al.z, al.w, ah.x, ah.y, ah.z, ah.w};
            float b[4] = {b4.x, b4.y, b4.z, b4.w};
#pragma unroll
            for (int i = 0; i < 8; i++)
#pragma unroll
                for (int j = 0; j < 4; j++) acc[i][j] += a[i] * b[j];
        }
        __syncthreads();
    }
#pragma unroll
    for (int i = 0; i < 8; i++) {
        int row = bm + ty * 8 + i;
        if (row < M) {
            __half2 pk[2];
            pk[0] = __floats2half2_rn(acc[i][0], acc[i][1]);
            pk[1] = __floats2half2_rn(acc[i][2], acc[i][3]);
            *(uint2*)(Yh + (size_t)row * Nout + bn + tx * 4) = *(uint2*)pk;
        }
    }
}

// ---------------- attention scores a_s[n,h], a_d[n,h] (fp16 h) ----------------

__global__ void scores_kernel(const __half* __restrict__ h, const float* __restrict__ att_s,
                              const float* __restrict__ att_d,
                              float* __restrict__ a_s, float* __restrict__ a_d,
                              int N, int H, int C) {
    int id = blockIdx.x * 256 + threadIdx.x;
    if (id >= N * H) return;
    int n = id / H, hh = id % H;
    const __half* hp = h + (size_t)n * H * C + hh * C;
    float ss = 0.f, sd = 0.f;
    for (int c = 0; c < C; c += 2) {
        float2 v = __half22float2(*(const __half2*)(hp + c));
        float2 s2 = *(const float2*)(att_s + hh * C + c);
        float2 d2 = *(const float2*)(att_d + hh * C + c);
        ss += v.x * s2.x + v.y * s2.y;
        sd += v.x * d2.x + v.y * d2.y;
    }
    a_s[id] = ss; a_d[id] = sd;
}

// ---------------- per-node GAT aggregation (wave per node, fp16 gather) -------
// Single pass, no max-subtraction (scores O(10), exp safe in fp32).
// Phase A: edge-parallel score+exp staged to LDS. Phase B: weighted fp16 gather.

template <int H, int C, int CPL>
__global__ __launch_bounds__(256) void agg_kernel(const __half* __restrict__ h,
                                                  const float* __restrict__ a_s,
                                                  const float* __restrict__ a_d,
                                                  const int* __restrict__ offs,
                                                  const int* __restrict__ csrc,
                                                  const float* __restrict__ bias,
                                                  float* __restrict__ out, int N) {
    const int HC = H * C;
    __shared__ float wbuf[4][64 * H];
    __shared__ int   sbuf[4][64];
    int lane = threadIdx.x & 63;
    int wid  = threadIdx.x >> 6;
    int node = blockIdx.x * 4 + wid;
    if (node >= N) return;
    int off = offs[node];
    int deg = offs[node + 1] - off;
    int mych = lane * CPL;
    int mh = mych / C;

    float adl[H];
#pragma unroll
    for (int hh = 0; hh < H; hh++) adl[hh] = a_d[node * H + hh];

    // self loop contribution
    float acc[CPL];
    float sc_self = a_s[node * H + mh] + adl[mh];
    sc_self = sc_self > 0.f ? sc_self : NEG_SLOPE * sc_self;
    float w_self = __expf(sc_self);
    {
        const __half* hp = h + (size_t)node * HC + mych;
        if (CPL == 4) {
            uint2 raw = *(const uint2*)hp;
            float2 f0 = __half22float2(*(__half2*)&raw.x);
            float2 f1 = __half22float2(*(__half2*)&raw.y);
            acc[0] = w_self * f0.x; acc[1] = w_self * f0.y;
            acc[2] = w_self * f1.x; acc[3] = w_self * f1.y;
        } else if (CPL == 2) {
            float2 f = __half22float2(*(const __half2*)hp);
            acc[0] = w_self * f.x; acc[1] = w_self * f.y;
        } else {
            acc[0] = w_self * __half2float(hp[0]);
        }
    }

    float denp[H];
#pragma unroll
    for (int hh = 0; hh < H; hh++) denp[hh] = 0.f;

    for (int base = 0; base < deg; base += 64) {
        int i = base + lane;
        if (i < deg) {
            int s = csrc[off + i];
            sbuf[wid][lane] = s;
            float asv[H];
            if (H == 4) {
                float4 t4 = *(const float4*)(a_s + (size_t)s * 4);
                asv[0] = t4.x; asv[1] = t4.y; asv[2] = t4.z; asv[3] = t4.w;
            } else {
                asv[0] = a_s[s];
            }
#pragma unroll
            for (int hh = 0; hh < H; hh++) {
                float sc = asv[hh] + adl[hh];
                sc = sc > 0.f ? sc : NEG_SLOPE * sc;
                float w = __expf(sc);
                wbuf[wid][lane * H + hh] = w;
                denp[hh] += w;
            }
        }
        asm volatile("s_waitcnt lgkmcnt(0)" ::: "memory");  // wave-local LDS visibility
        int cl = deg - base; if (cl > 64) cl = 64;
#pragma unroll 4
        for (int e = 0; e < cl; e++) {
            int s = sbuf[wid][e];
            float w = wbuf[wid][e * H + mh];
            const __half* hp = h + (size_t)s * HC + mych;
            if (CPL == 4) {
                uint2 raw = *(const uint2*)hp;
                float2 f0 = __half22float2(*(__half2*)&raw.x);
                float2 f1 = __half22float2(*(__half2*)&raw.y);
                acc[0] += w * f0.x; acc[1] += w * f0.y;
                acc[2] += w * f1.x; acc[3] += w * f1.y;
            } else if (CPL == 2) {
                float2 f = __half22float2(*(const __half2*)hp);
                acc[0] += w * f.x; acc[1] += w * f.y;
            } else {
                acc[0] += w * __half2float(hp[0]);
            }
        }
    }
#pragma unroll
    for (int hh = 0; hh < H; hh++) {
#pragma unroll
        for (int d = 32; d >= 1; d >>= 1)
            denp[hh] += __shfl_xor(denp[hh], d, 64);
    }
    float inv = 1.0f / (denp[mh] + w_self + 1e-16f);
#pragma unroll
    for (int k = 0; k < CPL; k++)
        out[(size_t)node * HC + mych + k] = acc[k] * inv + bias[mych + k];
}

// ---------------- batch norm ----------------

__global__ void bnstats_kernel(const float* __restrict__ buf, float* __restrict__ sums,
                               int N, int Cc) {
    int t = threadIdx.x;
    int c = t % Cc;
    int rpb = 256 / Cc;
    int row = blockIdx.x * rpb + t / Cc;
    int stride = gridDim.x * rpb;
    float s = 0.f, s2 = 0.f;
    for (int n = row; n < N; n += stride) {
        float v = buf[(size_t)n * Cc + c];
        s += v; s2 += v * v;
    }
    atomicAdd(&sums[c], s);
    atomicAdd(&sums[Cc + c], s2);
}

__global__ void bnfinal_kernel(const float* __restrict__ sums, const float* __restrict__ g,
                               const float* __restrict__ bt, float* __restrict__ ss,
                               float invN, int Cc) {
    int c = threadIdx.x;
    if (c < Cc) {
        float mu = sums[c] * invN;
        float var = sums[Cc + c] * invN - mu * mu;
        float sc = g[c] * rsqrtf(var + 1e-5f);
        ss[c] = sc;
        ss[Cc + c] = bt[c] - mu * sc;
    }
}

__global__ void bnapply_kernel(float* __restrict__ buf, const float* __restrict__ ss,
                               int total, int cmask, int Cc) {
    int i = blockIdx.x * 256 + threadIdx.x;
    if (i >= total) return;
    int c = i & cmask;
    float v = buf[i] * ss[c] + ss[Cc + c];
    buf[i] = v > 0.f ? v : (__expf(v) - 1.0f);   // ELU
}

// ---------------- global mean pool: one block per graph (batch is sorted) ----

__global__ __launch_bounds__(256) void pool_kernel(const float* __restrict__ h,
                                                   const int* __restrict__ batch,
                                                   float* __restrict__ pooled, int N) {
    int g = blockIdx.x;
    int t = threadIdx.x;
    int lo = 0, hi = N;
    while (lo < hi) { int mid = (lo + hi) >> 1; if (batch[mid] < g) lo = mid + 1; else hi = mid; }
    int s = lo;
    hi = N;
    while (lo < hi) { int mid = (lo + hi) >> 1; if (batch[mid] < g + 1) lo = mid + 1; else hi = mid; }
    int e = lo;

    int c = t & 63, rr = t >> 6;
    float acc = 0.f;
    for (int n = s + rr; n < e; n += 4)
        acc += h[(size_t)n * 64 + c];
    __shared__ float red[256];
    red[t] = acc;
    __syncthreads();
    if (t < 128) red[t] += red[t + 128];
    __syncthreads();
    if (t < 64) {
        float v = red[t] + red[t + 64];
        float cntf = (float)(e - s);
        pooled[g * 64 + t] = v / fmaxf(cntf, 1.0f);
    }
}

// ---------------- MLP head (single block) ----------------

__global__ __launch_bounds__(256) void mlp_kernel(const float* __restrict__ pooled,
                                                  const float* __restrict__ fw1, const float* __restrict__ fb1,
                                                  const float* __restrict__ fw2, const float* __restrict__ fb2,
                                                  const float* __restrict__ fw3, const float* __restrict__ fb3,
                                                  float* __restrict__ out) {
    __shared__ float pm[64 * 64];
    __shared__ float z1[64 * 128];
    __shared__ float z2[64 * 32];
    int t = threadIdx.x;
    for (int i = t; i < 64 * 64; i += 256) pm[i] = pooled[i];
    __syncthreads();
    for (int i = t; i < 64 * 128; i += 256) {
        int r = i >> 7, j = i & 127;
        float s = fb1[j];
        for (int k = 0; k < 64; k++) s += pm[r * 64 + k] * fw1[k * 128 + j];
        z1[i] = s > 0.f ? s : NEG_SLOPE * s;
    }
    __syncthreads();
    for (int i = t; i < 64 * 32; i += 256) {
        int r = i >> 5, j = i & 31;
        float s = fb2[j];
        for (int k = 0; k < 128; k++) s += z1[r * 128 + k] * fw2[k * 32 + j];
        z2[i] = s > 0.f ? s : NEG_SLOPE * s;
    }
    __syncthreads();
    for (int i = t; i < 64 * 2; i += 256) {
        int r = i >> 1, j = i & 1;
        float s = fb3[j];
        for (int k = 0; k < 32; k++) s += z2[r * 32 + k] * fw3[k * 2 + j];
        out[i] = s;
    }
}

// ---------------- launch ----------------

extern "C" void kernel_launch(void* const* d_in, const int* in_sizes, int n_in,
                              void* d_out, int out_size, void* d_ws, size_t ws_size,
                              hipStream_t stream) {
    const float* x   = (const float*)d_in[0];
    const int*   ei  = (const int*)d_in[1];
    const int*   batch = (const int*)d_in[2];
    const float* W1  = (const float*)d_in[3];
    const float* as1 = (const float*)d_in[4];
    const float* ad1 = (const float*)d_in[5];
    const float* b1  = (const float*)d_in[6];
    const float* W2  = (const float*)d_in[7];
    const float* as2 = (const float*)d_in[8];
    const float* ad2 = (const float*)d_in[9];
    const float* b2  = (const float*)d_in[10];
    const float* W3  = (const float*)d_in[11];
    const float* as3 = (const float*)d_in[12];
    const float* ad3 = (const float*)d_in[13];
    const float* b3  = (const float*)d_in[14];
    const float* g1  = (const float*)d_in[15];
    const float* bt1 = (const float*)d_in[16];
    const float* g2  = (const float*)d_in[17];
    const float* bt2 = (const float*)d_in[18];
    const float* g3  = (const float*)d_in[19];
    const float* bt3 = (const float*)d_in[20];
    const float* fw1 = (const float*)d_in[21];
    const float* fb1 = (const float*)d_in[22];
    const float* fw2 = (const float*)d_in[23];
    const float* fb2 = (const float*)d_in[24];
    const float* fw3 = (const float*)d_in[25];
    const float* fb3 = (const float*)d_in[26];

    const int N = in_sizes[0] / 128;
    const int E = in_sizes[1] / 2;
    const int* srcv = ei;
    const int* dstv = ei + E;

    // workspace layout (hA region reused as fp16 h buffer; half the floats used)
    float* fws   = (float*)d_ws;
    float* hA    = fws;                            // N*256 floats (holds N*256 halves)
    float* hB    = hA + (size_t)N * 256;           // N*256
    float* a_s   = hB + (size_t)N * 256;           // N*4
    float* a_d   = a_s + (size_t)N * 4;            // N*4
    float* bnsum = a_d + (size_t)N * 4;            // 512
    float* bnss  = bnsum + 512;                    // 512
    float* pooled= bnss + 512;                     // 4096
    float* cnt   = pooled + 4096;                  // 64 (unused)
    int*   deg   = (int*)(cnt + 64);               // N
    int*   offs  = deg + N;                        // N+1
    int*   curs  = offs + N + 1;                   // N
    int*   csrc  = curs + N;                       // E
    int*   bsums = csrc + E;                       // ceil(N/1024)
    __half* hH   = (__half*)hA;                    // N*256 halves

    const int nbScan = (N + SCAN_CHUNK - 1) / SCAN_CHUNK;

    // --- build CSR by dst (reused across all 3 layers) ---
    hipMemsetAsync(deg, 0, (size_t)N * 4, stream);
    deg_kernel<<<(E + 255) / 256, 256, 0, stream>>>(dstv, deg, E);
    scan_part1<<<nbScan, 256, 0, stream>>>(deg, bsums, N);
    scan_part2<<<1, 256, 0, stream>>>(bsums, nbScan);
    scan_part3<<<nbScan, 256, 0, stream>>>(deg, bsums, offs, curs, N);
    fill_kernel<<<(E + 255) / 256, 256, 0, stream>>>(srcv, dstv, curs, csrc, E);

    dim3 blk(256);

    // --- layer 1: 128 -> 4x64 ---
    {
        dim3 grid((N + 127) / 128, 256 / 64);
        gemm_kernel<<<grid, blk, 0, stream>>>(x, W1, hH, N, 128, 256);
        scores_kernel<<<(N * 4 + 255) / 256, blk, 0, stream>>>(hH, as1, ad1, a_s, a_d, N, 4, 64);
        agg_kernel<4, 64, 4><<<(N + 3) / 4, blk, 0, stream>>>(hH, a_s, a_d, offs, csrc, b1, hB, N);
        hipMemsetAsync(bnsum, 0, 2 * 256 * 4, stream);
        bnstats_kernel<<<256, blk, 0, stream>>>(hB, bnsum, N, 256);
        bnfinal_kernel<<<1, blk, 0, stream>>>(bnsum, g1, bt1, bnss, 1.0f / N, 256);
        bnapply_kernel<<<((size_t)N * 256 + 255) / 256, blk, 0, stream>>>(hB, bnss, N * 256, 255, 256);
    }
    // --- layer 2: 256 -> 4x32 ---
    {
        dim3 grid((N + 127) / 128, 128 / 64);
        gemm_kernel<<<grid, blk, 0, stream>>>(hB, W2, hH, N, 256, 128);
        scores_kernel<<<(N * 4 + 255) / 256, blk, 0, stream>>>(hH, as2, ad2, a_s, a_d, N, 4, 32);
        agg_kernel<4, 32, 2><<<(N + 3) / 4, blk, 0, stream>>>(hH, a_s, a_d, offs, csrc, b2, hB, N);
        hipMemsetAsync(bnsum, 0, 2 * 128 * 4, stream);
        bnstats_kernel<<<256, blk, 0, stream>>>(hB, bnsum, N, 128);
        bnfinal_kernel<<<1, blk, 0, stream>>>(bnsum, g2, bt2, bnss, 1.0f / N, 128);
        bnapply_kernel<<<((size_t)N * 128 + 255) / 256, blk, 0, stream>>>(hB, bnss, N * 128, 127, 128);
    }
    // --- layer 3: 128 -> 1x64 (mean over 1 head = identity) ---
    {
        dim3 grid((N + 127) / 128, 64 / 64);
        gemm_kernel<<<grid, blk, 0, stream>>>(hB, W3, hH, N, 128, 64);
        scores_kernel<<<(N + 255) / 256, blk, 0, stream>>>(hH, as3, ad3, a_s, a_d, N, 1, 64);
        agg_kernel<1, 64, 1><<<(N + 3) / 4, blk, 0, stream>>>(hH, a_s, a_d, offs, csrc, b3, hB, N);
        hipMemsetAsync(bnsum, 0, 2 * 64 * 4, stream);
        bnstats_kernel<<<256, blk, 0, stream>>>(hB, bnsum, N, 64);
        bnfinal_kernel<<<1, blk, 0, stream>>>(bnsum, g3, bt3, bnss, 1.0f / N, 64);
        bnapply_kernel<<<((size_t)N * 64 + 255) / 256, blk, 0, stream>>>(hB, bnss, N * 64, 63, 64);
    }

    // --- global mean pool (no atomics; batch sorted) + MLP head ---
    pool_kernel<<<64, blk, 0, stream>>>(hB, batch, pooled, N);
    mlp_kernel<<<1, blk, 0, stream>>>(pooled, fw1, fb1, fw2, fb2, fw3, fb3, (float*)d_out);
}

// Round 6
// 714.928 us; speedup vs baseline: 1.9903x; 1.1333x over previous
//
#include <hip/hip_runtime.h>
#include <hip/hip_fp16.h>
#include <math.h>

#define NEG_SLOPE 0.2f
#define SCAN_CHUNK 1024   // 256 threads x 4 elems

typedef _Float16 f16x8 __attribute__((ext_vector_type(8)));
typedef float    f32x4 __attribute__((ext_vector_type(4)));

// ---------------- CSR build ----------------

__global__ void deg_kernel(const int* __restrict__ dst, int* __restrict__ deg, int E) {
    int i = blockIdx.x * 256 + threadIdx.x;
    if (i < E) atomicAdd(&deg[dst[i]], 1);
}

__global__ __launch_bounds__(256) void scan_part1(const int* __restrict__ deg,
                                                  int* __restrict__ bsums, int n) {
    __shared__ int red[256];
    int t = threadIdx.x;
    int b0 = blockIdx.x * SCAN_CHUNK + t * 4;
    int s = 0;
#pragma unroll
    for (int k = 0; k < 4; k++) {
        int idx = b0 + k;
        if (idx < n) s += deg[idx];
    }
    red[t] = s;
    __syncthreads();
    for (int off = 128; off >= 1; off >>= 1) {
        if (t < off) red[t] += red[t + off];
        __syncthreads();
    }
    if (t == 0) bsums[blockIdx.x] = red[0];
}

__global__ __launch_bounds__(256) void scan_part2(int* __restrict__ bsums, int nb) {
    __shared__ int tmp[256];
    __shared__ int carrysh;
    int t = threadIdx.x;
    if (t == 0) carrysh = 0;
    __syncthreads();
    for (int base = 0; base < nb; base += 256) {
        int idx = base + t;
        int v = (idx < nb) ? bsums[idx] : 0;
        tmp[t] = v;
        __syncthreads();
        for (int off = 1; off < 256; off <<= 1) {
            int x = (t >= off) ? tmp[t - off] : 0;
            __syncthreads();
            tmp[t] += x;
            __syncthreads();
        }
        int carry = carrysh;
        if (idx < nb) bsums[idx] = tmp[t] + carry;
        __syncthreads();
        if (t == 255) carrysh = carry + tmp[255];
        __syncthreads();
    }
}

__global__ __launch_bounds__(256) void scan_part3(const int* __restrict__ deg,
                                                  const int* __restrict__ bsums,
                                                  int* __restrict__ offs,
                                                  int* __restrict__ curs, int n) {
    __shared__ int tmp[256];
    int t = threadIdx.x;
    int b = blockIdx.x;
    int b0 = b * SCAN_CHUNK + t * 4;
    int loc[4]; int s = 0;
#pragma unroll
    for (int k = 0; k < 4; k++) {
        int idx = b0 + k;
        int v = (idx < n) ? deg[idx] : 0;
        loc[k] = v; s += v;
    }
    tmp[t] = s;
    __syncthreads();
    for (int off = 1; off < 256; off <<= 1) {
        int x = (t >= off) ? tmp[t - off] : 0;
        __syncthreads();
        tmp[t] += x;
        __syncthreads();
    }
    int carry = (b == 0) ? 0 : bsums[b - 1];
    int pre = carry + tmp[t] - s;
#pragma unroll
    for (int k = 0; k < 4; k++) {
        int idx = b0 + k;
        if (idx < n) {
            curs[idx] = pre;
            offs[idx + 1] = pre + loc[k];
            pre += loc[k];
        }
    }
    if (b == 0 && t == 0) offs[0] = 0;
}

__global__ void fill_kernel(const int* __restrict__ src, const int* __restrict__ dst,
                            int* __restrict__ curs, int* __restrict__ csrc, int E) {
    int i = blockIdx.x * 256 + threadIdx.x;
    if (i < E) {
        int d = dst[i];
        int p = atomicAdd(&curs[d], 1);
        csrc[p] = src[i];
    }
}

// ---------------- fp32 -> fp16 cast (x input) ----------------

__global__ void cast_kernel(const float* __restrict__ in, __half* __restrict__ out, int total4) {
    int i = blockIdx.x * 256 + threadIdx.x;
    if (i >= total4) return;
    float4 v = *(const float4*)(in + i * 4);
    __half2 pk[2];
    pk[0] = __floats2half2_rn(v.x, v.y);
    pk[1] = __floats2half2_rn(v.z, v.w);
    *(uint2*)(out + i * 4) = *(uint2*)pk;
}

// ---------------- weight pre-swizzle: W[k][n] fp32 -> Wsw[k/8][n][k%8] fp16 ----

__global__ void preswz_kernel(const float* __restrict__ W, __half* __restrict__ Wsw,
                              int K, int Nout) {
    int i = blockIdx.x * 256 + threadIdx.x;
    if (i >= K * Nout) return;
    int k = i / Nout, n = i % Nout;
    Wsw[((size_t)(k >> 3) * Nout + n) * 8 + (k & 7)] = __float2half(W[i]);
}

// ---------------- MFMA fp16 GEMM: Yh[M,Nout] = Xh[M,K] @ W[K,Nout] ------------
// Block: 256 thr = 4 waves; 128 rows x 64 cols. A frags direct from global
// (16B/lane, k-contiguous). B pre-swizzled in LDS (ds_read_b128 per frag).
// Layouts (verified m89/m91/m120): A[m=lane&15][k=quad*8+j],
// B[k=quad*8+j][n=lane&15], D col=lane&15 row=quad*4+reg.

__global__ __launch_bounds__(256) void gemm_mfma(const __half* __restrict__ X,
                                                 const __half* __restrict__ Wsw,
                                                 __half* __restrict__ Yh,
                                                 int M, int K, int Nout) {
    extern __shared__ __half Bs[];   // (K/8) * 64 * 8 halves
    int tid = threadIdx.x;
    int wave = tid >> 6, lane = tid & 63;
    int bm = blockIdx.x * 128;
    int bn = blockIdx.y * 64;

    int ktCount = K >> 3;
    int totalVec = ktCount * 64;     // one uint4 per (kt, nn)
    for (int i = tid; i < totalVec; i += 256) {
        int kt = i >> 6, off = i & 63;
        ((uint4*)Bs)[i] = *(const uint4*)(Wsw + ((size_t)kt * Nout + bn + off) * 8);
    }
    __syncthreads();

    int quad = lane >> 4, l15 = lane & 15;
    int row0 = bm + wave * 32 + l15;
    bool r0ok = (row0 < M), r1ok = (row0 + 16 < M);
    const __half* a0p = X + (size_t)row0 * K + quad * 8;
    const __half* a1p = a0p + (size_t)16 * K;

    f32x4 acc[2][4] = {};
    for (int kstep = 0; kstep < K; kstep += 32) {
        f16x8 a0 = {}, a1 = {};
        if (r0ok) a0 = *(const f16x8*)(a0p + kstep);
        if (r1ok) a1 = *(const f16x8*)(a1p + kstep);
        int ktbase = (kstep >> 3) + quad;
#pragma unroll
        for (int nt = 0; nt < 4; nt++) {
            f16x8 b = *(const f16x8*)(Bs + ((size_t)ktbase * 64 + nt * 16 + l15) * 8);
            acc[0][nt] = __builtin_amdgcn_mfma_f32_16x16x32_f16(a0, b, acc[0][nt], 0, 0, 0);
            acc[1][nt] = __builtin_amdgcn_mfma_f32_16x16x32_f16(a1, b, acc[1][nt], 0, 0, 0);
        }
    }
#pragma unroll
    for (int mt = 0; mt < 2; mt++) {
#pragma unroll
        for (int r = 0; r < 4; r++) {
            int row = bm + wave * 32 + mt * 16 + quad * 4 + r;
            if (row < M) {
#pragma unroll
                for (int nt = 0; nt < 4; nt++)
                    Yh[(size_t)row * Nout + bn + nt * 16 + l15] = __float2half(acc[mt][nt][r]);
            }
        }
    }
}

// ---------------- attention scores a_s[n,h], a_d[n,h] (fp16 h) ----------------

__global__ void scores_kernel(const __half* __restrict__ h, const float* __restrict__ att_s,
                              const float* __restrict__ att_d,
                              float* __restrict__ a_s, float* __restrict__ a_d,
                              int N, int H, int C) {
    int id = blockIdx.x * 256 + threadIdx.x;
    if (id >= N * H) return;
    int n = id / H, hh = id % H;
    const __half* hp = h + (size_t)n * H * C + hh * C;
    float ss = 0.f, sd = 0.f;
    for (int c = 0; c < C; c += 2) {
        float2 v = __half22float2(*(const __half2*)(hp + c));
        float2 s2 = *(const float2*)(att_s + hh * C + c);
        float2 d2 = *(const float2*)(att_d + hh * C + c);
        ss += v.x * s2.x + v.y * s2.y;
        sd += v.x * d2.x + v.y * d2.y;
    }
    a_s[id] = ss; a_d[id] = sd;
}

// ---------------- per-node GAT aggregation (wave per node, fp16 gather) -------

template <int H, int C, int CPL>
__global__ __launch_bounds__(256) void agg_kernel(const __half* __restrict__ h,
                                                  const float* __restrict__ a_s,
                                                  const float* __restrict__ a_d,
                                                  const int* __restrict__ offs,
                                                  const int* __restrict__ csrc,
                                                  const float* __restrict__ bias,
                                                  float* __restrict__ out, int N) {
    const int HC = H * C;
    __shared__ float wbuf[4][64 * H];
    __shared__ int   sbuf[4][64];
    int lane = threadIdx.x & 63;
    int wid  = threadIdx.x >> 6;
    int node = blockIdx.x * 4 + wid;
    if (node >= N) return;
    int off = offs[node];
    int deg = offs[node + 1] - off;
    int mych = lane * CPL;
    int mh = mych / C;

    float adl[H];
#pragma unroll
    for (int hh = 0; hh < H; hh++) adl[hh] = a_d[node * H + hh];

    float acc[CPL];
    float sc_self = a_s[node * H + mh] + adl[mh];
    sc_self = sc_self > 0.f ? sc_self : NEG_SLOPE * sc_self;
    float w_self = __expf(sc_self);
    {
        const __half* hp = h + (size_t)node * HC + mych;
        if (CPL == 4) {
            uint2 raw = *(const uint2*)hp;
            float2 f0 = __half22float2(*(__half2*)&raw.x);
            float2 f1 = __half22float2(*(__half2*)&raw.y);
            acc[0] = w_self * f0.x; acc[1] = w_self * f0.y;
            acc[2] = w_self * f1.x; acc[3] = w_self * f1.y;
        } else if (CPL == 2) {
            float2 f = __half22float2(*(const __half2*)hp);
            acc[0] = w_self * f.x; acc[1] = w_self * f.y;
        } else {
            acc[0] = w_self * __half2float(hp[0]);
        }
    }

    float denp[H];
#pragma unroll
    for (int hh = 0; hh < H; hh++) denp[hh] = 0.f;

    for (int base = 0; base < deg; base += 64) {
        int i = base + lane;
        if (i < deg) {
            int s = csrc[off + i];
            sbuf[wid][lane] = s;
            float asv[H];
            if (H == 4) {
                float4 t4 = *(const float4*)(a_s + (size_t)s * 4);
                asv[0] = t4.x; asv[1] = t4.y; asv[2] = t4.z; asv[3] = t4.w;
            } else {
                asv[0] = a_s[s];
            }
#pragma unroll
            for (int hh = 0; hh < H; hh++) {
                float sc = asv[hh] + adl[hh];
                sc = sc > 0.f ? sc : NEG_SLOPE * sc;
                float w = __expf(sc);
                wbuf[wid][lane * H + hh] = w;
                denp[hh] += w;
            }
        }
        asm volatile("s_waitcnt lgkmcnt(0)" ::: "memory");
        int cl = deg - base; if (cl > 64) cl = 64;
#pragma unroll 4
        for (int e = 0; e < cl; e++) {
            int s = sbuf[wid][e];
            float w = wbuf[wid][e * H + mh];
            const __half* hp = h + (size_t)s * HC + mych;
            if (CPL == 4) {
                uint2 raw = *(const uint2*)hp;
                float2 f0 = __half22float2(*(__half2*)&raw.x);
                float2 f1 = __half22float2(*(__half2*)&raw.y);
                acc[0] += w * f0.x; acc[1] += w * f0.y;
                acc[2] += w * f1.x; acc[3] += w * f1.y;
            } else if (CPL == 2) {
                float2 f = __half22float2(*(const __half2*)hp);
                acc[0] += w * f.x; acc[1] += w * f.y;
            } else {
                acc[0] += w * __half2float(hp[0]);
            }
        }
    }
#pragma unroll
    for (int hh = 0; hh < H; hh++) {
#pragma unroll
        for (int d = 32; d >= 1; d >>= 1)
            denp[hh] += __shfl_xor(denp[hh], d, 64);
    }
    float inv = 1.0f / (denp[mh] + w_self + 1e-16f);
#pragma unroll
    for (int k = 0; k < CPL; k++)
        out[(size_t)node * HC + mych + k] = acc[k] * inv + bias[mych + k];
}

// ---------------- batch norm ----------------

__global__ void bnstats_kernel(const float* __restrict__ buf, float* __restrict__ sums,
                               int N, int Cc) {
    int t = threadIdx.x;
    int c = t % Cc;
    int rpb = 256 / Cc;
    int row = blockIdx.x * rpb + t / Cc;
    int stride = gridDim.x * rpb;
    float s = 0.f, s2 = 0.f;
    for (int n = row; n < N; n += stride) {
        float v = buf[(size_t)n * Cc + c];
        s += v; s2 += v * v;
    }
    atomicAdd(&sums[c], s);
    atomicAdd(&sums[Cc + c], s2);
}

__global__ void bnfinal_kernel(const float* __restrict__ sums, const float* __restrict__ g,
                               const float* __restrict__ bt, float* __restrict__ ss,
                               float invN, int Cc) {
    int c = threadIdx.x;
    if (c < Cc) {
        float mu = sums[c] * invN;
        float var = sums[Cc + c] * invN - mu * mu;
        float sc = g[c] * rsqrtf(var + 1e-5f);
        ss[c] = sc;
        ss[Cc + c] = bt[c] - mu * sc;
    }
}

// fp32 -> fp16 BN+ELU (feeds next layer's MFMA GEMM)
__global__ void bnapply_h_kernel(const float* __restrict__ in, const float* __restrict__ ss,
                                 __half* __restrict__ outh, int total, int cmask, int Cc) {
    int i = blockIdx.x * 256 + threadIdx.x;
    if (i >= total) return;
    int c = i & cmask;
    float v = in[i] * ss[c] + ss[Cc + c];
    v = v > 0.f ? v : (__expf(v) - 1.0f);
    outh[i] = __float2half(v);
}

// fp32 in-place BN+ELU (layer 3, feeds pool)
__global__ void bnapply_kernel(float* __restrict__ buf, const float* __restrict__ ss,
                               int total, int cmask, int Cc) {
    int i = blockIdx.x * 256 + threadIdx.x;
    if (i >= total) return;
    int c = i & cmask;
    float v = buf[i] * ss[c] + ss[Cc + c];
    buf[i] = v > 0.f ? v : (__expf(v) - 1.0f);
}

// ---------------- global mean pool: one block per graph (batch is sorted) ----

__global__ __launch_bounds__(256) void pool_kernel(const float* __restrict__ h,
                                                   const int* __restrict__ batch,
                                                   float* __restrict__ pooled, int N) {
    int g = blockIdx.x;
    int t = threadIdx.x;
    int lo = 0, hi = N;
    while (lo < hi) { int mid = (lo + hi) >> 1; if (batch[mid] < g) lo = mid + 1; else hi = mid; }
    int s = lo;
    hi = N;
    while (lo < hi) { int mid = (lo + hi) >> 1; if (batch[mid] < g + 1) lo = mid + 1; else hi = mid; }
    int e = lo;

    int c = t & 63, rr = t >> 6;
    float acc = 0.f;
    for (int n = s + rr; n < e; n += 4)
        acc += h[(size_t)n * 64 + c];
    __shared__ float red[256];
    red[t] = acc;
    __syncthreads();
    if (t < 128) red[t] += red[t + 128];
    __syncthreads();
    if (t < 64) {
        float v = red[t] + red[t + 64];
        float cntf = (float)(e - s);
        pooled[g * 64 + t] = v / fmaxf(cntf, 1.0f);
    }
}

// ---------------- MLP head (single block) ----------------

__global__ __launch_bounds__(256) void mlp_kernel(const float* __restrict__ pooled,
                                                  const float* __restrict__ fw1, const float* __restrict__ fb1,
                                                  const float* __restrict__ fw2, const float* __restrict__ fb2,
                                                  const float* __restrict__ fw3, const float* __restrict__ fb3,
                                                  float* __restrict__ out) {
    __shared__ float pm[64 * 64];
    __shared__ float z1[64 * 128];
    __shared__ float z2[64 * 32];
    int t = threadIdx.x;
    for (int i = t; i < 64 * 64; i += 256) pm[i] = pooled[i];
    __syncthreads();
    for (int i = t; i < 64 * 128; i += 256) {
        int r = i >> 7, j = i & 127;
        float s = fb1[j];
        for (int k = 0; k < 64; k++) s += pm[r * 64 + k] * fw1[k * 128 + j];
        z1[i] = s > 0.f ? s : NEG_SLOPE * s;
    }
    __syncthreads();
    for (int i = t; i < 64 * 32; i += 256) {
        int r = i >> 5, j = i & 31;
        float s = fb2[j];
        for (int k = 0; k < 128; k++) s += z1[r * 128 + k] * fw2[k * 32 + j];
        z2[i] = s > 0.f ? s : NEG_SLOPE * s;
    }
    __syncthreads();
    for (int i = t; i < 64 * 2; i += 256) {
        int r = i >> 1, j = i & 1;
        float s = fb3[j];
        for (int k = 0; k < 32; k++) s += z2[r * 32 + k] * fw3[k * 2 + j];
        out[i] = s;
    }
}

// ---------------- launch ----------------

extern "C" void kernel_launch(void* const* d_in, const int* in_sizes, int n_in,
                              void* d_out, int out_size, void* d_ws, size_t ws_size,
                              hipStream_t stream) {
    const float* x   = (const float*)d_in[0];
    const int*   ei  = (const int*)d_in[1];
    const int*   batch = (const int*)d_in[2];
    const float* W1  = (const float*)d_in[3];
    const float* as1 = (const float*)d_in[4];
    const float* ad1 = (const float*)d_in[5];
    const float* b1  = (const float*)d_in[6];
    const float* W2  = (const float*)d_in[7];
    const float* as2 = (const float*)d_in[8];
    const float* ad2 = (const float*)d_in[9];
    const float* b2  = (const float*)d_in[10];
    const float* W3  = (const float*)d_in[11];
    const float* as3 = (const float*)d_in[12];
    const float* ad3 = (const float*)d_in[13];
    const float* b3  = (const float*)d_in[14];
    const float* g1  = (const float*)d_in[15];
    const float* bt1 = (const float*)d_in[16];
    const float* g2  = (const float*)d_in[17];
    const float* bt2 = (const float*)d_in[18];
    const float* g3  = (const float*)d_in[19];
    const float* bt3 = (const float*)d_in[20];
    const float* fw1 = (const float*)d_in[21];
    const float* fb1 = (const float*)d_in[22];
    const float* fw2 = (const float*)d_in[23];
    const float* fb2 = (const float*)d_in[24];
    const float* fw3 = (const float*)d_in[25];
    const float* fb3 = (const float*)d_in[26];

    const int N = in_sizes[0] / 128;
    const int E = in_sizes[1] / 2;
    const int* srcv = ei;
    const int* dstv = ei + E;

    // workspace layout (floats)
    float* fws   = (float*)d_ws;
    float* HhF   = fws;                            // N*128 floats -> Hh fp16 N*256
    float* XhF   = HhF + (size_t)N * 128;          // N*128 floats -> Xh fp16 N*256
    float* hB    = XhF + (size_t)N * 128;          // N*256 floats
    float* a_s   = hB + (size_t)N * 256;           // N*4
    float* a_d   = a_s + (size_t)N * 4;            // N*4
    float* bnsum = a_d + (size_t)N * 4;            // 512
    float* bnss  = bnsum + 512;                    // 512
    float* pooled= bnss + 512;                     // 4096
    int*   deg   = (int*)(pooled + 4096);          // N
    int*   offs  = deg + N;                        // N+1
    int*   curs  = offs + N + 1;                   // N
    int*   csrc  = curs + N;                       // E
    int*   bsums = csrc + E;                       // ceil(N/1024)
    float* wswF  = (float*)(bsums + ((N + SCAN_CHUNK - 1) / SCAN_CHUNK));
    __half* W1sw = (__half*)wswF;                  // 128*256 halves
    __half* W2sw = W1sw + 128 * 256;               // 256*128 halves
    __half* W3sw = W2sw + 256 * 128;               // 128*64 halves
    __half* Hh   = (__half*)HhF;
    __half* Xh   = (__half*)XhF;

    const int nbScan = (N + SCAN_CHUNK - 1) / SCAN_CHUNK;
    dim3 blk(256);

    // --- build CSR by dst (reused across all 3 layers) ---
    hipMemsetAsync(deg, 0, (size_t)N * 4, stream);
    deg_kernel<<<(E + 255) / 256, blk, 0, stream>>>(dstv, deg, E);
    scan_part1<<<nbScan, blk, 0, stream>>>(deg, bsums, N);
    scan_part2<<<1, blk, 0, stream>>>(bsums, nbScan);
    scan_part3<<<nbScan, blk, 0, stream>>>(deg, bsums, offs, curs, N);
    fill_kernel<<<(E + 255) / 256, blk, 0, stream>>>(srcv, dstv, curs, csrc, E);

    // --- weight pre-swizzle + x cast ---
    preswz_kernel<<<(128 * 256 + 255) / 256, blk, 0, stream>>>(W1, W1sw, 128, 256);
    preswz_kernel<<<(256 * 128 + 255) / 256, blk, 0, stream>>>(W2, W2sw, 256, 128);
    preswz_kernel<<<(128 * 64 + 255) / 256, blk, 0, stream>>>(W3, W3sw, 128, 64);
    cast_kernel<<<((size_t)N * 128 / 4 + 255) / 256, blk, 0, stream>>>(x, Xh, N * 128 / 4);

    // --- layer 1: 128 -> 4x64 ---
    {
        dim3 grid((N + 127) / 128, 256 / 64);
        gemm_mfma<<<grid, blk, 128 * 128, stream>>>(Xh, W1sw, Hh, N, 128, 256);
        scores_kernel<<<(N * 4 + 255) / 256, blk, 0, stream>>>(Hh, as1, ad1, a_s, a_d, N, 4, 64);
        agg_kernel<4, 64, 4><<<(N + 3) / 4, blk, 0, stream>>>(Hh, a_s, a_d, offs, csrc, b1, hB, N);
        hipMemsetAsync(bnsum, 0, 2 * 256 * 4, stream);
        bnstats_kernel<<<256, blk, 0, stream>>>(hB, bnsum, N, 256);
        bnfinal_kernel<<<1, blk, 0, stream>>>(bnsum, g1, bt1, bnss, 1.0f / N, 256);
        bnapply_h_kernel<<<((size_t)N * 256 + 255) / 256, blk, 0, stream>>>(hB, bnss, Xh, N * 256, 255, 256);
    }
    // --- layer 2: 256 -> 4x32 ---
    {
        dim3 grid((N + 127) / 128, 128 / 64);
        gemm_mfma<<<grid, blk, 256 * 128, stream>>>(Xh, W2sw, Hh, N, 256, 128);
        scores_kernel<<<(N * 4 + 255) / 256, blk, 0, stream>>>(Hh, as2, ad2, a_s, a_d, N, 4, 32);
        agg_kernel<4, 32, 2><<<(N + 3) / 4, blk, 0, stream>>>(Hh, a_s, a_d, offs, csrc, b2, hB, N);
        hipMemsetAsync(bnsum, 0, 2 * 128 * 4, stream);
        bnstats_kernel<<<256, blk, 0, stream>>>(hB, bnsum, N, 128);
        bnfinal_kernel<<<1, blk, 0, stream>>>(bnsum, g2, bt2, bnss, 1.0f / N, 128);
        bnapply_h_kernel<<<((size_t)N * 128 + 255) / 256, blk, 0, stream>>>(hB, bnss, Xh, N * 128, 127, 128);
    }
    // --- layer 3: 128 -> 1x64 (mean over 1 head = identity) ---
    {
        dim3 grid((N + 127) / 128, 64 / 64);
        gemm_mfma<<<grid, blk, 128 * 128, stream>>>(Xh, W3sw, Hh, N, 128, 64);
        scores_kernel<<<(N + 255) / 256, blk, 0, stream>>>(Hh, as3, ad3, a_s, a_d, N, 1, 64);
        agg_kernel<1, 64, 1><<<(N + 3) / 4, blk, 0, stream>>>(Hh, a_s, a_d, offs, csrc, b3, hB, N);
        hipMemsetAsync(bnsum, 0, 2 * 64 * 4, stream);
        bnstats_kernel<<<256, blk, 0, stream>>>(hB, bnsum, N, 64);
        bnfinal_kernel<<<1, blk, 0, stream>>>(bnsum, g3, bt3, bnss, 1.0f / N, 64);
        bnapply_kernel<<<((size_t)N * 64 + 255) / 256, blk, 0, stream>>>(hB, bnss, N * 64, 63, 64);
    }

    // --- global mean pool (no atomics; batch sorted) + MLP head ---
    pool_kernel<<<64, blk, 0, stream>>>(hB, batch, pooled, N);
    mlp_kernel<<<1, blk, 0, stream>>>(pooled, fw1, fb1, fw2, fb2, fw3, fb3, (float*)d_out);
}

// Round 7
// 647.509 us; speedup vs baseline: 2.1975x; 1.1041x over previous
//
#include <hip/hip_runtime.h>
#include <hip/hip_fp16.h>
#include <math.h>

#define NEG_SLOPE 0.2f
#define SCAN_CHUNK 1024   // 256 threads x 4 elems

typedef _Float16 f16x8 __attribute__((ext_vector_type(8)));
typedef float    f32x4 __attribute__((ext_vector_type(4)));

// ---------------- CSR build ----------------

__global__ void deg_kernel(const int* __restrict__ dst, int* __restrict__ deg, int E) {
    int i = blockIdx.x * 256 + threadIdx.x;
    if (i < E) atomicAdd(&deg[dst[i]], 1);
}

__global__ __launch_bounds__(256) void scan_part1(const int* __restrict__ deg,
                                                  int* __restrict__ bsums, int n) {
    __shared__ int red[256];
    int t = threadIdx.x;
    int b0 = blockIdx.x * SCAN_CHUNK + t * 4;
    int s = 0;
#pragma unroll
    for (int k = 0; k < 4; k++) {
        int idx = b0 + k;
        if (idx < n) s += deg[idx];
    }
    red[t] = s;
    __syncthreads();
    for (int off = 128; off >= 1; off >>= 1) {
        if (t < off) red[t] += red[t + off];
        __syncthreads();
    }
    if (t == 0) bsums[blockIdx.x] = red[0];
}

__global__ __launch_bounds__(256) void scan_part2(int* __restrict__ bsums, int nb) {
    __shared__ int tmp[256];
    __shared__ int carrysh;
    int t = threadIdx.x;
    if (t == 0) carrysh = 0;
    __syncthreads();
    for (int base = 0; base < nb; base += 256) {
        int idx = base + t;
        int v = (idx < nb) ? bsums[idx] : 0;
        tmp[t] = v;
        __syncthreads();
        for (int off = 1; off < 256; off <<= 1) {
            int x = (t >= off) ? tmp[t - off] : 0;
            __syncthreads();
            tmp[t] += x;
            __syncthreads();
        }
        int carry = carrysh;
        if (idx < nb) bsums[idx] = tmp[t] + carry;
        __syncthreads();
        if (t == 255) carrysh = carry + tmp[255];
        __syncthreads();
    }
}

__global__ __launch_bounds__(256) void scan_part3(const int* __restrict__ deg,
                                                  const int* __restrict__ bsums,
                                                  int* __restrict__ offs,
                                                  int* __restrict__ curs, int n) {
    __shared__ int tmp[256];
    int t = threadIdx.x;
    int b = blockIdx.x;
    int b0 = b * SCAN_CHUNK + t * 4;
    int loc[4]; int s = 0;
#pragma unroll
    for (int k = 0; k < 4; k++) {
        int idx = b0 + k;
        int v = (idx < n) ? deg[idx] : 0;
        loc[k] = v; s += v;
    }
    tmp[t] = s;
    __syncthreads();
    for (int off = 1; off < 256; off <<= 1) {
        int x = (t >= off) ? tmp[t - off] : 0;
        __syncthreads();
        tmp[t] += x;
        __syncthreads();
    }
    int carry = (b == 0) ? 0 : bsums[b - 1];
    int pre = carry + tmp[t] - s;
#pragma unroll
    for (int k = 0; k < 4; k++) {
        int idx = b0 + k;
        if (idx < n) {
            curs[idx] = pre;
            offs[idx + 1] = pre + loc[k];
            pre += loc[k];
        }
    }
    if (b == 0 && t == 0) offs[0] = 0;
}

__global__ void fill_kernel(const int* __restrict__ src, const int* __restrict__ dst,
                            int* __restrict__ curs, int* __restrict__ csrc, int E) {
    int i = blockIdx.x * 256 + threadIdx.x;
    if (i < E) {
        int d = dst[i];
        int p = atomicAdd(&curs[d], 1);
        csrc[p] = src[i];
    }
}

// ---------------- fused prep: 3x weight pre-swizzle + x cast ----------------
// Wsw[k/8][n][k%8] fp16  (B-fragment order for MFMA)

__device__ inline void swz1(const float* __restrict__ W, __half* __restrict__ Wsw,
                            int Nout, int i) {
    int k = i / Nout, n = i % Nout;
    Wsw[((size_t)(k >> 3) * Nout + n) * 8 + (k & 7)] = __float2half(W[i]);
}

__global__ void prep_kernel(const float* __restrict__ W1, const float* __restrict__ W2,
                            const float* __restrict__ W3,
                            __half* __restrict__ W1sw, __half* __restrict__ W2sw,
                            __half* __restrict__ W3sw,
                            const float* __restrict__ x, __half* __restrict__ Xh,
                            int castN4) {
    int i = blockIdx.x * 256 + threadIdx.x;
    const int R0 = 128 * 256, R1 = R0 + 256 * 128, R2 = R1 + 128 * 64;
    if (i < R0) { swz1(W1, W1sw, 256, i); }
    else if (i < R1) { swz1(W2, W2sw, 128, i - R0); }
    else if (i < R2) { swz1(W3, W3sw, 64, i - R1); }
    else {
        int j = i - R2;
        if (j < castN4) {
            float4 v = *(const float4*)(x + (size_t)j * 4);
            __half2 pk[2];
            pk[0] = __floats2half2_rn(v.x, v.y);
            pk[1] = __floats2half2_rn(v.z, v.w);
            *(uint2*)(Xh + (size_t)j * 4) = *(uint2*)pk;
        }
    }
}

// ---------------- MFMA fp16 GEMM + fused attention scores ------------------
// Yh[M,Nout] = Xh[M,K] @ W[K,Nout]; also a_s[n,h] = sum_c Y*att_s etc.
// Block: 256 thr = 4 waves; 128 rows x 64 cols. CH = channels per head;
// head of a column = gcol / CH, and att flat index == gcol (since H*CH==Nout).
// Layouts (verified m89/m91): A[m=lane&15][k=quad*8+j], B[k=quad*8+j][n=lane&15],
// D col=lane&15 row=quad*4+reg.

template <int CH>
__global__ __launch_bounds__(256) void gemm_mfma(const __half* __restrict__ X,
                                                 const __half* __restrict__ Wsw,
                                                 __half* __restrict__ Yh,
                                                 const float* __restrict__ att_s,
                                                 const float* __restrict__ att_d,
                                                 float* __restrict__ a_s,
                                                 float* __restrict__ a_d,
                                                 int M, int K, int Nout) {
    extern __shared__ __half Bs[];   // (K/8) * 64 * 8 halves
    int tid = threadIdx.x;
    int wave = tid >> 6, lane = tid & 63;
    int bm = blockIdx.x * 128;
    int bn = blockIdx.y * 64;

    int ktCount = K >> 3;
    int totalVec = ktCount * 64;
    for (int i = tid; i < totalVec; i += 256) {
        int kt = i >> 6, off = i & 63;
        ((uint4*)Bs)[i] = *(const uint4*)(Wsw + ((size_t)kt * Nout + bn + off) * 8);
    }
    __syncthreads();

    int quad = lane >> 4, l15 = lane & 15;
    int row0 = bm + wave * 32 + l15;
    bool r0ok = (row0 < M), r1ok = (row0 + 16 < M);
    const __half* a0p = X + (size_t)row0 * K + quad * 8;
    const __half* a1p = a0p + (size_t)16 * K;

    f32x4 acc[2][4] = {};
    for (int kstep = 0; kstep < K; kstep += 32) {
        f16x8 a0 = {}, a1 = {};
        if (r0ok) a0 = *(const f16x8*)(a0p + kstep);
        if (r1ok) a1 = *(const f16x8*)(a1p + kstep);
        int ktbase = (kstep >> 3) + quad;
#pragma unroll
        for (int nt = 0; nt < 4; nt++) {
            f16x8 b = *(const f16x8*)(Bs + ((size_t)ktbase * 64 + nt * 16 + l15) * 8);
            acc[0][nt] = __builtin_amdgcn_mfma_f32_16x16x32_f16(a0, b, acc[0][nt], 0, 0, 0);
            acc[1][nt] = __builtin_amdgcn_mfma_f32_16x16x32_f16(a1, b, acc[1][nt], 0, 0, 0);
        }
    }

    // store Yh
#pragma unroll
    for (int mt = 0; mt < 2; mt++) {
#pragma unroll
        for (int r = 0; r < 4; r++) {
            int row = bm + wave * 32 + mt * 16 + quad * 4 + r;
            if (row < M) {
#pragma unroll
                for (int nt = 0; nt < 4; nt++)
                    Yh[(size_t)row * Nout + bn + nt * 16 + l15] = __float2half(acc[mt][nt][r]);
            }
        }
    }

    // fused scores: per-lane partial dot with att vectors, 16-lane reduce
    constexpr int LH = 64 / CH;      // local heads per 64-col tile (1 or 2)
    const int H = Nout / CH;
    float as_l[4], ad_l[4];
#pragma unroll
    for (int nt = 0; nt < 4; nt++) {
        int gcol = bn + nt * 16 + l15;
        as_l[nt] = att_s[gcol];
        ad_l[nt] = att_d[gcol];
    }
    float ps[2][4][LH], pd[2][4][LH];
#pragma unroll
    for (int mt = 0; mt < 2; mt++)
#pragma unroll
        for (int r = 0; r < 4; r++)
#pragma unroll
            for (int lh = 0; lh < LH; lh++) { ps[mt][r][lh] = 0.f; pd[mt][r][lh] = 0.f; }
#pragma unroll
    for (int mt = 0; mt < 2; mt++)
#pragma unroll
        for (int nt = 0; nt < 4; nt++) {
            int lh = (nt * 16) / CH;   // head partition independent of l15 for CH in {32,64}
#pragma unroll
            for (int r = 0; r < 4; r++) {
                ps[mt][r][lh] += acc[mt][nt][r] * as_l[nt];
                pd[mt][r][lh] += acc[mt][nt][r] * ad_l[nt];
            }
        }
#pragma unroll
    for (int d = 1; d <= 8; d <<= 1) {
#pragma unroll
        for (int mt = 0; mt < 2; mt++)
#pragma unroll
            for (int r = 0; r < 4; r++)
#pragma unroll
                for (int lh = 0; lh < LH; lh++) {
                    ps[mt][r][lh] += __shfl_xor(ps[mt][r][lh], d, 64);
                    pd[mt][r][lh] += __shfl_xor(pd[mt][r][lh], d, 64);
                }
    }
    if (l15 == 0) {
#pragma unroll
        for (int mt = 0; mt < 2; mt++)
#pragma unroll
            for (int r = 0; r < 4; r++) {
                int row = bm + wave * 32 + mt * 16 + quad * 4 + r;
                if (row < M) {
#pragma unroll
                    for (int lh = 0; lh < LH; lh++) {
                        int ghead = bn / CH + lh;
                        a_s[(size_t)row * H + ghead] = ps[mt][r][lh];
                        a_d[(size_t)row * H + ghead] = pd[mt][r][lh];
                    }
                }
            }
    }
}

// ---------------- per-node GAT aggregation (wave per node, fp16 in/out) -------

template <int H, int C, int CPL>
__global__ __launch_bounds__(256) void agg_kernel(const __half* __restrict__ h,
                                                  const float* __restrict__ a_s,
                                                  const float* __restrict__ a_d,
                                                  const int* __restrict__ offs,
                                                  const int* __restrict__ csrc,
                                                  const float* __restrict__ bias,
                                                  __half* __restrict__ out, int N) {
    const int HC = H * C;
    __shared__ float wbuf[4][64 * H];
    __shared__ int   sbuf[4][64];
    int lane = threadIdx.x & 63;
    int wid  = threadIdx.x >> 6;
    int node = blockIdx.x * 4 + wid;
    if (node >= N) return;
    int off = offs[node];
    int deg = offs[node + 1] - off;
    int mych = lane * CPL;
    int mh = mych / C;

    float adl[H];
#pragma unroll
    for (int hh = 0; hh < H; hh++) adl[hh] = a_d[node * H + hh];

    float acc[CPL];
    float sc_self = a_s[node * H + mh] + adl[mh];
    sc_self = sc_self > 0.f ? sc_self : NEG_SLOPE * sc_self;
    float w_self = __expf(sc_self);
    {
        const __half* hp = h + (size_t)node * HC + mych;
        if (CPL == 4) {
            uint2 raw = *(const uint2*)hp;
            float2 f0 = __half22float2(*(__half2*)&raw.x);
            float2 f1 = __half22float2(*(__half2*)&raw.y);
            acc[0] = w_self * f0.x; acc[1] = w_self * f0.y;
            acc[2] = w_self * f1.x; acc[3] = w_self * f1.y;
        } else if (CPL == 2) {
            float2 f = __half22float2(*(const __half2*)hp);
            acc[0] = w_self * f.x; acc[1] = w_self * f.y;
        } else {
            acc[0] = w_self * __half2float(hp[0]);
        }
    }

    float denp[H];
#pragma unroll
    for (int hh = 0; hh < H; hh++) denp[hh] = 0.f;

    for (int base = 0; base < deg; base += 64) {
        int i = base + lane;
        if (i < deg) {
            int s = csrc[off + i];
            sbuf[wid][lane] = s;
            float asv[H];
            if (H == 4) {
                float4 t4 = *(const float4*)(a_s + (size_t)s * 4);
                asv[0] = t4.x; asv[1] = t4.y; asv[2] = t4.z; asv[3] = t4.w;
            } else {
                asv[0] = a_s[s];
            }
#pragma unroll
            for (int hh = 0; hh < H; hh++) {
                float sc = asv[hh] + adl[hh];
                sc = sc > 0.f ? sc : NEG_SLOPE * sc;
                float w = __expf(sc);
                wbuf[wid][lane * H + hh] = w;
                denp[hh] += w;
            }
        }
        asm volatile("s_waitcnt lgkmcnt(0)" ::: "memory");
        int cl = deg - base; if (cl > 64) cl = 64;
#pragma unroll 8
        for (int e = 0; e < cl; e++) {
            int s = sbuf[wid][e];
            float w = wbuf[wid][e * H + mh];
            const __half* hp = h + (size_t)s * HC + mych;
            if (CPL == 4) {
                uint2 raw = *(const uint2*)hp;
                float2 f0 = __half22float2(*(__half2*)&raw.x);
                float2 f1 = __half22float2(*(__half2*)&raw.y);
                acc[0] += w * f0.x; acc[1] += w * f0.y;
                acc[2] += w * f1.x; acc[3] += w * f1.y;
            } else if (CPL == 2) {
                float2 f = __half22float2(*(const __half2*)hp);
                acc[0] += w * f.x; acc[1] += w * f.y;
            } else {
                acc[0] += w * __half2float(hp[0]);
            }
        }
    }
#pragma unroll
    for (int hh = 0; hh < H; hh++) {
#pragma unroll
        for (int d = 32; d >= 1; d >>= 1)
            denp[hh] += __shfl_xor(denp[hh], d, 64);
    }
    float inv = 1.0f / (denp[mh] + w_self + 1e-16f);
    if (CPL == 4) {
        __half2 o0 = __floats2half2_rn(acc[0] * inv + bias[mych + 0], acc[1] * inv + bias[mych + 1]);
        __half2 o1 = __floats2half2_rn(acc[2] * inv + bias[mych + 2], acc[3] * inv + bias[mych + 3]);
        uint2 pk; pk.x = *(unsigned*)&o0; pk.y = *(unsigned*)&o1;
        *(uint2*)(out + (size_t)node * HC + mych) = pk;
    } else if (CPL == 2) {
        __half2 o = __floats2half2_rn(acc[0] * inv + bias[mych + 0], acc[1] * inv + bias[mych + 1]);
        *(__half2*)(out + (size_t)node * HC + mych) = o;
    } else {
        out[(size_t)node * HC + mych] = __float2half(acc[0] * inv + bias[mych]);
    }
}

// ---------------- batch norm (fp16 activations, fp32 stats) ----------------

__global__ void bnstats_kernel(const __half* __restrict__ buf, float* __restrict__ sums,
                               int N, int Cc) {
    int t = threadIdx.x;
    int c = t % Cc;
    int rpb = 256 / Cc;
    int row = blockIdx.x * rpb + t / Cc;
    int stride = gridDim.x * rpb;
    float s = 0.f, s2 = 0.f;
    for (int n = row; n < N; n += stride) {
        float v = __half2float(buf[(size_t)n * Cc + c]);
        s += v; s2 += v * v;
    }
    atomicAdd(&sums[c], s);
    atomicAdd(&sums[Cc + c], s2);
}

__global__ void bnfinal_kernel(const float* __restrict__ sums, const float* __restrict__ g,
                               const float* __restrict__ bt, float* __restrict__ ss,
                               float invN, int Cc) {
    int c = threadIdx.x;
    if (c < Cc) {
        float mu = sums[c] * invN;
        float var = sums[Cc + c] * invN - mu * mu;
        float sc = g[c] * rsqrtf(var + 1e-5f);
        ss[c] = sc;
        ss[Cc + c] = bt[c] - mu * sc;
    }
}

// fp16 -> BN+ELU -> fp16 (feeds next layer's MFMA GEMM / pool)
__global__ void bnapply_kernel(const __half* __restrict__ in, const float* __restrict__ ss,
                               __half* __restrict__ outh, int total, int cmask, int Cc) {
    int i = blockIdx.x * 256 + threadIdx.x;
    if (i >= total) return;
    int c = i & cmask;
    float v = __half2float(in[i]) * ss[c] + ss[Cc + c];
    v = v > 0.f ? v : (__expf(v) - 1.0f);
    outh[i] = __float2half(v);
}

// ---------------- global mean pool: one block per graph (batch sorted) ------

__global__ __launch_bounds__(256) void pool_kernel(const __half* __restrict__ h,
                                                   const int* __restrict__ batch,
                                                   float* __restrict__ pooled, int N) {
    int g = blockIdx.x;
    int t = threadIdx.x;
    int lo = 0, hi = N;
    while (lo < hi) { int mid = (lo + hi) >> 1; if (batch[mid] < g) lo = mid + 1; else hi = mid; }
    int s = lo;
    hi = N;
    while (lo < hi) { int mid = (lo + hi) >> 1; if (batch[mid] < g + 1) lo = mid + 1; else hi = mid; }
    int e = lo;

    int c = t & 63, rr = t >> 6;
    float acc = 0.f;
    for (int n = s + rr; n < e; n += 4)
        acc += __half2float(h[(size_t)n * 64 + c]);
    __shared__ float red[256];
    red[t] = acc;
    __syncthreads();
    if (t < 128) red[t] += red[t + 128];
    __syncthreads();
    if (t < 64) {
        float v = red[t] + red[t + 64];
        float cntf = (float)(e - s);
        pooled[g * 64 + t] = v / fmaxf(cntf, 1.0f);
    }
}

// ---------------- MLP head (single block) ----------------

__global__ __launch_bounds__(256) void mlp_kernel(const float* __restrict__ pooled,
                                                  const float* __restrict__ fw1, const float* __restrict__ fb1,
                                                  const float* __restrict__ fw2, const float* __restrict__ fb2,
                                                  const float* __restrict__ fw3, const float* __restrict__ fb3,
                                                  float* __restrict__ out) {
    __shared__ float pm[64 * 64];
    __shared__ float z1[64 * 128];
    __shared__ float z2[64 * 32];
    int t = threadIdx.x;
    for (int i = t; i < 64 * 64; i += 256) pm[i] = pooled[i];
    __syncthreads();
    for (int i = t; i < 64 * 128; i += 256) {
        int r = i >> 7, j = i & 127;
        float s = fb1[j];
        for (int k = 0; k < 64; k++) s += pm[r * 64 + k] * fw1[k * 128 + j];
        z1[i] = s > 0.f ? s : NEG_SLOPE * s;
    }
    __syncthreads();
    for (int i = t; i < 64 * 32; i += 256) {
        int r = i >> 5, j = i & 31;
        float s = fb2[j];
        for (int k = 0; k < 128; k++) s += z1[r * 128 + k] * fw2[k * 32 + j];
        z2[i] = s > 0.f ? s : NEG_SLOPE * s;
    }
    __syncthreads();
    for (int i = t; i < 64 * 2; i += 256) {
        int r = i >> 1, j = i & 1;
        float s = fb3[j];
        for (int k = 0; k < 32; k++) s += z2[r * 32 + k] * fw3[k * 2 + j];
        out[i] = s;
    }
}

// ---------------- launch ----------------

extern "C" void kernel_launch(void* const* d_in, const int* in_sizes, int n_in,
                              void* d_out, int out_size, void* d_ws, size_t ws_size,
                              hipStream_t stream) {
    const float* x   = (const float*)d_in[0];
    const int*   ei  = (const int*)d_in[1];
    const int*   batch = (const int*)d_in[2];
    const float* W1  = (const float*)d_in[3];
    const float* as1 = (const float*)d_in[4];
    const float* ad1 = (const float*)d_in[5];
    const float* b1  = (const float*)d_in[6];
    const float* W2  = (const float*)d_in[7];
    const float* as2 = (const float*)d_in[8];
    const float* ad2 = (const float*)d_in[9];
    const float* b2  = (const float*)d_in[10];
    const float* W3  = (const float*)d_in[11];
    const float* as3 = (const float*)d_in[12];
    const float* ad3 = (const float*)d_in[13];
    const float* b3  = (const float*)d_in[14];
    const float* g1  = (const float*)d_in[15];
    const float* bt1 = (const float*)d_in[16];
    const float* g2  = (const float*)d_in[17];
    const float* bt2 = (const float*)d_in[18];
    const float* g3  = (const float*)d_in[19];
    const float* bt3 = (const float*)d_in[20];
    const float* fw1 = (const float*)d_in[21];
    const float* fb1 = (const float*)d_in[22];
    const float* fw2 = (const float*)d_in[23];
    const float* fb2 = (const float*)d_in[24];
    const float* fw3 = (const float*)d_in[25];
    const float* fb3 = (const float*)d_in[26];

    const int N = in_sizes[0] / 128;
    const int E = in_sizes[1] / 2;
    const int* srcv = ei;
    const int* dstv = ei + E;

    // workspace layout (floats)
    float* fws   = (float*)d_ws;
    float* HhF   = fws;                            // N*128 floats -> Hh fp16 N*256
    float* XhF   = HhF + (size_t)N * 128;          // N*128 floats -> Xh fp16 N*256
    float* hBF   = XhF + (size_t)N * 128;          // N*128 floats -> hBh fp16 N*256
    float* a_s   = hBF + (size_t)N * 128;          // N*4
    float* a_d   = a_s + (size_t)N * 4;            // N*4
    float* bnsum = a_d + (size_t)N * 4;            // 512
    float* bnss  = bnsum + 512;                    // 512
    float* pooled= bnss + 512;                     // 4096
    int*   deg   = (int*)(pooled + 4096);          // N
    int*   offs  = deg + N;                        // N+1
    int*   curs  = offs + N + 1;                   // N
    int*   csrc  = curs + N;                       // E
    int*   bsums = csrc + E;                       // ceil(N/1024)
    float* wswF  = (float*)(bsums + ((N + SCAN_CHUNK - 1) / SCAN_CHUNK));
    __half* W1sw = (__half*)wswF;                  // 128*256 halves
    __half* W2sw = W1sw + 128 * 256;               // 256*128 halves
    __half* W3sw = W2sw + 256 * 128;               // 128*64 halves
    __half* Hh   = (__half*)HhF;
    __half* Xh   = (__half*)XhF;
    __half* hBh  = (__half*)hBF;

    const int nbScan = (N + SCAN_CHUNK - 1) / SCAN_CHUNK;
    dim3 blk(256);

    // --- build CSR by dst (reused across all 3 layers) ---
    hipMemsetAsync(deg, 0, (size_t)N * 4, stream);
    deg_kernel<<<(E + 255) / 256, blk, 0, stream>>>(dstv, deg, E);
    scan_part1<<<nbScan, blk, 0, stream>>>(deg, bsums, N);
    scan_part2<<<1, blk, 0, stream>>>(bsums, nbScan);
    scan_part3<<<nbScan, blk, 0, stream>>>(deg, bsums, offs, curs, N);
    fill_kernel<<<(E + 255) / 256, blk, 0, stream>>>(srcv, dstv, curs, csrc, E);

    // --- fused weight pre-swizzle + x cast ---
    {
        int castN4 = N * 32;                       // N*128/4
        int total = 128 * 256 + 256 * 128 + 128 * 64 + castN4;
        prep_kernel<<<(total + 255) / 256, blk, 0, stream>>>(W1, W2, W3, W1sw, W2sw, W3sw,
                                                             x, Xh, castN4);
    }

    // --- layer 1: 128 -> 4x64 ---
    {
        dim3 grid((N + 127) / 128, 256 / 64);
        gemm_mfma<64><<<grid, blk, 128 * 128, stream>>>(Xh, W1sw, Hh, as1, ad1, a_s, a_d, N, 128, 256);
        agg_kernel<4, 64, 4><<<(N + 3) / 4, blk, 0, stream>>>(Hh, a_s, a_d, offs, csrc, b1, hBh, N);
        hipMemsetAsync(bnsum, 0, 2 * 256 * 4, stream);
        bnstats_kernel<<<256, blk, 0, stream>>>(hBh, bnsum, N, 256);
        bnfinal_kernel<<<1, blk, 0, stream>>>(bnsum, g1, bt1, bnss, 1.0f / N, 256);
        bnapply_kernel<<<((size_t)N * 256 + 255) / 256, blk, 0, stream>>>(hBh, bnss, Xh, N * 256, 255, 256);
    }
    // --- layer 2: 256 -> 4x32 ---
    {
        dim3 grid((N + 127) / 128, 128 / 64);
        gemm_mfma<32><<<grid, blk, 256 * 128, stream>>>(Xh, W2sw, Hh, as2, ad2, a_s, a_d, N, 256, 128);
        agg_kernel<4, 32, 2><<<(N + 3) / 4, blk, 0, stream>>>(Hh, a_s, a_d, offs, csrc, b2, hBh, N);
        hipMemsetAsync(bnsum, 0, 2 * 128 * 4, stream);
        bnstats_kernel<<<256, blk, 0, stream>>>(hBh, bnsum, N, 128);
        bnfinal_kernel<<<1, blk, 0, stream>>>(bnsum, g2, bt2, bnss, 1.0f / N, 128);
        bnapply_kernel<<<((size_t)N * 128 + 255) / 256, blk, 0, stream>>>(hBh, bnss, Xh, N * 128, 127, 128);
    }
    // --- layer 3: 128 -> 1x64 (mean over 1 head = identity) ---
    {
        dim3 grid((N + 127) / 128, 64 / 64);
        gemm_mfma<64><<<grid, blk, 128 * 128, stream>>>(Xh, W3sw, Hh, as3, ad3, a_s, a_d, N, 128, 64);
        agg_kernel<1, 64, 1><<<(N + 3) / 4, blk, 0, stream>>>(Hh, a_s, a_d, offs, csrc, b3, hBh, N);
        hipMemsetAsync(bnsum, 0, 2 * 64 * 4, stream);
        bnstats_kernel<<<256, blk, 0, stream>>>(hBh, bnsum, N, 64);
        bnfinal_kernel<<<1, blk, 0, stream>>>(bnsum, g3, bt3, bnss, 1.0f / N, 64);
        bnapply_kernel<<<((size_t)N * 64 + 255) / 256, blk, 0, stream>>>(hBh, bnss, Xh, N * 64, 63, 64);
    }

    // --- global mean pool (no atomics; batch sorted) + MLP head ---
    pool_kernel<<<64, blk, 0, stream>>>(Xh, batch, pooled, N);
    mlp_kernel<<<1, blk, 0, stream>>>(pooled, fw1, fb1, fw2, fb2, fw3, fb3, (float*)d_out);
}

// Round 8
// 614.027 us; speedup vs baseline: 2.3173x; 1.0545x over previous
//
#include <hip/hip_runtime.h>
#include <hip/hip_fp16.h>
#include <math.h>

#define NEG_SLOPE 0.2f
#define SCAN_CHUNK 1024   // 256 threads x 4 elems

typedef _Float16 f16x8 __attribute__((ext_vector_type(8)));
typedef float    f32x4 __attribute__((ext_vector_type(4)));

// ---------------- CSR build ----------------

__global__ void deg_kernel(const int* __restrict__ dst, int* __restrict__ deg, int E) {
    int i = blockIdx.x * 256 + threadIdx.x;
    if (i < E) atomicAdd(&deg[dst[i]], 1);
}

__global__ __launch_bounds__(256) void scan_part1(const int* __restrict__ deg,
                                                  int* __restrict__ bsums, int n) {
    __shared__ int red[256];
    int t = threadIdx.x;
    int b0 = blockIdx.x * SCAN_CHUNK + t * 4;
    int s = 0;
#pragma unroll
    for (int k = 0; k < 4; k++) {
        int idx = b0 + k;
        if (idx < n) s += deg[idx];
    }
    red[t] = s;
    __syncthreads();
    for (int off = 128; off >= 1; off >>= 1) {
        if (t < off) red[t] += red[t + off];
        __syncthreads();
    }
    if (t == 0) bsums[blockIdx.x] = red[0];
}

__global__ __launch_bounds__(256) void scan_part2(int* __restrict__ bsums, int nb) {
    __shared__ int tmp[256];
    __shared__ int carrysh;
    int t = threadIdx.x;
    if (t == 0) carrysh = 0;
    __syncthreads();
    for (int base = 0; base < nb; base += 256) {
        int idx = base + t;
        int v = (idx < nb) ? bsums[idx] : 0;
        tmp[t] = v;
        __syncthreads();
        for (int off = 1; off < 256; off <<= 1) {
            int x = (t >= off) ? tmp[t - off] : 0;
            __syncthreads();
            tmp[t] += x;
            __syncthreads();
        }
        int carry = carrysh;
        if (idx < nb) bsums[idx] = tmp[t] + carry;
        __syncthreads();
        if (t == 255) carrysh = carry + tmp[255];
        __syncthreads();
    }
}

__global__ __launch_bounds__(256) void scan_part3(const int* __restrict__ deg,
                                                  const int* __restrict__ bsums,
                                                  int* __restrict__ offs,
                                                  int* __restrict__ curs, int n) {
    __shared__ int tmp[256];
    int t = threadIdx.x;
    int b = blockIdx.x;
    int b0 = b * SCAN_CHUNK + t * 4;
    int loc[4]; int s = 0;
#pragma unroll
    for (int k = 0; k < 4; k++) {
        int idx = b0 + k;
        int v = (idx < n) ? deg[idx] : 0;
        loc[k] = v; s += v;
    }
    tmp[t] = s;
    __syncthreads();
    for (int off = 1; off < 256; off <<= 1) {
        int x = (t >= off) ? tmp[t - off] : 0;
        __syncthreads();
        tmp[t] += x;
        __syncthreads();
    }
    int carry = (b == 0) ? 0 : bsums[b - 1];
    int pre = carry + tmp[t] - s;
#pragma unroll
    for (int k = 0; k < 4; k++) {
        int idx = b0 + k;
        if (idx < n) {
            curs[idx] = pre;
            offs[idx + 1] = pre + loc[k];
            pre += loc[k];
        }
    }
    if (b == 0 && t == 0) offs[0] = 0;
}

__global__ void fill_kernel(const int* __restrict__ src, const int* __restrict__ dst,
                            int* __restrict__ curs, int* __restrict__ csrc, int E) {
    int i = blockIdx.x * 256 + threadIdx.x;
    if (i < E) {
        int d = dst[i];
        int p = atomicAdd(&curs[d], 1);
        csrc[p] = src[i];
    }
}

// ---------------- fused prep: 3x weight pre-swizzle + x cast ----------------
// Wsw[k/8][n][k%8] fp16  (B-fragment order for MFMA)

__device__ inline void swz1(const float* __restrict__ W, __half* __restrict__ Wsw,
                            int Nout, int i) {
    int k = i / Nout, n = i % Nout;
    Wsw[((size_t)(k >> 3) * Nout + n) * 8 + (k & 7)] = __float2half(W[i]);
}

__global__ void prep_kernel(const float* __restrict__ W1, const float* __restrict__ W2,
                            const float* __restrict__ W3,
                            __half* __restrict__ W1sw, __half* __restrict__ W2sw,
                            __half* __restrict__ W3sw,
                            const float* __restrict__ x, __half* __restrict__ Xh,
                            int castN4) {
    int i = blockIdx.x * 256 + threadIdx.x;
    const int R0 = 128 * 256, R1 = R0 + 256 * 128, R2 = R1 + 128 * 64;
    if (i < R0) { swz1(W1, W1sw, 256, i); }
    else if (i < R1) { swz1(W2, W2sw, 128, i - R0); }
    else if (i < R2) { swz1(W3, W3sw, 64, i - R1); }
    else {
        int j = i - R2;
        if (j < castN4) {
            float4 v = *(const float4*)(x + (size_t)j * 4);
            __half2 pk[2];
            pk[0] = __floats2half2_rn(v.x, v.y);
            pk[1] = __floats2half2_rn(v.z, v.w);
            *(uint2*)(Xh + (size_t)j * 4) = *(uint2*)pk;
        }
    }
}

// ---------------- MFMA fp16 GEMM + fused attention scores ------------------
// Layouts (verified m89/m91): A[m=lane&15][k=quad*8+j], B[k=quad*8+j][n=lane&15],
// D col=lane&15 row=quad*4+reg.

template <int CH>
__global__ __launch_bounds__(256) void gemm_mfma(const __half* __restrict__ X,
                                                 const __half* __restrict__ Wsw,
                                                 __half* __restrict__ Yh,
                                                 const float* __restrict__ att_s,
                                                 const float* __restrict__ att_d,
                                                 float* __restrict__ a_s,
                                                 float* __restrict__ a_d,
                                                 int M, int K, int Nout) {
    extern __shared__ __half Bs[];   // (K/8) * 64 * 8 halves
    int tid = threadIdx.x;
    int wave = tid >> 6, lane = tid & 63;
    int bm = blockIdx.x * 128;
    int bn = blockIdx.y * 64;

    int ktCount = K >> 3;
    int totalVec = ktCount * 64;
    for (int i = tid; i < totalVec; i += 256) {
        int kt = i >> 6, off = i & 63;
        ((uint4*)Bs)[i] = *(const uint4*)(Wsw + ((size_t)kt * Nout + bn + off) * 8);
    }
    __syncthreads();

    int quad = lane >> 4, l15 = lane & 15;
    int row0 = bm + wave * 32 + l15;
    bool r0ok = (row0 < M), r1ok = (row0 + 16 < M);
    const __half* a0p = X + (size_t)row0 * K + quad * 8;
    const __half* a1p = a0p + (size_t)16 * K;

    f32x4 acc[2][4] = {};
    for (int kstep = 0; kstep < K; kstep += 32) {
        f16x8 a0 = {}, a1 = {};
        if (r0ok) a0 = *(const f16x8*)(a0p + kstep);
        if (r1ok) a1 = *(const f16x8*)(a1p + kstep);
        int ktbase = (kstep >> 3) + quad;
#pragma unroll
        for (int nt = 0; nt < 4; nt++) {
            f16x8 b = *(const f16x8*)(Bs + ((size_t)ktbase * 64 + nt * 16 + l15) * 8);
            acc[0][nt] = __builtin_amdgcn_mfma_f32_16x16x32_f16(a0, b, acc[0][nt], 0, 0, 0);
            acc[1][nt] = __builtin_amdgcn_mfma_f32_16x16x32_f16(a1, b, acc[1][nt], 0, 0, 0);
        }
    }

    // store Yh
#pragma unroll
    for (int mt = 0; mt < 2; mt++) {
#pragma unroll
        for (int r = 0; r < 4; r++) {
            int row = bm + wave * 32 + mt * 16 + quad * 4 + r;
            if (row < M) {
#pragma unroll
                for (int nt = 0; nt < 4; nt++)
                    Yh[(size_t)row * Nout + bn + nt * 16 + l15] = __float2half(acc[mt][nt][r]);
            }
        }
    }

    // fused scores: per-lane partial dot with att vectors, 16-lane reduce
    constexpr int LH = 64 / CH;      // local heads per 64-col tile (1 or 2)
    const int H = Nout / CH;
    float as_l[4], ad_l[4];
#pragma unroll
    for (int nt = 0; nt < 4; nt++) {
        int gcol = bn + nt * 16 + l15;
        as_l[nt] = att_s[gcol];
        ad_l[nt] = att_d[gcol];
    }
    float ps[2][4][LH], pd[2][4][LH];
#pragma unroll
    for (int mt = 0; mt < 2; mt++)
#pragma unroll
        for (int r = 0; r < 4; r++)
#pragma unroll
            for (int lh = 0; lh < LH; lh++) { ps[mt][r][lh] = 0.f; pd[mt][r][lh] = 0.f; }
#pragma unroll
    for (int mt = 0; mt < 2; mt++)
#pragma unroll
        for (int nt = 0; nt < 4; nt++) {
            int lh = (nt * 16) / CH;
#pragma unroll
            for (int r = 0; r < 4; r++) {
                ps[mt][r][lh] += acc[mt][nt][r] * as_l[nt];
                pd[mt][r][lh] += acc[mt][nt][r] * ad_l[nt];
            }
        }
#pragma unroll
    for (int d = 1; d <= 8; d <<= 1) {
#pragma unroll
        for (int mt = 0; mt < 2; mt++)
#pragma unroll
            for (int r = 0; r < 4; r++)
#pragma unroll
                for (int lh = 0; lh < LH; lh++) {
                    ps[mt][r][lh] += __shfl_xor(ps[mt][r][lh], d, 64);
                    pd[mt][r][lh] += __shfl_xor(pd[mt][r][lh], d, 64);
                }
    }
    if (l15 == 0) {
#pragma unroll
        for (int mt = 0; mt < 2; mt++)
#pragma unroll
            for (int r = 0; r < 4; r++) {
                int row = bm + wave * 32 + mt * 16 + quad * 4 + r;
                if (row < M) {
#pragma unroll
                    for (int lh = 0; lh < LH; lh++) {
                        int ghead = bn / CH + lh;
                        a_s[(size_t)row * H + ghead] = ps[mt][r][lh];
                        a_d[(size_t)row * H + ghead] = pd[mt][r][lh];
                    }
                }
            }
    }
}

// ---------------- per-node GAT aggregation (wave per node, EPW edges/iter) ----
// EPW = 256/HC lane-groups of LPE=64/EPW lanes each gather a different edge
// concurrently (4 fp16 channels per lane). Cross-group shfl reduce at the end.

template <int H, int C, int EPW>
__global__ __launch_bounds__(256) void agg_kernel(const __half* __restrict__ h,
                                                  const float* __restrict__ a_s,
                                                  const float* __restrict__ a_d,
                                                  const int* __restrict__ offs,
                                                  const int* __restrict__ csrc,
                                                  const float* __restrict__ bias,
                                                  __half* __restrict__ out, int N) {
    const int HC = H * C;
    const int LPE = 64 / EPW;        // lanes per edge
    __shared__ float wbuf[4][64 * H];
    __shared__ int   sbuf[4][64];
    int lane = threadIdx.x & 63;
    int wid  = threadIdx.x >> 6;
    int node = blockIdx.x * 4 + wid;
    if (node >= N) return;
    int off = offs[node];
    int deg = offs[node + 1] - off;
    int grp  = lane / LPE;
    int mych = (lane % LPE) * 4;
    int mh = mych / C;

    float adl[H];
#pragma unroll
    for (int hh = 0; hh < H; hh++) adl[hh] = a_d[node * H + hh];

    float acc[4] = {0.f, 0.f, 0.f, 0.f};
    float sc_self = a_s[node * H + mh] + adl[mh];
    sc_self = sc_self > 0.f ? sc_self : NEG_SLOPE * sc_self;
    float w_self = __expf(sc_self);
    if (grp == 0) {
        const __half* hp = h + (size_t)node * HC + mych;
        uint2 raw = *(const uint2*)hp;
        float2 f0 = __half22float2(*(__half2*)&raw.x);
        float2 f1 = __half22float2(*(__half2*)&raw.y);
        acc[0] = w_self * f0.x; acc[1] = w_self * f0.y;
        acc[2] = w_self * f1.x; acc[3] = w_self * f1.y;
    }

    float denp[H];
#pragma unroll
    for (int hh = 0; hh < H; hh++) denp[hh] = 0.f;

    for (int base = 0; base < deg; base += 64) {
        int i = base + lane;
        if (i < deg) {
            int s = csrc[off + i];
            sbuf[wid][lane] = s;
            float asv[H];
            if (H == 4) {
                float4 t4 = *(const float4*)(a_s + (size_t)s * 4);
                asv[0] = t4.x; asv[1] = t4.y; asv[2] = t4.z; asv[3] = t4.w;
            } else {
                asv[0] = a_s[s];
            }
#pragma unroll
            for (int hh = 0; hh < H; hh++) {
                float sc = asv[hh] + adl[hh];
                sc = sc > 0.f ? sc : NEG_SLOPE * sc;
                float w = __expf(sc);
                wbuf[wid][lane * H + hh] = w;
                denp[hh] += w;
            }
        }
        asm volatile("s_waitcnt lgkmcnt(0)" ::: "memory");
        int cl = deg - base; if (cl > 64) cl = 64;
#pragma unroll 8
        for (int e = 0; e < cl; e += EPW) {
            int idx = e + grp;
            if (idx < cl) {
                int s = sbuf[wid][idx];
                float w = wbuf[wid][idx * H + mh];
                const __half* hp = h + (size_t)s * HC + mych;
                uint2 raw = *(const uint2*)hp;
                float2 f0 = __half22float2(*(__half2*)&raw.x);
                float2 f1 = __half22float2(*(__half2*)&raw.y);
                acc[0] += w * f0.x; acc[1] += w * f0.y;
                acc[2] += w * f1.x; acc[3] += w * f1.y;
            }
        }
    }
#pragma unroll
    for (int hh = 0; hh < H; hh++) {
#pragma unroll
        for (int d = 32; d >= 1; d >>= 1)
            denp[hh] += __shfl_xor(denp[hh], d, 64);
    }
    // reduce accumulators across the EPW lane-groups
#pragma unroll
    for (int d = LPE; d < 64; d <<= 1) {
#pragma unroll
        for (int k = 0; k < 4; k++)
            acc[k] += __shfl_xor(acc[k], d, 64);
    }
    float inv = 1.0f / (denp[mh] + w_self + 1e-16f);
    if (grp == 0) {
        __half2 o0 = __floats2half2_rn(acc[0] * inv + bias[mych + 0], acc[1] * inv + bias[mych + 1]);
        __half2 o1 = __floats2half2_rn(acc[2] * inv + bias[mych + 2], acc[3] * inv + bias[mych + 3]);
        uint2 pk; pk.x = *(unsigned*)&o0; pk.y = *(unsigned*)&o1;
        *(uint2*)(out + (size_t)node * HC + mych) = pk;
    }
}

// ---------------- batch norm (fp16 activations, fp32 stats) ----------------

__global__ void bnstats_kernel(const __half* __restrict__ buf, float* __restrict__ sums,
                               int N, int Cc) {
    int t = threadIdx.x;
    int c = t % Cc;
    int rpb = 256 / Cc;
    int row = blockIdx.x * rpb + t / Cc;
    int stride = gridDim.x * rpb;
    float s = 0.f, s2 = 0.f;
    for (int n = row; n < N; n += stride) {
        float v = __half2float(buf[(size_t)n * Cc + c]);
        s += v; s2 += v * v;
    }
    atomicAdd(&sums[c], s);
    atomicAdd(&sums[Cc + c], s2);
}

// fused bnfinal + apply: scale/shift computed per-block in LDS; 8 halves/thread
__global__ __launch_bounds__(256) void bnapply_kernel(const __half* __restrict__ in,
                                                      const float* __restrict__ sums,
                                                      const float* __restrict__ gg,
                                                      const float* __restrict__ bt,
                                                      __half* __restrict__ outh,
                                                      int total, int cmask, int Cc,
                                                      float invN) {
    __shared__ float ssc[256], ssb[256];
    int t = threadIdx.x;
    if (t < Cc) {
        float mu = sums[t] * invN;
        float var = sums[Cc + t] * invN - mu * mu;
        float sc = gg[t] * rsqrtf(var + 1e-5f);
        ssc[t] = sc;
        ssb[t] = bt[t] - mu * sc;
    }
    __syncthreads();
    int base = blockIdx.x * 2048 + t * 8;
    if (base >= total) return;
    uint4 raw = *(const uint4*)(in + base);
    __half2* hp = (__half2*)&raw;
    uint4 outv; __half2* op = (__half2*)&outv;
    int c0 = base & cmask;
#pragma unroll
    for (int j = 0; j < 4; j++) {
        float2 f = __half22float2(hp[j]);
        int ca = c0 + 2 * j, cb = c0 + 2 * j + 1;
        float va = f.x * ssc[ca] + ssb[ca]; va = va > 0.f ? va : (__expf(va) - 1.0f);
        float vb = f.y * ssc[cb] + ssb[cb]; vb = vb > 0.f ? vb : (__expf(vb) - 1.0f);
        op[j] = __floats2half2_rn(va, vb);
    }
    *(uint4*)(outh + base) = outv;
}

// ---------------- fused global mean pool + MLP head (row-parallel) ----------
// one block per graph (batch is sorted); MLP stages are row-independent.

__global__ __launch_bounds__(256) void poolmlp_kernel(const __half* __restrict__ h,
                                                      const int* __restrict__ batch,
                                                      const float* __restrict__ fw1, const float* __restrict__ fb1,
                                                      const float* __restrict__ fw2, const float* __restrict__ fb2,
                                                      const float* __restrict__ fw3, const float* __restrict__ fb3,
                                                      float* __restrict__ out, int N) {
    int g = blockIdx.x;
    int t = threadIdx.x;
    int lo = 0, hi = N;
    while (lo < hi) { int mid = (lo + hi) >> 1; if (batch[mid] < g) lo = mid + 1; else hi = mid; }
    int s = lo;
    hi = N;
    while (lo < hi) { int mid = (lo + hi) >> 1; if (batch[mid] < g + 1) lo = mid + 1; else hi = mid; }
    int e = lo;

    __shared__ float red[256];
    __shared__ float pm[64];
    __shared__ float z1[128];
    __shared__ float z2[32];
    int c = t & 63, rr = t >> 6;
    float acc = 0.f;
    for (int n = s + rr; n < e; n += 4)
        acc += __half2float(h[(size_t)n * 64 + c]);
    red[t] = acc;
    __syncthreads();
    if (t < 128) red[t] += red[t + 128];
    __syncthreads();
    if (t < 64) pm[t] = (red[t] + red[t + 64]) / fmaxf((float)(e - s), 1.0f);
    __syncthreads();
    if (t < 128) {
        float v = fb1[t];
        for (int k = 0; k < 64; k++) v += pm[k] * fw1[k * 128 + t];
        z1[t] = v > 0.f ? v : NEG_SLOPE * v;
    }
    __syncthreads();
    if (t < 32) {
        float v = fb2[t];
        for (int k = 0; k < 128; k++) v += z1[k] * fw2[k * 32 + t];
        z2[t] = v > 0.f ? v : NEG_SLOPE * v;
    }
    __syncthreads();
    if (t < 2) {
        float v = fb3[t];
        for (int k = 0; k < 32; k++) v += z2[k] * fw3[k * 2 + t];
        out[g * 2 + t] = v;
    }
}

// ---------------- launch ----------------

extern "C" void kernel_launch(void* const* d_in, const int* in_sizes, int n_in,
                              void* d_out, int out_size, void* d_ws, size_t ws_size,
                              hipStream_t stream) {
    const float* x   = (const float*)d_in[0];
    const int*   ei  = (const int*)d_in[1];
    const int*   batch = (const int*)d_in[2];
    const float* W1  = (const float*)d_in[3];
    const float* as1 = (const float*)d_in[4];
    const float* ad1 = (const float*)d_in[5];
    const float* b1  = (const float*)d_in[6];
    const float* W2  = (const float*)d_in[7];
    const float* as2 = (const float*)d_in[8];
    const float* ad2 = (const float*)d_in[9];
    const float* b2  = (const float*)d_in[10];
    const float* W3  = (const float*)d_in[11];
    const float* as3 = (const float*)d_in[12];
    const float* ad3 = (const float*)d_in[13];
    const float* b3  = (const float*)d_in[14];
    const float* g1  = (const float*)d_in[15];
    const float* bt1 = (const float*)d_in[16];
    const float* g2  = (const float*)d_in[17];
    const float* bt2 = (const float*)d_in[18];
    const float* g3  = (const float*)d_in[19];
    const float* bt3 = (const float*)d_in[20];
    const float* fw1 = (const float*)d_in[21];
    const float* fb1 = (const float*)d_in[22];
    const float* fw2 = (const float*)d_in[23];
    const float* fb2 = (const float*)d_in[24];
    const float* fw3 = (const float*)d_in[25];
    const float* fb3 = (const float*)d_in[26];

    const int N = in_sizes[0] / 128;
    const int E = in_sizes[1] / 2;
    const int* srcv = ei;
    const int* dstv = ei + E;

    // workspace layout (floats)
    float* fws   = (float*)d_ws;
    float* HhF   = fws;                            // N*128 floats -> Hh fp16 N*256
    float* XhF   = HhF + (size_t)N * 128;          // N*128 floats -> Xh fp16 N*256
    float* hBF   = XhF + (size_t)N * 128;          // N*128 floats -> hBh fp16 N*256
    float* a_s   = hBF + (size_t)N * 128;          // N*4
    float* a_d   = a_s + (size_t)N * 4;            // N*4
    float* bnsum = a_d + (size_t)N * 4;            // 512
    int*   deg   = (int*)(bnsum + 512);            // N
    int*   offs  = deg + N;                        // N+1
    int*   curs  = offs + N + 1;                   // N
    int*   csrc  = curs + N;                       // E
    int*   bsums = csrc + E;                       // ceil(N/1024)
    float* wswF  = (float*)(bsums + ((N + SCAN_CHUNK - 1) / SCAN_CHUNK));
    __half* W1sw = (__half*)wswF;                  // 128*256 halves
    __half* W2sw = W1sw + 128 * 256;               // 256*128 halves
    __half* W3sw = W2sw + 256 * 128;               // 128*64 halves
    __half* Hh   = (__half*)HhF;
    __half* Xh   = (__half*)XhF;
    __half* hBh  = (__half*)hBF;

    const int nbScan = (N + SCAN_CHUNK - 1) / SCAN_CHUNK;
    dim3 blk(256);

    // --- build CSR by dst (reused across all 3 layers) ---
    hipMemsetAsync(deg, 0, (size_t)N * 4, stream);
    deg_kernel<<<(E + 255) / 256, blk, 0, stream>>>(dstv, deg, E);
    scan_part1<<<nbScan, blk, 0, stream>>>(deg, bsums, N);
    scan_part2<<<1, blk, 0, stream>>>(bsums, nbScan);
    scan_part3<<<nbScan, blk, 0, stream>>>(deg, bsums, offs, curs, N);
    fill_kernel<<<(E + 255) / 256, blk, 0, stream>>>(srcv, dstv, curs, csrc, E);

    // --- fused weight pre-swizzle + x cast ---
    {
        int castN4 = N * 32;                       // N*128/4
        int total = 128 * 256 + 256 * 128 + 128 * 64 + castN4;
        prep_kernel<<<(total + 255) / 256, blk, 0, stream>>>(W1, W2, W3, W1sw, W2sw, W3sw,
                                                             x, Xh, castN4);
    }

    // --- layer 1: 128 -> 4x64 ---
    {
        dim3 grid((N + 127) / 128, 256 / 64);
        gemm_mfma<64><<<grid, blk, 128 * 128, stream>>>(Xh, W1sw, Hh, as1, ad1, a_s, a_d, N, 128, 256);
        agg_kernel<4, 64, 1><<<(N + 3) / 4, blk, 0, stream>>>(Hh, a_s, a_d, offs, csrc, b1, hBh, N);
        hipMemsetAsync(bnsum, 0, 2 * 256 * 4, stream);
        bnstats_kernel<<<256, blk, 0, stream>>>(hBh, bnsum, N, 256);
        int total = N * 256;
        bnapply_kernel<<<(total + 2047) / 2048, blk, 0, stream>>>(hBh, bnsum, g1, bt1, Xh,
                                                                  total, 255, 256, 1.0f / N);
    }
    // --- layer 2: 256 -> 4x32 ---
    {
        dim3 grid((N + 127) / 128, 128 / 64);
        gemm_mfma<32><<<grid, blk, 256 * 128, stream>>>(Xh, W2sw, Hh, as2, ad2, a_s, a_d, N, 256, 128);
        agg_kernel<4, 32, 2><<<(N + 3) / 4, blk, 0, stream>>>(Hh, a_s, a_d, offs, csrc, b2, hBh, N);
        hipMemsetAsync(bnsum, 0, 2 * 128 * 4, stream);
        bnstats_kernel<<<256, blk, 0, stream>>>(hBh, bnsum, N, 128);
        int total = N * 128;
        bnapply_kernel<<<(total + 2047) / 2048, blk, 0, stream>>>(hBh, bnsum, g2, bt2, Xh,
                                                                  total, 127, 128, 1.0f / N);
    }
    // --- layer 3: 128 -> 1x64 (mean over 1 head = identity) ---
    {
        dim3 grid((N + 127) / 128, 64 / 64);
        gemm_mfma<64><<<grid, blk, 128 * 128, stream>>>(Xh, W3sw, Hh, as3, ad3, a_s, a_d, N, 128, 64);
        agg_kernel<1, 64, 4><<<(N + 3) / 4, blk, 0, stream>>>(Hh, a_s, a_d, offs, csrc, b3, hBh, N);
        hipMemsetAsync(bnsum, 0, 2 * 64 * 4, stream);
        bnstats_kernel<<<256, blk, 0, stream>>>(hBh, bnsum, N, 64);
        int total = N * 64;
        bnapply_kernel<<<(total + 2047) / 2048, blk, 0, stream>>>(hBh, bnsum, g3, bt3, Xh,
                                                                  total, 63, 64, 1.0f / N);
    }

    // --- fused global mean pool + MLP head ---
    poolmlp_kernel<<<64, blk, 0, stream>>>(Xh, batch, fw1, fb1, fw2, fb2, fw3, fb3,
                                           (float*)d_out, N);
}

// Round 9
// 584.578 us; speedup vs baseline: 2.4341x; 1.0504x over previous
//
#include <hip/hip_runtime.h>
#include <hip/hip_fp16.h>
#include <math.h>

#define NEG_SLOPE 0.2f
#define SCAN_CHUNK 1024   // 256 threads x 4 elems

typedef _Float16 f16x8 __attribute__((ext_vector_type(8)));
typedef float    f32x4 __attribute__((ext_vector_type(4)));

// ---------------- CSR build ----------------

__global__ void deg_kernel(const int* __restrict__ dst, int* __restrict__ deg, int E) {
    int i = blockIdx.x * 256 + threadIdx.x;
    if (i < E) atomicAdd(&deg[dst[i]], 1);
}

__global__ __launch_bounds__(256) void scan_part1(const int* __restrict__ deg,
                                                  int* __restrict__ bsums, int n) {
    __shared__ int red[256];
    int t = threadIdx.x;
    int b0 = blockIdx.x * SCAN_CHUNK + t * 4;
    int s = 0;
#pragma unroll
    for (int k = 0; k < 4; k++) {
        int idx = b0 + k;
        if (idx < n) s += deg[idx];
    }
    red[t] = s;
    __syncthreads();
    for (int off = 128; off >= 1; off >>= 1) {
        if (t < off) red[t] += red[t + off];
        __syncthreads();
    }
    if (t == 0) bsums[blockIdx.x] = red[0];
}

__global__ __launch_bounds__(256) void scan_part2(int* __restrict__ bsums, int nb) {
    __shared__ int tmp[256];
    __shared__ int carrysh;
    int t = threadIdx.x;
    if (t == 0) carrysh = 0;
    __syncthreads();
    for (int base = 0; base < nb; base += 256) {
        int idx = base + t;
        int v = (idx < nb) ? bsums[idx] : 0;
        tmp[t] = v;
        __syncthreads();
        for (int off = 1; off < 256; off <<= 1) {
            int x = (t >= off) ? tmp[t - off] : 0;
            __syncthreads();
            tmp[t] += x;
            __syncthreads();
        }
        int carry = carrysh;
        if (idx < nb) bsums[idx] = tmp[t] + carry;
        __syncthreads();
        if (t == 255) carrysh = carry + tmp[255];
        __syncthreads();
    }
}

__global__ __launch_bounds__(256) void scan_part3(const int* __restrict__ deg,
                                                  const int* __restrict__ bsums,
                                                  int* __restrict__ offs,
                                                  int* __restrict__ curs, int n) {
    __shared__ int tmp[256];
    int t = threadIdx.x;
    int b = blockIdx.x;
    int b0 = b * SCAN_CHUNK + t * 4;
    int loc[4]; int s = 0;
#pragma unroll
    for (int k = 0; k < 4; k++) {
        int idx = b0 + k;
        int v = (idx < n) ? deg[idx] : 0;
        loc[k] = v; s += v;
    }
    tmp[t] = s;
    __syncthreads();
    for (int off = 1; off < 256; off <<= 1) {
        int x = (t >= off) ? tmp[t - off] : 0;
        __syncthreads();
        tmp[t] += x;
        __syncthreads();
    }
    int carry = (b == 0) ? 0 : bsums[b - 1];
    int pre = carry + tmp[t] - s;
#pragma unroll
    for (int k = 0; k < 4; k++) {
        int idx = b0 + k;
        if (idx < n) {
            curs[idx] = pre;
            offs[idx + 1] = pre + loc[k];
            pre += loc[k];
        }
    }
    if (b == 0 && t == 0) offs[0] = 0;
}

__global__ void fill_kernel(const int* __restrict__ src, const int* __restrict__ dst,
                            int* __restrict__ curs, int* __restrict__ csrc, int E) {
    int i = blockIdx.x * 256 + threadIdx.x;
    if (i < E) {
        int d = dst[i];
        int p = atomicAdd(&curs[d], 1);
        csrc[p] = src[i];
    }
}

// ---------------- fused prep: 3x weight pre-swizzle + x cast ----------------
// Wsw[k/8][n][k%8] fp16  (B-fragment order for MFMA)

__device__ inline void swz1(const float* __restrict__ W, __half* __restrict__ Wsw,
                            int Nout, int i) {
    int k = i / Nout, n = i % Nout;
    Wsw[((size_t)(k >> 3) * Nout + n) * 8 + (k & 7)] = __float2half(W[i]);
}

__global__ void prep_kernel(const float* __restrict__ W1, const float* __restrict__ W2,
                            const float* __restrict__ W3,
                            __half* __restrict__ W1sw, __half* __restrict__ W2sw,
                            __half* __restrict__ W3sw,
                            const float* __restrict__ x, __half* __restrict__ Xh,
                            int castN4) {
    int i = blockIdx.x * 256 + threadIdx.x;
    const int R0 = 128 * 256, R1 = R0 + 256 * 128, R2 = R1 + 128 * 64;
    if (i < R0) { swz1(W1, W1sw, 256, i); }
    else if (i < R1) { swz1(W2, W2sw, 128, i - R0); }
    else if (i < R2) { swz1(W3, W3sw, 64, i - R1); }
    else {
        int j = i - R2;
        if (j < castN4) {
            float4 v = *(const float4*)(x + (size_t)j * 4);
            __half2 pk[2];
            pk[0] = __floats2half2_rn(v.x, v.y);
            pk[1] = __floats2half2_rn(v.z, v.w);
            *(uint2*)(Xh + (size_t)j * 4) = *(uint2*)pk;
        }
    }
}

// ---------------- MFMA fp16 GEMM + fused prev-layer BN + fused scores --------
// Yh[M,Nout] = f(Xh)[M,K] @ W[K,Nout], f = optional BN+ELU (stats from sums).
// Layouts (verified m89/m91): A[m=lane&15][k=quad*8+j], B[k=quad*8+j][n=lane&15],
// D col=lane&15 row=quad*4+reg.

template <int CH, bool BN>
__global__ __launch_bounds__(256) void gemm_mfma(const __half* __restrict__ X,
                                                 const __half* __restrict__ Wsw,
                                                 __half* __restrict__ Yh,
                                                 const float* __restrict__ att_s,
                                                 const float* __restrict__ att_d,
                                                 float* __restrict__ a_s,
                                                 float* __restrict__ a_d,
                                                 const float* __restrict__ sums,
                                                 const float* __restrict__ gbn,
                                                 const float* __restrict__ btbn,
                                                 float invN,
                                                 int M, int K, int Nout) {
    extern __shared__ char smem_raw[];
    __half* Bs = (__half*)smem_raw;                       // K*64 halves
    float* ssc = (float*)(smem_raw + (size_t)K * 64 * 2); // K floats (BN only)
    float* ssb = ssc + K;
    int tid = threadIdx.x;
    int wave = tid >> 6, lane = tid & 63;
    int bm = blockIdx.x * 128;
    int bn = blockIdx.y * 64;

    if (BN && tid < K) {
        float mu = sums[tid] * invN;
        float var = sums[K + tid] * invN - mu * mu;
        float sc = gbn[tid] * rsqrtf(var + 1e-5f);
        ssc[tid] = sc;
        ssb[tid] = btbn[tid] - mu * sc;
    }

    int ktCount = K >> 3;
    int totalVec = ktCount * 64;
    for (int i = tid; i < totalVec; i += 256) {
        int kt = i >> 6, off = i & 63;
        ((uint4*)Bs)[i] = *(const uint4*)(Wsw + ((size_t)kt * Nout + bn + off) * 8);
    }
    __syncthreads();

    int quad = lane >> 4, l15 = lane & 15;
    int row0 = bm + wave * 32 + l15;
    bool r0ok = (row0 < M), r1ok = (row0 + 16 < M);
    const __half* a0p = X + (size_t)row0 * K + quad * 8;
    const __half* a1p = a0p + (size_t)16 * K;

    f32x4 acc[2][4] = {};
    for (int kstep = 0; kstep < K; kstep += 32) {
        f16x8 a0 = {}, a1 = {};
        if (r0ok) a0 = *(const f16x8*)(a0p + kstep);
        if (r1ok) a1 = *(const f16x8*)(a1p + kstep);
        if (BN) {
            int c0 = kstep + quad * 8;
#pragma unroll
            for (int j = 0; j < 8; j++) {
                float sc = ssc[c0 + j], sb = ssb[c0 + j];
                float v0 = (float)a0[j] * sc + sb;
                v0 = v0 > 0.f ? v0 : (__expf(v0) - 1.0f);
                a0[j] = (_Float16)v0;
                float v1 = (float)a1[j] * sc + sb;
                v1 = v1 > 0.f ? v1 : (__expf(v1) - 1.0f);
                a1[j] = (_Float16)v1;
            }
        }
        int ktbase = (kstep >> 3) + quad;
#pragma unroll
        for (int nt = 0; nt < 4; nt++) {
            f16x8 b = *(const f16x8*)(Bs + ((size_t)ktbase * 64 + nt * 16 + l15) * 8);
            acc[0][nt] = __builtin_amdgcn_mfma_f32_16x16x32_f16(a0, b, acc[0][nt], 0, 0, 0);
            acc[1][nt] = __builtin_amdgcn_mfma_f32_16x16x32_f16(a1, b, acc[1][nt], 0, 0, 0);
        }
    }

    // store Yh
#pragma unroll
    for (int mt = 0; mt < 2; mt++) {
#pragma unroll
        for (int r = 0; r < 4; r++) {
            int row = bm + wave * 32 + mt * 16 + quad * 4 + r;
            if (row < M) {
#pragma unroll
                for (int nt = 0; nt < 4; nt++)
                    Yh[(size_t)row * Nout + bn + nt * 16 + l15] = __float2half(acc[mt][nt][r]);
            }
        }
    }

    // fused scores: per-lane partial dot with att vectors, 16-lane reduce
    constexpr int LH = 64 / CH;      // local heads per 64-col tile (1 or 2)
    const int H = Nout / CH;
    float as_l[4], ad_l[4];
#pragma unroll
    for (int nt = 0; nt < 4; nt++) {
        int gcol = bn + nt * 16 + l15;
        as_l[nt] = att_s[gcol];
        ad_l[nt] = att_d[gcol];
    }
    float ps[2][4][LH], pd[2][4][LH];
#pragma unroll
    for (int mt = 0; mt < 2; mt++)
#pragma unroll
        for (int r = 0; r < 4; r++)
#pragma unroll
            for (int lh = 0; lh < LH; lh++) { ps[mt][r][lh] = 0.f; pd[mt][r][lh] = 0.f; }
#pragma unroll
    for (int mt = 0; mt < 2; mt++)
#pragma unroll
        for (int nt = 0; nt < 4; nt++) {
            int lh = (nt * 16) / CH;
#pragma unroll
            for (int r = 0; r < 4; r++) {
                ps[mt][r][lh] += acc[mt][nt][r] * as_l[nt];
                pd[mt][r][lh] += acc[mt][nt][r] * ad_l[nt];
            }
        }
#pragma unroll
    for (int d = 1; d <= 8; d <<= 1) {
#pragma unroll
        for (int mt = 0; mt < 2; mt++)
#pragma unroll
            for (int r = 0; r < 4; r++)
#pragma unroll
                for (int lh = 0; lh < LH; lh++) {
                    ps[mt][r][lh] += __shfl_xor(ps[mt][r][lh], d, 64);
                    pd[mt][r][lh] += __shfl_xor(pd[mt][r][lh], d, 64);
                }
    }
    if (l15 == 0) {
#pragma unroll
        for (int mt = 0; mt < 2; mt++)
#pragma unroll
            for (int r = 0; r < 4; r++) {
                int row = bm + wave * 32 + mt * 16 + quad * 4 + r;
                if (row < M) {
#pragma unroll
                    for (int lh = 0; lh < LH; lh++) {
                        int ghead = bn / CH + lh;
                        a_s[(size_t)row * H + ghead] = ps[mt][r][lh];
                        a_d[(size_t)row * H + ghead] = pd[mt][r][lh];
                    }
                }
            }
    }
}

// ---------------- per-node GAT aggregation (wave per node) --------------------
// 8 fp16 channels per lane (one uint4/lane/edge). LPE = HC/8 lanes per edge,
// EPW = 64/LPE edges gathered concurrently. Cross-group shfl reduce at the end.

template <int H, int C>
__global__ __launch_bounds__(256) void agg_kernel(const __half* __restrict__ h,
                                                  const float* __restrict__ a_s,
                                                  const float* __restrict__ a_d,
                                                  const int* __restrict__ offs,
                                                  const int* __restrict__ csrc,
                                                  const float* __restrict__ bias,
                                                  __half* __restrict__ out, int N) {
    const int HC = H * C;
    const int LPE = HC / 8;          // lanes per edge
    const int EPW = 64 / LPE;        // edges per iteration
    __shared__ float wbuf[4][64 * H];
    __shared__ int   sbuf[4][64];
    int lane = threadIdx.x & 63;
    int wid  = threadIdx.x >> 6;
    int node = blockIdx.x * 4 + wid;
    if (node >= N) return;
    int off = offs[node];
    int deg = offs[node + 1] - off;
    int grp  = lane / LPE;
    int cl   = lane % LPE;
    int mych = cl * 8;
    int mh   = mych / C;

    float adl[H];
#pragma unroll
    for (int hh = 0; hh < H; hh++) adl[hh] = a_d[node * H + hh];

    float acc[8] = {};
    float sc_self = a_s[node * H + mh] + adl[mh];
    sc_self = sc_self > 0.f ? sc_self : NEG_SLOPE * sc_self;
    float w_self = __expf(sc_self);
    if (grp == 0) {
        uint4 raw = *(const uint4*)(h + (size_t)node * HC + mych);
        __half2* hp2 = (__half2*)&raw;
#pragma unroll
        for (int j = 0; j < 4; j++) {
            float2 f = __half22float2(hp2[j]);
            acc[2 * j] = w_self * f.x; acc[2 * j + 1] = w_self * f.y;
        }
    }

    float denp[H];
#pragma unroll
    for (int hh = 0; hh < H; hh++) denp[hh] = 0.f;

    for (int base = 0; base < deg; base += 64) {
        int i = base + lane;
        if (i < deg) {
            int s = csrc[off + i];
            sbuf[wid][lane] = s;
            float asv[H];
            if (H == 4) {
                float4 t4 = *(const float4*)(a_s + (size_t)s * 4);
                asv[0] = t4.x; asv[1] = t4.y; asv[2] = t4.z; asv[3] = t4.w;
            } else {
                asv[0] = a_s[s];
            }
#pragma unroll
            for (int hh = 0; hh < H; hh++) {
                float sc = asv[hh] + adl[hh];
                sc = sc > 0.f ? sc : NEG_SLOPE * sc;
                float w = __expf(sc);
                wbuf[wid][lane * H + hh] = w;
                denp[hh] += w;
            }
        }
        asm volatile("s_waitcnt lgkmcnt(0)" ::: "memory");
        int clc = deg - base; if (clc > 64) clc = 64;
#pragma unroll 8
        for (int e = 0; e < clc; e += EPW) {
            int idx = e + grp;
            if (idx < clc) {
                int s = sbuf[wid][idx];
                float w = wbuf[wid][idx * H + mh];
                uint4 raw = *(const uint4*)(h + (size_t)s * HC + mych);
                __half2* hp2 = (__half2*)&raw;
#pragma unroll
                for (int j = 0; j < 4; j++) {
                    float2 f = __half22float2(hp2[j]);
                    acc[2 * j] += w * f.x; acc[2 * j + 1] += w * f.y;
                }
            }
        }
    }
#pragma unroll
    for (int hh = 0; hh < H; hh++) {
#pragma unroll
        for (int d = 32; d >= 1; d >>= 1)
            denp[hh] += __shfl_xor(denp[hh], d, 64);
    }
    // reduce accumulators across the EPW lane-groups (channel-aligned lanes)
#pragma unroll
    for (int d = LPE; d < 64; d <<= 1) {
#pragma unroll
        for (int k = 0; k < 8; k++)
            acc[k] += __shfl_xor(acc[k], d, 64);
    }
    float inv = 1.0f / (denp[mh] + w_self + 1e-16f);
    if (grp == 0) {
        uint4 pk;
        __half2* op = (__half2*)&pk;
#pragma unroll
        for (int j = 0; j < 4; j++)
            op[j] = __floats2half2_rn(acc[2 * j] * inv + bias[mych + 2 * j],
                                      acc[2 * j + 1] * inv + bias[mych + 2 * j + 1]);
        *(uint4*)(out + (size_t)node * HC + mych) = pk;
    }
}

// ---------------- batch norm stats (fp16 activations, fp32 sums) -------------

__global__ void bnstats_kernel(const __half* __restrict__ buf, float* __restrict__ sums,
                               int N, int Cc) {
    int t = threadIdx.x;
    int c = t % Cc;
    int rpb = 256 / Cc;
    int row = blockIdx.x * rpb + t / Cc;
    int stride = gridDim.x * rpb;
    float s = 0.f, s2 = 0.f;
    for (int n = row; n < N; n += stride) {
        float v = __half2float(buf[(size_t)n * Cc + c]);
        s += v; s2 += v * v;
    }
    atomicAdd(&sums[c], s);
    atomicAdd(&sums[Cc + c], s2);
}

// ---------------- fused BN3+ELU + global mean pool + MLP head ----------------
// one block per graph (batch is sorted); MLP stages are row-independent.

__global__ __launch_bounds__(256) void poolmlp_kernel(const __half* __restrict__ h,
                                                      const int* __restrict__ batch,
                                                      const float* __restrict__ sums,
                                                      const float* __restrict__ gbn,
                                                      const float* __restrict__ btbn,
                                                      float invN,
                                                      const float* __restrict__ fw1, const float* __restrict__ fb1,
                                                      const float* __restrict__ fw2, const float* __restrict__ fb2,
                                                      const float* __restrict__ fw3, const float* __restrict__ fb3,
                                                      float* __restrict__ out, int N) {
    int g = blockIdx.x;
    int t = threadIdx.x;
    __shared__ float ssc[64], ssb[64];
    if (t < 64) {
        float mu = sums[t] * invN;
        float var = sums[64 + t] * invN - mu * mu;
        float sc = gbn[t] * rsqrtf(var + 1e-5f);
        ssc[t] = sc;
        ssb[t] = btbn[t] - mu * sc;
    }
    int lo = 0, hi = N;
    while (lo < hi) { int mid = (lo + hi) >> 1; if (batch[mid] < g) lo = mid + 1; else hi = mid; }
    int s = lo;
    hi = N;
    while (lo < hi) { int mid = (lo + hi) >> 1; if (batch[mid] < g + 1) lo = mid + 1; else hi = mid; }
    int e = lo;
    __syncthreads();

    __shared__ float red[256];
    __shared__ float pm[64];
    __shared__ float z1[128];
    __shared__ float z2[32];
    int c = t & 63, rr = t >> 6;
    float sc = ssc[c], sb = ssb[c];
    float acc = 0.f;
    for (int n = s + rr; n < e; n += 4) {
        float v = __half2float(h[(size_t)n * 64 + c]) * sc + sb;
        acc += v > 0.f ? v : (__expf(v) - 1.0f);
    }
    red[t] = acc;
    __syncthreads();
    if (t < 128) red[t] += red[t + 128];
    __syncthreads();
    if (t < 64) pm[t] = (red[t] + red[t + 64]) / fmaxf((float)(e - s), 1.0f);
    __syncthreads();
    if (t < 128) {
        float v = fb1[t];
        for (int k = 0; k < 64; k++) v += pm[k] * fw1[k * 128 + t];
        z1[t] = v > 0.f ? v : NEG_SLOPE * v;
    }
    __syncthreads();
    if (t < 32) {
        float v = fb2[t];
        for (int k = 0; k < 128; k++) v += z1[k] * fw2[k * 32 + t];
        z2[t] = v > 0.f ? v : NEG_SLOPE * v;
    }
    __syncthreads();
    if (t < 2) {
        float v = fb3[t];
        for (int k = 0; k < 32; k++) v += z2[k] * fw3[k * 2 + t];
        out[g * 2 + t] = v;
    }
}

// ---------------- launch ----------------

extern "C" void kernel_launch(void* const* d_in, const int* in_sizes, int n_in,
                              void* d_out, int out_size, void* d_ws, size_t ws_size,
                              hipStream_t stream) {
    const float* x   = (const float*)d_in[0];
    const int*   ei  = (const int*)d_in[1];
    const int*   batch = (const int*)d_in[2];
    const float* W1  = (const float*)d_in[3];
    const float* as1 = (const float*)d_in[4];
    const float* ad1 = (const float*)d_in[5];
    const float* b1  = (const float*)d_in[6];
    const float* W2  = (const float*)d_in[7];
    const float* as2 = (const float*)d_in[8];
    const float* ad2 = (const float*)d_in[9];
    const float* b2  = (const float*)d_in[10];
    const float* W3  = (const float*)d_in[11];
    const float* as3 = (const float*)d_in[12];
    const float* ad3 = (const float*)d_in[13];
    const float* b3  = (const float*)d_in[14];
    const float* g1  = (const float*)d_in[15];
    const float* bt1 = (const float*)d_in[16];
    const float* g2  = (const float*)d_in[17];
    const float* bt2 = (const float*)d_in[18];
    const float* g3  = (const float*)d_in[19];
    const float* bt3 = (const float*)d_in[20];
    const float* fw1 = (const float*)d_in[21];
    const float* fb1 = (const float*)d_in[22];
    const float* fw2 = (const float*)d_in[23];
    const float* fb2 = (const float*)d_in[24];
    const float* fw3 = (const float*)d_in[25];
    const float* fb3 = (const float*)d_in[26];

    const int N = in_sizes[0] / 128;
    const int E = in_sizes[1] / 2;
    const int* srcv = ei;
    const int* dstv = ei + E;

    // workspace layout (floats)
    float* fws   = (float*)d_ws;
    float* HhF   = fws;                            // N*128 floats -> Hh fp16 N*256
    float* XhF   = HhF + (size_t)N * 128;          // N*128 floats -> Xh fp16 N*256
    float* hBF   = XhF + (size_t)N * 128;          // N*128 floats -> hBh fp16 N*256
    float* a_s   = hBF + (size_t)N * 128;          // N*4
    float* a_d   = a_s + (size_t)N * 4;            // N*4
    float* bnsum1= a_d + (size_t)N * 4;            // 512
    float* bnsum2= bnsum1 + 512;                   // 512
    float* bnsum3= bnsum2 + 512;                   // 512
    int*   deg   = (int*)(bnsum3 + 512);           // N   (contiguous w/ bnsum for 1 memset)
    int*   offs  = deg + N;                        // N+1
    int*   curs  = offs + N + 1;                   // N
    int*   csrc  = curs + N;                       // E
    int*   bsums = csrc + E;                       // ceil(N/1024)
    float* wswF  = (float*)(bsums + ((N + SCAN_CHUNK - 1) / SCAN_CHUNK));
    __half* W1sw = (__half*)wswF;                  // 128*256 halves
    __half* W2sw = W1sw + 128 * 256;               // 256*128 halves
    __half* W3sw = W2sw + 256 * 128;               // 128*64 halves
    __half* Hh   = (__half*)HhF;
    __half* Xh   = (__half*)XhF;
    __half* hBh  = (__half*)hBF;

    const int nbScan = (N + SCAN_CHUNK - 1) / SCAN_CHUNK;
    dim3 blk(256);

    // one memset: bnsum1..3 (1536 floats) + deg (N ints), contiguous
    hipMemsetAsync(bnsum1, 0, (3 * 512 + (size_t)N) * 4, stream);

    // --- build CSR by dst (reused across all 3 layers) ---
    deg_kernel<<<(E + 255) / 256, blk, 0, stream>>>(dstv, deg, E);
    scan_part1<<<nbScan, blk, 0, stream>>>(deg, bsums, N);
    scan_part2<<<1, blk, 0, stream>>>(bsums, nbScan);
    scan_part3<<<nbScan, blk, 0, stream>>>(deg, bsums, offs, curs, N);
    fill_kernel<<<(E + 255) / 256, blk, 0, stream>>>(srcv, dstv, curs, csrc, E);

    // --- fused weight pre-swizzle + x cast ---
    {
        int castN4 = N * 32;                       // N*128/4
        int total = 128 * 256 + 256 * 128 + 128 * 64 + castN4;
        prep_kernel<<<(total + 255) / 256, blk, 0, stream>>>(W1, W2, W3, W1sw, W2sw, W3sw,
                                                             x, Xh, castN4);
    }

    // --- layer 1: 128 -> 4x64 (no input BN) ---
    {
        dim3 grid((N + 127) / 128, 4);
        gemm_mfma<64, false><<<grid, blk, 128 * 128, stream>>>(
            Xh, W1sw, Hh, as1, ad1, a_s, a_d, nullptr, nullptr, nullptr, 0.f, N, 128, 256);
        agg_kernel<4, 64><<<(N + 3) / 4, blk, 0, stream>>>(Hh, a_s, a_d, offs, csrc, b1, hBh, N);
        bnstats_kernel<<<256, blk, 0, stream>>>(hBh, bnsum1, N, 256);
    }
    // --- layer 2: 256 -> 4x32 (BN1+ELU fused into A-load) ---
    {
        dim3 grid((N + 127) / 128, 2);
        gemm_mfma<32, true><<<grid, blk, 256 * 128 + 2 * 256 * 4, stream>>>(
            hBh, W2sw, Hh, as2, ad2, a_s, a_d, bnsum1, g1, bt1, 1.0f / N, N, 256, 128);
        agg_kernel<4, 32><<<(N + 3) / 4, blk, 0, stream>>>(Hh, a_s, a_d, offs, csrc, b2, Xh, N);
        bnstats_kernel<<<256, blk, 0, stream>>>(Xh, bnsum2, N, 128);
    }
    // --- layer 3: 128 -> 1x64 (BN2+ELU fused into A-load) ---
    {
        dim3 grid((N + 127) / 128, 1);
        gemm_mfma<64, true><<<grid, blk, 128 * 128 + 2 * 128 * 4, stream>>>(
            Xh, W3sw, Hh, as3, ad3, a_s, a_d, bnsum2, g2, bt2, 1.0f / N, N, 128, 64);
        agg_kernel<1, 64><<<(N + 3) / 4, blk, 0, stream>>>(Hh, a_s, a_d, offs, csrc, b3, hBh, N);
        bnstats_kernel<<<256, blk, 0, stream>>>(hBh, bnsum3, N, 64);
    }

    // --- fused BN3+ELU + global mean pool + MLP head ---
    poolmlp_kernel<<<64, blk, 0, stream>>>(hBh, batch, bnsum3, g3, bt3, 1.0f / N,
                                           fw1, fb1, fw2, fb2, fw3, fb3,
                                           (float*)d_out, N);
}